// Round 10
// baseline (1764.129 us; speedup 1.0000x reference)
//
#include <hip/hip_runtime.h>
#include <hip/hip_bf16.h>
#include <math.h>

#define DEV __device__ __forceinline__

DEV float wsum64(float v){
  #pragma unroll
  for (int off = 32; off; off >>= 1) v += __shfl_xor(v, off, 64);
  return v;
}
DEV float geluf(float x){
  return 0.5f*x*(1.f + tanhf(0.7978845608028654f*(x + 0.044715f*x*x*x)));
}
DEV float gelu_bwdf(float x){
  float x2 = x*x;
  float t = tanhf(0.79788456f*x*(1.f + 0.044715f*x2));
  return 0.5f*x*((1.f - t*t)*(0.79788456f + 0.1070322243f*x2)) + 0.5f*(1.f + t);
}
DEV float sigmf(float x){ return 1.f/(1.f + expf(-x)); }

// ---------------------------------------------------------------------------
// Stem s11: x[512,3,96,96] -> conv7x7 s2 p3 -> BN -> ReLU -> pool2 -> xs[512,8,24,24]
__global__ __launch_bounds__(192) void k_s11(const float* __restrict__ x,
    const float* __restrict__ w, const float* __restrict__ bias,
    const float* __restrict__ bn, float* __restrict__ xs){
  __shared__ float st[3*37*2*53];   // 11766 floats
  __shared__ float wl[49*3*8];      // 1176
  int bx = blockIdx.x;
  int bd = bx / 3, g = bx - bd*3;
  int t = threadIdx.x;
  for (int e = t; e < 1176; e += 192){
    int tap = e / 24, r = e - tap*24, ci = r >> 3, c = r & 7;
    wl[e] = w[(c*3 + ci)*49 + tap];
  }
  const float* xb = x + (size_t)bd*3*9216;
  for (int e = t; e < 3*37*102; e += 192){
    int ci = e / 3774, r2 = e - ci*3774;
    int ihl = r2 / 102, pi = r2 - ihl*102;
    int ih = ihl + 32*g - 3, iw = pi - 3;
    float v = 0.f;
    if (ih>=0 && ih<96 && iw>=0 && iw<96) v = xb[(size_t)ci*9216 + ih*96 + iw];
    st[((ci*37 + ihl)*2 + (pi&1))*53 + (pi>>1)] = v;
  }
  __syncthreads();
  int pr = t / 24, pc = t - pr*24;
  float a00[8], a01[8], a10[8], a11[8];
  #pragma unroll
  for (int c=0;c<8;c++){ a00[c]=0.f; a01[c]=0.f; a10[c]=0.f; a11[c]=0.f; }
  for (int ci=0; ci<3; ci++){
    for (int kh=0; kh<7; kh++){
      int rb0 = (ci*37 + 4*pr + kh)*106 + 2*pc;
      int rb1 = rb0 + 212;
      #pragma unroll
      for (int kw=0; kw<7; kw++){
        int off = (kw&1)*53 + (kw>>1);
        float v00 = st[rb0+off], v01 = st[rb0+off+1];
        float v10 = st[rb1+off], v11 = st[rb1+off+1];
        const float4* wp = (const float4*)&wl[((kh*7+kw)*3 + ci)*8];
        float wv[8];
        *(float4*)&wv[0] = wp[0]; *(float4*)&wv[4] = wp[1];
        #pragma unroll
        for (int c=0;c<8;c++){
          a00[c] += v00*wv[c]; a01[c] += v01*wv[c];
          a10[c] += v10*wv[c]; a11[c] += v11*wv[c];
        }
      }
    }
  }
  int pos = (g*8 + pr)*24 + pc;
  #pragma unroll
  for (int c=0;c<8;c++){
    float gg=bn[c], be=bn[8+c], m=bn[16+c], vv=bn[24+c];
    float s = gg*rsqrtf(vv + 1e-5f);
    float bi = bias[c];
    float mx = 0.f;
    mx = fmaxf(mx, (a00[c]+bi-m)*s+be);
    mx = fmaxf(mx, (a01[c]+bi-m)*s+be);
    mx = fmaxf(mx, (a10[c]+bi-m)*s+be);
    mx = fmaxf(mx, (a11[c]+bi-m)*s+be);
    xs[((size_t)bd*8 + c)*576 + pos] = mx;
  }
}

// Stem s12: same structure on frame-diffs (4 groups of 3 channels, diff at staging).
__global__ __launch_bounds__(192) void k_s12(const float* __restrict__ x,
    const float* __restrict__ w, const float* __restrict__ bias,
    const float* __restrict__ bn, float* __restrict__ xd){
  __shared__ float st[3*37*2*53];
  __shared__ float wl[49*12*8];     // 4704
  int bx = blockIdx.x;
  int bd = bx / 3, g = bx - bd*3;
  int b = bd >> 8, dd = bd & 255;
  int t = threadIdx.x;
  for (int e = t; e < 4704; e += 192){
    int tap = e / 96, r = e - tap*96, ci = r >> 3, c = r & 7;
    wl[e] = w[(c*12 + ci)*49 + tap];
  }
  int fa[4], fb[4];
  fa[0] = dd>=2 ? dd-1 : 0;     fb[0] = dd>=2 ? dd-2 : 0;
  fa[1] = dd;                   fb[1] = dd>=1 ? dd-1 : 0;
  fa[2] = dd<=254 ? dd+1 : 255; fb[2] = dd;
  fa[3] = dd<=253 ? dd+2 : 255; fb[3] = dd<=254 ? dd+1 : 255;
  int pr = t / 24, pc = t - pr*24;
  float a00[8], a01[8], a10[8], a11[8];
  #pragma unroll
  for (int c=0;c<8;c++){ a00[c]=0.f; a01[c]=0.f; a10[c]=0.f; a11[c]=0.f; }
  for (int g4=0; g4<4; g4++){
    if (fa[g4] == fb[g4]) continue;   // zero diff, uniform per block
    __syncthreads();
    const float* xa = x + ((size_t)(b*256 + fa[g4]))*3*9216;
    const float* xbp= x + ((size_t)(b*256 + fb[g4]))*3*9216;
    for (int e = t; e < 3*37*102; e += 192){
      int ci = e / 3774, r2 = e - ci*3774;
      int ihl = r2 / 102, pi = r2 - ihl*102;
      int ih = ihl + 32*g - 3, iw = pi - 3;
      float v = 0.f;
      if (ih>=0 && ih<96 && iw>=0 && iw<96){
        size_t off = (size_t)ci*9216 + ih*96 + iw;
        v = xa[off] - xbp[off];
      }
      st[((ci*37 + ihl)*2 + (pi&1))*53 + (pi>>1)] = v;
    }
    __syncthreads();
    for (int ci=0; ci<3; ci++){
      int gch = g4*3 + ci;
      for (int kh=0; kh<7; kh++){
        int rb0 = (ci*37 + 4*pr + kh)*106 + 2*pc;
        int rb1 = rb0 + 212;
        #pragma unroll
        for (int kw=0; kw<7; kw++){
          int off = (kw&1)*53 + (kw>>1);
          float v00 = st[rb0+off], v01 = st[rb0+off+1];
          float v10 = st[rb1+off], v11 = st[rb1+off+1];
          const float4* wp = (const float4*)&wl[((kh*7+kw)*12 + gch)*8];
          float wv[8];
          *(float4*)&wv[0] = wp[0]; *(float4*)&wv[4] = wp[1];
          #pragma unroll
          for (int c=0;c<8;c++){
            a00[c] += v00*wv[c]; a01[c] += v01*wv[c];
            a10[c] += v10*wv[c]; a11[c] += v11*wv[c];
          }
        }
      }
    }
  }
  int pos = (g*8 + pr)*24 + pc;
  #pragma unroll
  for (int c=0;c<8;c++){
    float gg=bn[c], be=bn[8+c], m=bn[16+c], vv=bn[24+c];
    float s = gg*rsqrtf(vv + 1e-5f);
    float bi = bias[c];
    float mx = 0.f;
    mx = fmaxf(mx, (a00[c]+bi-m)*s+be);
    mx = fmaxf(mx, (a01[c]+bi-m)*s+be);
    mx = fmaxf(mx, (a10[c]+bi-m)*s+be);
    mx = fmaxf(mx, (a11[c]+bi-m)*s+be);
    xd[((size_t)bd*8 + c)*576 + pos] = mx;
  }
}

// Merged s21+s22: conv1 on 0.5*(xs+xd), conv2 on xd, both 7x7 s1 p3 + BN relu pool.
// Writes pm = 0.5*(p1+p2)  [512,16,12,12]. One block per bd.
__global__ __launch_bounds__(256) void k_s2m(const float* __restrict__ xs,
    const float* __restrict__ xd,
    const float* __restrict__ w1, const float* __restrict__ b1,
    const float* __restrict__ bn1,
    const float* __restrict__ w2, const float* __restrict__ b2,
    const float* __restrict__ bn2, float* __restrict__ pm){
  __shared__ float st[8*30*33];     // 7920
  __shared__ float wl[49*8*16];     // 6272
  int bd = blockIdx.x;
  int t = threadIdx.x;
  const float* pa = xs + (size_t)bd*8*576;
  const float* pb = xd + (size_t)bd*8*576;
  float r1[16];
  // ---- phase 1: conv s21 on 0.5*(xs+xd) ----
  for (int e = t; e < 6272; e += 256){
    int tap = e >> 7, r = e & 127, ci = r >> 4, c = r & 15;
    wl[e] = w1[(c*8 + ci)*49 + tap];
  }
  for (int e = t; e < 7920; e += 256){
    int ci = e / 990, r2 = e - ci*990;
    int r = r2 / 33, cc = r2 - r*33;
    int ih = r - 3, iw = cc - 3;
    float v = 0.f;
    if (ih>=0 && ih<24 && iw>=0 && iw<24){
      int off = ci*576 + ih*24 + iw;
      v = 0.5f*(pa[off] + pb[off]);
    }
    st[(ci*30 + r)*33 + cc] = v;
  }
  __syncthreads();
  int pr = 0, pc = 0;
  if (t < 144){ pr = t / 12; pc = t - pr*12; }
  if (t < 144){
    float a00[16], a01[16], a10[16], a11[16];
    #pragma unroll
    for (int c=0;c<16;c++){ a00[c]=0.f; a01[c]=0.f; a10[c]=0.f; a11[c]=0.f; }
    for (int ci=0; ci<8; ci++){
      for (int kh=0; kh<7; kh++){
        int rb = (ci*30 + 2*pr + kh)*33 + 2*pc;
        #pragma unroll
        for (int kw=0; kw<7; kw++){
          float v00 = st[rb+kw],    v01 = st[rb+kw+1];
          float v10 = st[rb+33+kw], v11 = st[rb+34+kw];
          const float4* wp = (const float4*)&wl[((kh*7+kw)*8 + ci)*16];
          float wv[16];
          *(float4*)&wv[0]  = wp[0]; *(float4*)&wv[4]  = wp[1];
          *(float4*)&wv[8]  = wp[2]; *(float4*)&wv[12] = wp[3];
          #pragma unroll
          for (int c=0;c<16;c++){
            a00[c] += v00*wv[c]; a01[c] += v01*wv[c];
            a10[c] += v10*wv[c]; a11[c] += v11*wv[c];
          }
        }
      }
    }
    #pragma unroll
    for (int c=0;c<16;c++){
      float gg=bn1[c], be=bn1[16+c], m=bn1[32+c], vv=bn1[48+c];
      float s = gg*rsqrtf(vv + 1e-5f);
      float bi = b1[c];
      float mx = 0.f;
      mx = fmaxf(mx, (a00[c]+bi-m)*s+be);
      mx = fmaxf(mx, (a01[c]+bi-m)*s+be);
      mx = fmaxf(mx, (a10[c]+bi-m)*s+be);
      mx = fmaxf(mx, (a11[c]+bi-m)*s+be);
      r1[c] = mx;
    }
  }
  __syncthreads();
  // ---- phase 2: conv s22 on xd ----
  for (int e = t; e < 6272; e += 256){
    int tap = e >> 7, r = e & 127, ci = r >> 4, c = r & 15;
    wl[e] = w2[(c*8 + ci)*49 + tap];
  }
  for (int e = t; e < 7920; e += 256){
    int ci = e / 990, r2 = e - ci*990;
    int r = r2 / 33, cc = r2 - r*33;
    int ih = r - 3, iw = cc - 3;
    float v = 0.f;
    if (ih>=0 && ih<24 && iw>=0 && iw<24)
      v = pb[ci*576 + ih*24 + iw];
    st[(ci*30 + r)*33 + cc] = v;
  }
  __syncthreads();
  if (t < 144){
    float a00[16], a01[16], a10[16], a11[16];
    #pragma unroll
    for (int c=0;c<16;c++){ a00[c]=0.f; a01[c]=0.f; a10[c]=0.f; a11[c]=0.f; }
    for (int ci=0; ci<8; ci++){
      for (int kh=0; kh<7; kh++){
        int rb = (ci*30 + 2*pr + kh)*33 + 2*pc;
        #pragma unroll
        for (int kw=0; kw<7; kw++){
          float v00 = st[rb+kw],    v01 = st[rb+kw+1];
          float v10 = st[rb+33+kw], v11 = st[rb+34+kw];
          const float4* wp = (const float4*)&wl[((kh*7+kw)*8 + ci)*16];
          float wv[16];
          *(float4*)&wv[0]  = wp[0]; *(float4*)&wv[4]  = wp[1];
          *(float4*)&wv[8]  = wp[2]; *(float4*)&wv[12] = wp[3];
          #pragma unroll
          for (int c=0;c<16;c++){
            a00[c] += v00*wv[c]; a01[c] += v01*wv[c];
            a10[c] += v10*wv[c]; a11[c] += v11*wv[c];
          }
        }
      }
    }
    #pragma unroll
    for (int c=0;c<16;c++){
      float gg=bn2[c], be=bn2[16+c], m=bn2[32+c], vv=bn2[48+c];
      float s = gg*rsqrtf(vv + 1e-5f);
      float bi = b2[c];
      float mx = 0.f;
      mx = fmaxf(mx, (a00[c]+bi-m)*s+be);
      mx = fmaxf(mx, (a01[c]+bi-m)*s+be);
      mx = fmaxf(mx, (a10[c]+bi-m)*s+be);
      mx = fmaxf(mx, (a11[c]+bi-m)*s+be);
      pm[((size_t)bd*16 + c)*144 + pr*12 + pc] = 0.5f*(r1[c] + mx);
    }
  }
}

// s3 conv3x3 p1 + BN + attention-mask pooled signal. Input pm (pre-averaged).
__global__ __launch_bounds__(256) void k_s3(const float* __restrict__ pm,
    const float* __restrict__ w,
    const float* __restrict__ bias, const float* __restrict__ bn,
    float* __restrict__ sig){
  __shared__ float ins[16*14*14];
  __shared__ float wT[144*64];
  __shared__ float redS[64*4];
  __shared__ float redF[64*4];
  int bd = blockIdx.x;
  int t = threadIdx.x;
  for (int i = t; i < 16*196; i += 256){
    int ci = i/196, r = i - ci*196, y = r/14, xx = r - y*14;
    float v = 0.f;
    if (y>=1 && y<=12 && xx>=1 && xx<=12){
      size_t idx = ((size_t)bd*16 + ci)*144 + (y-1)*12 + (xx-1);
      v = pm[idx];
    }
    ins[i] = v;
  }
  for (int i = t; i < 9216; i += 256){
    int c = i & 63, k = i >> 6;
    wT[i] = w[c*144 + k];
  }
  __syncthreads();
  int c = t & 63, pg = t >> 6;
  float acc[36];
  #pragma unroll
  for (int pp=0;pp<36;pp++) acc[pp]=0.f;
  for (int k=0; k<144; k++){
    int ci = k/9, kk = k - ci*9, kh = kk/3, kw = kk - kh*3;
    float wv = wT[k*64 + c];
    const float* ip = &ins[ci*196];
    #pragma unroll
    for (int pp=0;pp<36;pp++){
      int y = pg*3 + pp/12, xx = pp%12;
      acc[pp] += ip[(y+kh)*14 + (xx+kw)] * wv;
    }
  }
  float g=bn[c], be=bn[64+c], m=bn[128+c], vv=bn[192+c];
  float s = g*rsqrtf(vv + 1e-5f);
  float bi = bias[c];
  float sS = 0.f, sF = 0.f;
  #pragma unroll
  for (int pp=0;pp<36;pp++){
    float f = (acc[pp] + bi - m)*s + be;
    float sg = sigmf(f);
    sS += sg; sF += f*sg;
  }
  redS[c*4+pg] = sS; redF[c*4+pg] = sF;
  __syncthreads();
  if (t < 64){
    float S = redS[t*4]+redS[t*4+1]+redS[t*4+2]+redS[t*4+3];
    float F = redF[t*4]+redF[t*4+1]+redF[t*4+2]+redF[t*4+3];
    sig[(size_t)bd*64 + t] = 0.5f*F/S;
  }
}

// c1 1x1 conv: sig[b,t,64] -> h[b,256,256] (channel-major). block=(b,o). grid 512.
__global__ __launch_bounds__(256) void k_c1(const float* __restrict__ sig,
    const float* __restrict__ w, const float* __restrict__ bias,
    float* __restrict__ h){
  int b = blockIdx.x >> 8, o = blockIdx.x & 255, tt = threadIdx.x;
  __shared__ float wl[64];
  if (tt < 64) wl[tt] = w[o*64 + tt];
  __syncthreads();
  const float4* sp = (const float4*)(sig + ((size_t)(b*256 + tt))*64);
  const float4* wp = (const float4*)wl;
  float a = bias[o];
  #pragma unroll
  for (int i=0;i<16;i++){
    float4 s4 = sp[i]; float4 w4 = wp[i];
    a += s4.x*w4.x + s4.y*w4.y + s4.z*w4.z + s4.w*w4.w;
  }
  h[((size_t)b*256 + o)*256 + tt] = fmaxf(a, 0.f);
}

// conv1d 256->256 k3 p1 + relu. 512 blocks (8 outch each) for 2 blocks/CU.
// mode: 0=none 1=acc:=out 2=acc+=out.
__global__ __launch_bounds__(256) void k_conv1d(const float* __restrict__ hin,
    const float* __restrict__ w, const float* __restrict__ bias,
    float* __restrict__ hout, float* __restrict__ accb, int mode){
  __shared__ float ins[256*34];
  __shared__ float ws[8*256*4];    // 8 outch, padded stride-4 taps (32KB)
  int bx = blockIdx.x;
  int b = bx >> 8;
  int rem = bx & 255;
  int og = rem >> 3;               // 32 groups of 8 outch
  int tg = rem & 7;
  int tid = threadIdx.x;
  int t0 = tg*32;
  for (int idx = tid; idx < 256*34; idx += 256){
    int ii = idx/34, jj = idx - ii*34;
    int tglob = t0 - 1 + jj;
    float v = 0.f;
    if (tglob >= 0 && tglob < 256) v = hin[((size_t)b*256 + ii)*256 + tglob];
    ins[idx] = v;
  }
  for (int idx = tid; idx < 6144; idx += 256){
    int q = idx/3;
    ws[q*4 + (idx - q*3)] = w[(size_t)og*6144 + idx];
  }
  __syncthreads();
  int ol = tid >> 5, tl = tid & 31;
  int o = og*8 + ol;
  float a1 = bias[o];
  const float4* w1q = (const float4*)(ws + (size_t)ol*1024);
  for (int i=0;i<256;i++){
    float v0 = ins[i*34 + tl];
    float v1 = ins[i*34 + tl + 1];
    float v2 = ins[i*34 + tl + 2];
    float4 wa = w1q[i];
    a1 += wa.x*v0 + wa.y*v1 + wa.z*v2;
  }
  a1 = fmaxf(a1, 0.f);
  size_t i1 = ((size_t)b*256 + o)*256 + t0 + tl;
  hout[i1] = a1;
  if (mode == 1) accb[i1] = a1;
  else if (mode == 2) accb[i1] += a1;
}

// Fused LN + projections + eta. One block per (b,t) row. grid 512.
__global__ __launch_bounds__(256) void k_lnproj(const float* __restrict__ acc,
    const float* __restrict__ g, const float* __restrict__ be,
    const float* __restrict__ wqp, const float* __restrict__ wkp,
    const float* __restrict__ wvp, const float* __restrict__ lrw,
    const float* __restrict__ lrb, float* __restrict__ xq,
    float* __restrict__ xk, float* __restrict__ xv,
    float* __restrict__ etalr){
  int b = blockIdx.x >> 8, tt = blockIdx.x & 255, c = threadIdx.x;
  __shared__ float hrow[256];
  __shared__ float rs[4];
  __shared__ float rq[4];
  __shared__ float epb[4][4];   // [wave][head]
  int wv_ = c >> 6, ln = c & 63;
  float v = acc[((size_t)b*256 + c)*256 + tt];
  float s1 = wsum64(v), s2 = wsum64(v*v);
  if (ln == 0){ rs[wv_]=s1; rq[wv_]=s2; }
  __syncthreads();
  float mu = (rs[0]+rs[1]+rs[2]+rs[3])*(1.f/256.f);
  float msq = (rq[0]+rq[1]+rq[2]+rq[3])*(1.f/256.f);
  float var = msq - mu*mu;
  float hv = (v-mu)*rsqrtf(var + 1e-5f)*g[c] + be[c];
  hrow[c] = hv;
  __syncthreads();
  // eta partials (per wave, 4 heads)
  {
    float p0 = hv*lrw[c];
    float p1 = hv*lrw[256 + c];
    float p2 = hv*lrw[512 + c];
    float p3 = hv*lrw[768 + c];
    p0 = wsum64(p0); p1 = wsum64(p1); p2 = wsum64(p2); p3 = wsum64(p3);
    if (ln == 0){ epb[wv_][0]=p0; epb[wv_][1]=p1; epb[wv_][2]=p2; epb[wv_][3]=p3; }
  }
  // three projections
  float aq = 0.f, ak = 0.f, av = 0.f;
  for (int k=0;k<256;k++){
    float hk = hrow[k];
    aq += hk*wqp[(size_t)k*256 + c];
    ak += hk*wkp[(size_t)k*256 + c];
    av += hk*wvp[(size_t)k*256 + c];
  }
  size_t row = (size_t)blockIdx.x;
  xq[row*256 + c] = aq;
  xk[row*256 + c] = ak;
  xv[row*256 + c] = av;
  __syncthreads();
  if (c < 4){
    float a = lrb[c] + epb[0][c] + epb[1][c] + epb[2][c] + epb[3][c];
    etalr[((size_t)(b*4 + c))*256 + tt] = 0.1f*sigmf(a)*(1.f/64.f);
  }
}

// TTT-MLP scan, 512 threads (2 waves/SIMD). One block/(b,h). 7 barriers/step:
// gz1 exchange removed by publishing gelu_bwd factors (gb_pk) at phase B and
// computing the gZ2@W2^T dot with 4 accumulators on float4 gz2 reads.
__global__ __launch_bounds__(512) void k_ttt(
    const float* __restrict__ xq, const float* __restrict__ xk,
    const float* __restrict__ xv, const float* __restrict__ etalr,
    const float* __restrict__ tib, const float* __restrict__ lnw,
    const float* __restrict__ lnb, const float* __restrict__ W1g,
    const float* __restrict__ B1g, const float* __restrict__ W2g,
    const float* __restrict__ B2g, float* __restrict__ out){
  __shared__ float W1s[64*256];                 // [d][j]
  __shared__ float W2L[256*65];                 // [r][c] pitch 65
  __shared__ __align__(16) float k_pk[256];     // [d=64][slot4]
  __shared__ __align__(16) float q_pk[256];
  __shared__ __align__(16) float v_pk[256];
  __shared__ __align__(16) float x2_pk[1024];   // [j=256][slot4]
  __shared__ __align__(16) float x2b_pk[1024];
  __shared__ __align__(16) float gb_pk[1024];   // gelu_bwd(Z1) factors
  __shared__ __align__(16) float gz2_pk[256];   // [cl=64][slot4]
  __shared__ float pzs[4*576];                  // [row][cl*9+seg]
  __shared__ float a2w[64];
  __shared__ float coefs[16];                   // row-indexed [i*4+r]
  __shared__ float coef2s[16];
  __shared__ float els[4];
  __shared__ float toks_s[4];

  int b = blockIdx.x >> 2, h = blockIdx.x & 3;
  int tid = threadIdx.x;
  int j = tid & 255;
  int i2 = tid >> 8;
  int iw = j >> 6, cl = j & 63;
  int ps_iw = ((iw & 1) << 1) | (iw >> 1);      // pslot(iw)

  const float* W1b = W1g + (size_t)h*16384;
  const float* W2b = W2g + (size_t)h*16384;
  for (int i = tid; i < 16384; i += 512) W1s[i] = W1b[i];
  for (int i = tid; i < 16384; i += 512){
    int r = i >> 6, c = i & 63;
    W2L[r*65 + c] = W2b[i];
  }
  float b1r = B1g[h*256 + j];
  float b2r = B2g[h*64 + cl];
  float gr = lnw[h*64 + cl], br = lnb[h*64 + cl];
  if (tid < 4) toks_s[tid] = fmaxf(1.f/(float)(tid+1) + tib[tid], 0.f);
  __syncthreads();
  float tok3 = toks_s[3];
  float tik = toks_s[iw];

  const float* xqp = xq + (size_t)b*65536 + h*64;
  const float* xkp = xk + (size_t)b*65536 + h*64;
  const float* xvp = xv + (size_t)b*65536 + h*64;
  const float* ep  = etalr + (size_t)(b*4 + h)*256;

  float qv=0.f, kv=0.f, vv=0.f, elv=0.f;
  if (i2 == 0){ qv = xqp[(size_t)iw*256 + cl]; kv = xkp[(size_t)iw*256 + cl]; }
  else        { vv = xvp[(size_t)iw*256 + cl]; }
  if (tid < 4) elv = ep[tid];

  for (int n=0; n<64; n++){
    // --- stage ---
    if (i2 == 0){ k_pk[cl*4 + ps_iw] = kv; q_pk[cl*4 + ps_iw] = qv; }
    else        { v_pk[cl*4 + ps_iw] = vv; }
    if (tid < 4) els[tid] = elv;
    __syncthreads();                              // A
    // --- A1 (half0 waves; wave iw = row iw) ---
    if (i2 == 0){
      float4 k4a = *(const float4*)&k_pk[cl*4];   // slots = rows 0,2,1,3
      float a0 = wsum64(qv*k4a.x);
      float a1 = wsum64(qv*k4a.y);
      float a2 = wsum64(qv*k4a.z);
      float a3 = wsum64(qv*k4a.w);
      if (cl == 0){
        coefs[iw*4+0] = tik*els[0]*(a0+1.f);
        coefs[iw*4+2] = (iw>=2) ? tik*els[2]*(a1+1.f) : 0.f;
        coefs[iw*4+1] = (iw>=1) ? tik*els[1]*(a2+1.f) : 0.f;
        coefs[iw*4+3] = (iw>=3) ? tik*els[3]*(a3+1.f) : 0.f;
      }
    }
    // --- Z1 rows (i2, i2+2): full d-range ---
    float z10=b1r, z11=b1r, qw0=b1r, qw1=b1r;
    #pragma unroll 8
    for (int d=0; d<64; d++){
      float2 k2 = *(const float2*)&k_pk[d*4 + i2*2];
      float2 q2 = *(const float2*)&q_pk[d*4 + i2*2];
      float w = W1s[d*256 + j];
      z10 += k2.x*w; z11 += k2.y*w; qw0 += q2.x*w; qw1 += q2.y*w;
    }
    float x2o0 = geluf(z10), x2o1 = geluf(z11);
    { float2 t; t.x=x2o0; t.y=x2o1; *(float2*)&x2_pk[j*4 + i2*2] = t; }
    { float2 t; t.x=gelu_bwdf(z10); t.y=gelu_bwdf(z11);
      *(float2*)&gb_pk[j*4 + i2*2] = t; }
    __syncthreads();                              // B
    // --- prefetch next step ---
    float qn=0.f, kn=0.f, vn=0.f, eln=0.f;
    if (n < 63){
      int l2 = (n+1)*4 + iw;
      if (i2 == 0){ qn = xqp[(size_t)l2*256 + cl]; kn = xkp[(size_t)l2*256 + cl]; }
      else        { vn = xvp[(size_t)l2*256 + cl]; }
      if (tid < 4) eln = ep[(n+1)*4 + tid];
    }
    // --- Z2 split-K: seg = iw*2+i2, 32 d's, all 4 rows via slots ---
    {
      int d0 = (iw*2 + i2)*32;
      int seg = iw*2 + i2;
      float p0=0.f,p1=0.f,p2=0.f,p3=0.f;
      #pragma unroll 8
      for (int dd=0; dd<32; dd++){
        float4 x4 = *(const float4*)&x2_pk[(d0+dd)*4];
        float w = W2L[(d0+dd)*65 + cl];
        p0 += x4.x*w; p1 += x4.y*w; p2 += x4.z*w; p3 += x4.w*w;
      }
      pzs[0*576 + cl*9 + seg] = p0;   // slot0 = row0
      pzs[2*576 + cl*9 + seg] = p1;   // slot1 = row2
      pzs[1*576 + cl*9 + seg] = p2;   // slot2 = row1
      pzs[3*576 + cl*9 + seg] = p3;   // slot3 = row3
    }
    __syncthreads();                              // C
    // --- fused LN-L2 backward (half0 wave iw = row iw) ---
    if (i2 == 0){
      float z2 = b2r;
      #pragma unroll
      for (int sg=0; sg<8; sg++) z2 += pzs[iw*576 + cl*9 + sg];
      float mu = wsum64(z2)*(1.f/64.f);
      float df = z2 - mu;
      float var = wsum64(df*df)*(1.f/64.f);
      float stdv = sqrtf(var + 1e-6f);
      float xhat = df/stdv;
      float tgt = v_pk[cl*4 + ps_iw] - kv;
      float gxh = (gr*xhat + br - tgt)*gr;
      float sg1 = wsum64(gxh);
      float sg2 = wsum64(gxh*xhat);
      float gz2 = (64.f*gxh - sg1 - xhat*sg2)*(1.f/(64.f*stdv));
      gz2_pk[cl*4 + ps_iw] = gz2;
    }
    __syncthreads();                              // D
    // --- gZ1 all 4 rows locally (float4 gz2 reads x published gb factors) ---
    float gd0=0.f, gd1=0.f, gd2=0.f, gd3=0.f;
    #pragma unroll 8
    for (int c=0; c<64; c++){
      float4 g4 = *(const float4*)&gz2_pk[c*4];
      float w = W2L[j*65 + c];
      gd0 += g4.x*w; gd1 += g4.y*w; gd2 += g4.z*w; gd3 += g4.w*w;
    }
    float4 gb4 = *(const float4*)&gb_pk[j*4];
    float4 gz14;
    gz14.x = gd0*gb4.x; gz14.y = gd1*gb4.y;
    gz14.z = gd2*gb4.z; gz14.w = gd3*gb4.w;       // slots 0,2,1,3
    // --- Z1b/X2b rows (i2, i2+2) ---
    int R0 = i2, R1 = i2 + 2;
    float zb0 = qw0 - (coefs[R0*4+0]*gz14.x + coefs[R0*4+2]*gz14.y
                     + coefs[R0*4+1]*gz14.z + coefs[R0*4+3]*gz14.w);
    float zb1 = qw1 - (coefs[R1*4+0]*gz14.x + coefs[R1*4+2]*gz14.y
                     + coefs[R1*4+1]*gz14.z + coefs[R1*4+3]*gz14.w);
    float xb0 = geluf(zb0), xb1 = geluf(zb1);
    { float2 t; t.x=xb0; t.y=xb1; *(float2*)&x2b_pk[j*4 + i2*2] = t; }
    // --- A2 masked products, split 4/6 across halves (x2_pk is stable) ---
    if (i2 == 0){
      float xo1 = x2_pk[j*4 + 2];                 // row1
      float s00 = wsum64(xb0*x2o0);               // (0,0)
      float s20 = wsum64(xb1*x2o0);               // (2,0)
      float s22 = wsum64(xb1*x2o1);               // (2,2)
      float s21 = wsum64(xb1*xo1);                // (2,1)
      if (cl == 0){
        a2w[iw*16+0]  = s00;
        a2w[iw*16+8]  = s20;
        a2w[iw*16+10] = s22;
        a2w[iw*16+9]  = s21;
      }
    } else {
      float2 xo02 = *(const float2*)&x2_pk[j*4];  // rows 0,2
      float s11 = wsum64(xb0*x2o0);               // (1,1)
      float s10 = wsum64(xb0*xo02.x);             // (1,0)
      float s31 = wsum64(xb1*x2o0);               // (3,1)
      float s33 = wsum64(xb1*x2o1);               // (3,3)
      float s30 = wsum64(xb1*xo02.x);             // (3,0)
      float s32 = wsum64(xb1*xo02.y);             // (3,2)
      if (cl == 0){
        a2w[iw*16+5]  = s11;
        a2w[iw*16+4]  = s10;
        a2w[iw*16+13] = s31;
        a2w[iw*16+15] = s33;
        a2w[iw*16+12] = s30;
        a2w[iw*16+14] = s32;
      }
    }
    __syncthreads();                              // E
    if (tid < 16){
      int ii = tid >> 2, rr = tid & 3;
      float s = a2w[tid] + a2w[16+tid] + a2w[32+tid] + a2w[48+tid];
      coef2s[tid] = (rr <= ii) ? toks_s[ii]*els[rr]*(s + 1.f) : 0.f;
    }
    // --- Z2b split-K ---
    {
      int d0 = (iw*2 + i2)*32;
      int seg = iw*2 + i2;
      float p0=0.f,p1=0.f,p2=0.f,p3=0.f;
      #pragma unroll 8
      for (int dd=0; dd<32; dd++){
        float4 x4 = *(const float4*)&x2b_pk[(d0+dd)*4];
        float w = W2L[(d0+dd)*65 + cl];
        p0 += x4.x*w; p1 += x4.y*w; p2 += x4.z*w; p3 += x4.w*w;
      }
      pzs[0*576 + cl*9 + seg] = p0;
      pzs[2*576 + cl*9 + seg] = p1;
      pzs[1*576 + cl*9 + seg] = p2;
      pzs[3*576 + cl*9 + seg] = p3;
    }
    __syncthreads();                              // F
    // --- ln_fwd + output + b2 update (half0) ---
    if (i2 == 0){
      float z2b = b2r;
      #pragma unroll
      for (int sg=0; sg<8; sg++) z2b += pzs[iw*576 + cl*9 + sg];
      float4 g4r = *(const float4*)&gz2_pk[cl*4];
      z2b -= coef2s[iw*4+0]*g4r.x + coef2s[iw*4+2]*g4r.y
           + coef2s[iw*4+1]*g4r.z + coef2s[iw*4+3]*g4r.w;
      float mu2 = wsum64(z2b)*(1.f/64.f);
      float df2 = z2b - mu2;
      float var2 = wsum64(df2*df2)*(1.f/64.f);
      float lnv = gr*df2*rsqrtf(var2 + 1e-6f) + br;
      out[((size_t)b*256 + n*4 + iw)*256 + h*64 + cl] = qv + lnv;
      float le0 = tok3*els[0], le1 = tok3*els[2], le2 = tok3*els[1], le3 = tok3*els[3];
      b2r -= le0*g4r.x + le1*g4r.y + le2*g4r.z + le3*g4r.w;
    }
    // --- state updates (both halves; split rows/cols by i2) ---
    float le_s0 = tok3*els[0], le_s1 = tok3*els[2], le_s2 = tok3*els[1], le_s3 = tok3*els[3];
    float lg0 = le_s0*gz14.x, lg1v = le_s1*gz14.y, lg2 = le_s2*gz14.z, lg3 = le_s3*gz14.w;
    {
      int d0 = i2*32;
      #pragma unroll 8
      for (int dd=0; dd<32; dd++){
        float4 k4 = *(const float4*)&k_pk[(d0+dd)*4];
        W1s[(d0+dd)*256 + j] -= lg0*k4.x + lg1v*k4.y + lg2*k4.z + lg3*k4.w;
      }
    }
    b1r -= lg0 + lg1v + lg2 + lg3;
    float4 xb4 = *(const float4*)&x2b_pk[j*4];    // slots
    float lx0 = le_s0*xb4.x, lx1 = le_s1*xb4.y, lx2 = le_s2*xb4.z, lx3 = le_s3*xb4.w;
    {
      int c0 = i2*32;
      #pragma unroll 8
      for (int cc=0; cc<32; cc++){
        float4 g4 = *(const float4*)&gz2_pk[(c0+cc)*4];
        W2L[j*65 + c0+cc] -= lx0*g4.x + lx1*g4.y + lx2*g4.z + lx3*g4.w;
      }
    }
    __syncthreads();                              // G
    qv = qn; kv = kn; vv = vn; elv = eln;
  }
}

// Fused head: LN(post) -> @wo -> LN(ln) -> fc1 -> fc2 -> fc3. grid 512 rows.
__global__ __launch_bounds__(256) void k_head(const float* __restrict__ hid2,
    const float* __restrict__ pg, const float* __restrict__ pb,
    const float* __restrict__ wo, const float* __restrict__ lg,
    const float* __restrict__ lb, const float* __restrict__ fcw,
    const float* __restrict__ fcb, const float* __restrict__ fc2w,
    const float* __restrict__ fc2b, const float* __restrict__ fc3w,
    const float* __restrict__ fc3b, float* __restrict__ outp){
  int row = blockIdx.x, c = threadIdx.x;
  __shared__ float t1[256];
  __shared__ float t3[256];
  __shared__ float t4[128];
  __shared__ float t5[64];
  __shared__ float rs[4];
  __shared__ float rq[4];
  int wv = c >> 6, ln = c & 63;
  float v = hid2[(size_t)row*256 + c];
  float s1 = wsum64(v), s2 = wsum64(v*v);
  if (ln == 0){ rs[wv]=s1; rq[wv]=s2; }
  __syncthreads();
  float mu = (rs[0]+rs[1]+rs[2]+rs[3])*(1.f/256.f);
  float msq = (rq[0]+rq[1]+rq[2]+rq[3])*(1.f/256.f);
  float var = msq - mu*mu;
  t1[c] = (v-mu)*rsqrtf(var + 1e-5f)*pg[c] + pb[c];
  __syncthreads();
  float a = 0.f;
  for (int k=0;k<256;k++) a += t1[k]*wo[(size_t)k*256 + c];
  float u1 = wsum64(a), u2 = wsum64(a*a);
  if (ln == 0){ rs[wv]=u1; rq[wv]=u2; }
  __syncthreads();
  mu = (rs[0]+rs[1]+rs[2]+rs[3])*(1.f/256.f);
  msq = (rq[0]+rq[1]+rq[2]+rq[3])*(1.f/256.f);
  var = msq - mu*mu;
  t3[c] = (a-mu)*rsqrtf(var + 1e-5f)*lg[c] + lb[c];
  __syncthreads();
  if (c < 128){
    float s = fcb[c];
    for (int k=0;k<256;k++) s += t3[k]*fcw[(size_t)k*128 + c];
    t4[c] = s;
  }
  __syncthreads();
  if (c < 64){
    float s = fc2b[c];
    for (int k=0;k<128;k++) s += t4[k]*fc2w[(size_t)k*64 + c];
    t5[c] = s;
  }
  __syncthreads();
  if (c < 64){
    float p = t5[c]*fc3w[c];
    p = wsum64(p);
    if (c == 0) outp[row] = p + fc3b[0];
  }
}

extern "C" void kernel_launch(void* const* d_in, const int* in_sizes, int n_in,
                              void* d_out, int out_size, void* d_ws, size_t ws_size,
                              hipStream_t stream){
  (void)in_sizes; (void)n_in; (void)out_size; (void)ws_size;
  const float* x       = (const float*)d_in[0];
  const float* s11_w   = (const float*)d_in[1];
  const float* s11_b   = (const float*)d_in[2];
  const float* bn11    = (const float*)d_in[3];
  const float* s12_w   = (const float*)d_in[4];
  const float* s12_b   = (const float*)d_in[5];
  const float* bn12    = (const float*)d_in[6];
  const float* s21_w   = (const float*)d_in[7];
  const float* s21_b   = (const float*)d_in[8];
  const float* bn21    = (const float*)d_in[9];
  const float* s22_w   = (const float*)d_in[10];
  const float* s22_b   = (const float*)d_in[11];
  const float* bn22    = (const float*)d_in[12];
  const float* s3_w    = (const float*)d_in[13];
  const float* s3_b    = (const float*)d_in[14];
  const float* bn3     = (const float*)d_in[15];
  const float* c1_w    = (const float*)d_in[16];
  const float* c1_b    = (const float*)d_in[17];
  const float* cb_w    = (const float*)d_in[18];
  const float* cb_b    = (const float*)d_in[19];
  const float* ln_g    = (const float*)d_in[20];
  const float* ln_b    = (const float*)d_in[21];
  const float* wq      = (const float*)d_in[22];
  const float* wk      = (const float*)d_in[23];
  const float* wv      = (const float*)d_in[24];
  const float* wo      = (const float*)d_in[25];
  const float* lr_w    = (const float*)d_in[26];
  const float* lr_b    = (const float*)d_in[27];
  const float* tib     = (const float*)d_in[28];
  const float* tlnw    = (const float*)d_in[29];
  const float* tlnb    = (const float*)d_in[30];
  const float* W1      = (const float*)d_in[31];
  const float* B1      = (const float*)d_in[32];
  const float* W2      = (const float*)d_in[33];
  const float* B2      = (const float*)d_in[34];
  const float* post_g  = (const float*)d_in[35];
  const float* post_b  = (const float*)d_in[36];
  const float* fc_w    = (const float*)d_in[37];
  const float* fc_b    = (const float*)d_in[38];
  const float* fc2_w   = (const float*)d_in[39];
  const float* fc2_b   = (const float*)d_in[40];
  const float* fc3_w   = (const float*)d_in[41];
  const float* fc3_b   = (const float*)d_in[42];

  float* ws = (float*)d_ws;
  float* xs   = ws;                       // 2359296
  float* xd   = ws + 2359296;             // 2359296
  float* p1   = ws + 4718592;             // 1179648 (pm)
  float* sig  = ws + 7077888;             // 32768
  float* buf0 = ws + 7110656;             // 131072
  float* buf1 = ws + 7241728;             // 131072
  float* accb = ws + 7372800;             // 131072
  float* xqb  = ws + 7634944;             // 131072
  float* xkb  = ws + 7766016;             // 131072
  float* xvb  = ws + 7897088;             // 131072
  float* eta  = ws + 8028160;             // 2048
  float* hid2 = ws + 8030208;             // 131072

  k_s11<<<1536, 192, 0, stream>>>(x, s11_w, s11_b, bn11, xs);
  k_s12<<<1536, 192, 0, stream>>>(x, s12_w, s12_b, bn12, xd);
  k_s2m<<<512, 256, 0, stream>>>(xs, xd, s21_w, s21_b, bn21,
                                 s22_w, s22_b, bn22, p1);
  k_s3<<<512, 256, 0, stream>>>(p1, s3_w, s3_b, bn3, sig);
  k_c1<<<512, 256, 0, stream>>>(sig, c1_w, c1_b, buf0);
  {
    float* cin = buf0; float* cout = buf1;
    for (int l=0; l<8; l++){
      int mode = (l == 1) ? 1 : ((l & 1) ? 2 : 0);
      k_conv1d<<<512, 256, 0, stream>>>(cin, cb_w + (size_t)l*196608,
                                        cb_b + l*256, cout, accb, mode);
      float* tmp = cin; cin = cout; cout = tmp;
    }
  }
  k_lnproj<<<512, 256, 0, stream>>>(accb, ln_g, ln_b, wq, wk, wv,
                                    lr_w, lr_b, xqb, xkb, xvb, eta);
  k_ttt<<<8, 512, 0, stream>>>(xqb, xkb, xvb, eta, tib, tlnw, tlnb,
                               W1, B1, W2, B2, hid2);
  k_head<<<512, 256, 0, stream>>>(hid2, post_g, post_b, wo, ln_g, ln_b,
                                  fc_w, fc_b, fc2_w, fc2_b, fc3_w, fc3_b,
                                  (float*)d_out);
}

// Round 11
// 1744.185 us; speedup vs baseline: 1.0114x; 1.0114x over previous
//
#include <hip/hip_runtime.h>
#include <hip/hip_bf16.h>
#include <math.h>

#define DEV __device__ __forceinline__

DEV float wsum64(float v){
  #pragma unroll
  for (int off = 32; off; off >>= 1) v += __shfl_xor(v, off, 64);
  return v;
}
DEV float geluf(float x){
  return 0.5f*x*(1.f + tanhf(0.7978845608028654f*(x + 0.044715f*x*x*x)));
}
DEV float gelu_bwdf(float x){
  float x2 = x*x;
  float t = tanhf(0.79788456f*x*(1.f + 0.044715f*x2));
  return 0.5f*x*((1.f - t*t)*(0.79788456f + 0.1070322243f*x2)) + 0.5f*(1.f + t);
}
DEV float sigmf(float x){ return 1.f/(1.f + expf(-x)); }

// ---------------------------------------------------------------------------
// Merged stem: blocks [0,1536) run s11 (conv on x), [1536,3072) run s12
// (conv on frame-diffs). Co-residency lets s11's FMA waves fill s12's
// stage-latency bubbles.
__global__ __launch_bounds__(192) void k_stem(const float* __restrict__ x,
    const float* __restrict__ w11, const float* __restrict__ b11,
    const float* __restrict__ bn11p, float* __restrict__ xs,
    const float* __restrict__ w12, const float* __restrict__ b12,
    const float* __restrict__ bn12p, float* __restrict__ xd){
  __shared__ float st[3*37*2*53];   // 11766 floats
  __shared__ float wl[49*12*8];     // 4704 (s11 uses first 1176)
  int t = threadIdx.x;
  if (blockIdx.x < 1536){
    // ---------------- s11 ----------------
    int bx = blockIdx.x;
    int bd = bx / 3, g = bx - bd*3;
    for (int e = t; e < 1176; e += 192){
      int tap = e / 24, r = e - tap*24, ci = r >> 3, c = r & 7;
      wl[e] = w11[(c*3 + ci)*49 + tap];
    }
    const float* xb = x + (size_t)bd*3*9216;
    for (int e = t; e < 3*37*102; e += 192){
      int ci = e / 3774, r2 = e - ci*3774;
      int ihl = r2 / 102, pi = r2 - ihl*102;
      int ih = ihl + 32*g - 3, iw = pi - 3;
      float v = 0.f;
      if (ih>=0 && ih<96 && iw>=0 && iw<96) v = xb[(size_t)ci*9216 + ih*96 + iw];
      st[((ci*37 + ihl)*2 + (pi&1))*53 + (pi>>1)] = v;
    }
    __syncthreads();
    int pr = t / 24, pc = t - pr*24;
    float a00[8], a01[8], a10[8], a11[8];
    #pragma unroll
    for (int c=0;c<8;c++){ a00[c]=0.f; a01[c]=0.f; a10[c]=0.f; a11[c]=0.f; }
    for (int ci=0; ci<3; ci++){
      for (int kh=0; kh<7; kh++){
        int rb0 = (ci*37 + 4*pr + kh)*106 + 2*pc;
        int rb1 = rb0 + 212;
        #pragma unroll
        for (int kw=0; kw<7; kw++){
          int off = (kw&1)*53 + (kw>>1);
          float v00 = st[rb0+off], v01 = st[rb0+off+1];
          float v10 = st[rb1+off], v11 = st[rb1+off+1];
          const float4* wp = (const float4*)&wl[((kh*7+kw)*3 + ci)*8];
          float wv[8];
          *(float4*)&wv[0] = wp[0]; *(float4*)&wv[4] = wp[1];
          #pragma unroll
          for (int c=0;c<8;c++){
            a00[c] += v00*wv[c]; a01[c] += v01*wv[c];
            a10[c] += v10*wv[c]; a11[c] += v11*wv[c];
          }
        }
      }
    }
    int pos = (g*8 + pr)*24 + pc;
    #pragma unroll
    for (int c=0;c<8;c++){
      float gg=bn11p[c], be=bn11p[8+c], m=bn11p[16+c], vv=bn11p[24+c];
      float s = gg*rsqrtf(vv + 1e-5f);
      float bi = b11[c];
      float mx = 0.f;
      mx = fmaxf(mx, (a00[c]+bi-m)*s+be);
      mx = fmaxf(mx, (a01[c]+bi-m)*s+be);
      mx = fmaxf(mx, (a10[c]+bi-m)*s+be);
      mx = fmaxf(mx, (a11[c]+bi-m)*s+be);
      xs[((size_t)bd*8 + c)*576 + pos] = mx;
    }
  } else {
    // ---------------- s12 ----------------
    int bx = blockIdx.x - 1536;
    int bd = bx / 3, g = bx - bd*3;
    int b = bd >> 8, dd = bd & 255;
    for (int e = t; e < 4704; e += 192){
      int tap = e / 96, r = e - tap*96, ci = r >> 3, c = r & 7;
      wl[e] = w12[(c*12 + ci)*49 + tap];
    }
    int fa[4], fb[4];
    fa[0] = dd>=2 ? dd-1 : 0;     fb[0] = dd>=2 ? dd-2 : 0;
    fa[1] = dd;                   fb[1] = dd>=1 ? dd-1 : 0;
    fa[2] = dd<=254 ? dd+1 : 255; fb[2] = dd;
    fa[3] = dd<=253 ? dd+2 : 255; fb[3] = dd<=254 ? dd+1 : 255;
    int pr = t / 24, pc = t - pr*24;
    float a00[8], a01[8], a10[8], a11[8];
    #pragma unroll
    for (int c=0;c<8;c++){ a00[c]=0.f; a01[c]=0.f; a10[c]=0.f; a11[c]=0.f; }
    for (int g4=0; g4<4; g4++){
      if (fa[g4] == fb[g4]) continue;   // zero diff, uniform per block
      __syncthreads();
      const float* xa = x + ((size_t)(b*256 + fa[g4]))*3*9216;
      const float* xbp= x + ((size_t)(b*256 + fb[g4]))*3*9216;
      for (int e = t; e < 3*37*102; e += 192){
        int ci = e / 3774, r2 = e - ci*3774;
        int ihl = r2 / 102, pi = r2 - ihl*102;
        int ih = ihl + 32*g - 3, iw = pi - 3;
        float v = 0.f;
        if (ih>=0 && ih<96 && iw>=0 && iw<96){
          size_t off = (size_t)ci*9216 + ih*96 + iw;
          v = xa[off] - xbp[off];
        }
        st[((ci*37 + ihl)*2 + (pi&1))*53 + (pi>>1)] = v;
      }
      __syncthreads();
      for (int ci=0; ci<3; ci++){
        int gch = g4*3 + ci;
        for (int kh=0; kh<7; kh++){
          int rb0 = (ci*37 + 4*pr + kh)*106 + 2*pc;
          int rb1 = rb0 + 212;
          #pragma unroll
          for (int kw=0; kw<7; kw++){
            int off = (kw&1)*53 + (kw>>1);
            float v00 = st[rb0+off], v01 = st[rb0+off+1];
            float v10 = st[rb1+off], v11 = st[rb1+off+1];
            const float4* wp = (const float4*)&wl[((kh*7+kw)*12 + gch)*8];
            float wv[8];
            *(float4*)&wv[0] = wp[0]; *(float4*)&wv[4] = wp[1];
            #pragma unroll
            for (int c=0;c<8;c++){
              a00[c] += v00*wv[c]; a01[c] += v01*wv[c];
              a10[c] += v10*wv[c]; a11[c] += v11*wv[c];
            }
          }
        }
      }
    }
    int pos = (g*8 + pr)*24 + pc;
    #pragma unroll
    for (int c=0;c<8;c++){
      float gg=bn12p[c], be=bn12p[8+c], m=bn12p[16+c], vv=bn12p[24+c];
      float s = gg*rsqrtf(vv + 1e-5f);
      float bi = b12[c];
      float mx = 0.f;
      mx = fmaxf(mx, (a00[c]+bi-m)*s+be);
      mx = fmaxf(mx, (a01[c]+bi-m)*s+be);
      mx = fmaxf(mx, (a10[c]+bi-m)*s+be);
      mx = fmaxf(mx, (a11[c]+bi-m)*s+be);
      xd[((size_t)bd*8 + c)*576 + pos] = mx;
    }
  }
}

// Merged s21+s22: conv1 on 0.5*(xs+xd), conv2 on xd, both 7x7 s1 p3 + BN relu pool.
// Writes pm = 0.5*(p1+p2)  [512,16,12,12]. One block per bd.
__global__ __launch_bounds__(256) void k_s2m(const float* __restrict__ xs,
    const float* __restrict__ xd,
    const float* __restrict__ w1, const float* __restrict__ b1,
    const float* __restrict__ bn1,
    const float* __restrict__ w2, const float* __restrict__ b2,
    const float* __restrict__ bn2, float* __restrict__ pm){
  __shared__ float st[8*30*33];     // 7920
  __shared__ float wl[49*8*16];     // 6272
  int bd = blockIdx.x;
  int t = threadIdx.x;
  const float* pa = xs + (size_t)bd*8*576;
  const float* pb = xd + (size_t)bd*8*576;
  float r1[16];
  for (int e = t; e < 6272; e += 256){
    int tap = e >> 7, r = e & 127, ci = r >> 4, c = r & 15;
    wl[e] = w1[(c*8 + ci)*49 + tap];
  }
  for (int e = t; e < 7920; e += 256){
    int ci = e / 990, r2 = e - ci*990;
    int r = r2 / 33, cc = r2 - r*33;
    int ih = r - 3, iw = cc - 3;
    float v = 0.f;
    if (ih>=0 && ih<24 && iw>=0 && iw<24){
      int off = ci*576 + ih*24 + iw;
      v = 0.5f*(pa[off] + pb[off]);
    }
    st[(ci*30 + r)*33 + cc] = v;
  }
  __syncthreads();
  int pr = 0, pc = 0;
  if (t < 144){ pr = t / 12; pc = t - pr*12; }
  if (t < 144){
    float a00[16], a01[16], a10[16], a11[16];
    #pragma unroll
    for (int c=0;c<16;c++){ a00[c]=0.f; a01[c]=0.f; a10[c]=0.f; a11[c]=0.f; }
    for (int ci=0; ci<8; ci++){
      for (int kh=0; kh<7; kh++){
        int rb = (ci*30 + 2*pr + kh)*33 + 2*pc;
        #pragma unroll
        for (int kw=0; kw<7; kw++){
          float v00 = st[rb+kw],    v01 = st[rb+kw+1];
          float v10 = st[rb+33+kw], v11 = st[rb+34+kw];
          const float4* wp = (const float4*)&wl[((kh*7+kw)*8 + ci)*16];
          float wv[16];
          *(float4*)&wv[0]  = wp[0]; *(float4*)&wv[4]  = wp[1];
          *(float4*)&wv[8]  = wp[2]; *(float4*)&wv[12] = wp[3];
          #pragma unroll
          for (int c=0;c<16;c++){
            a00[c] += v00*wv[c]; a01[c] += v01*wv[c];
            a10[c] += v10*wv[c]; a11[c] += v11*wv[c];
          }
        }
      }
    }
    #pragma unroll
    for (int c=0;c<16;c++){
      float gg=bn1[c], be=bn1[16+c], m=bn1[32+c], vv=bn1[48+c];
      float s = gg*rsqrtf(vv + 1e-5f);
      float bi = b1[c];
      float mx = 0.f;
      mx = fmaxf(mx, (a00[c]+bi-m)*s+be);
      mx = fmaxf(mx, (a01[c]+bi-m)*s+be);
      mx = fmaxf(mx, (a10[c]+bi-m)*s+be);
      mx = fmaxf(mx, (a11[c]+bi-m)*s+be);
      r1[c] = mx;
    }
  }
  __syncthreads();
  for (int e = t; e < 6272; e += 256){
    int tap = e >> 7, r = e & 127, ci = r >> 4, c = r & 15;
    wl[e] = w2[(c*8 + ci)*49 + tap];
  }
  for (int e = t; e < 7920; e += 256){
    int ci = e / 990, r2 = e - ci*990;
    int r = r2 / 33, cc = r2 - r*33;
    int ih = r - 3, iw = cc - 3;
    float v = 0.f;
    if (ih>=0 && ih<24 && iw>=0 && iw<24)
      v = pb[ci*576 + ih*24 + iw];
    st[(ci*30 + r)*33 + cc] = v;
  }
  __syncthreads();
  if (t < 144){
    float a00[16], a01[16], a10[16], a11[16];
    #pragma unroll
    for (int c=0;c<16;c++){ a00[c]=0.f; a01[c]=0.f; a10[c]=0.f; a11[c]=0.f; }
    for (int ci=0; ci<8; ci++){
      for (int kh=0; kh<7; kh++){
        int rb = (ci*30 + 2*pr + kh)*33 + 2*pc;
        #pragma unroll
        for (int kw=0; kw<7; kw++){
          float v00 = st[rb+kw],    v01 = st[rb+kw+1];
          float v10 = st[rb+33+kw], v11 = st[rb+34+kw];
          const float4* wp = (const float4*)&wl[((kh*7+kw)*8 + ci)*16];
          float wv[16];
          *(float4*)&wv[0]  = wp[0]; *(float4*)&wv[4]  = wp[1];
          *(float4*)&wv[8]  = wp[2]; *(float4*)&wv[12] = wp[3];
          #pragma unroll
          for (int c=0;c<16;c++){
            a00[c] += v00*wv[c]; a01[c] += v01*wv[c];
            a10[c] += v10*wv[c]; a11[c] += v11*wv[c];
          }
        }
      }
    }
    #pragma unroll
    for (int c=0;c<16;c++){
      float gg=bn2[c], be=bn2[16+c], m=bn2[32+c], vv=bn2[48+c];
      float s = gg*rsqrtf(vv + 1e-5f);
      float bi = b2[c];
      float mx = 0.f;
      mx = fmaxf(mx, (a00[c]+bi-m)*s+be);
      mx = fmaxf(mx, (a01[c]+bi-m)*s+be);
      mx = fmaxf(mx, (a10[c]+bi-m)*s+be);
      mx = fmaxf(mx, (a11[c]+bi-m)*s+be);
      pm[((size_t)bd*16 + c)*144 + pr*12 + pc] = 0.5f*(r1[c] + mx);
    }
  }
}

// s3 conv3x3 p1 + BN + attention-mask pooled signal. Input pm (pre-averaged).
__global__ __launch_bounds__(256) void k_s3(const float* __restrict__ pm,
    const float* __restrict__ w,
    const float* __restrict__ bias, const float* __restrict__ bn,
    float* __restrict__ sig){
  __shared__ float ins[16*14*14];
  __shared__ float wT[144*64];
  __shared__ float redS[64*4];
  __shared__ float redF[64*4];
  int bd = blockIdx.x;
  int t = threadIdx.x;
  for (int i = t; i < 16*196; i += 256){
    int ci = i/196, r = i - ci*196, y = r/14, xx = r - y*14;
    float v = 0.f;
    if (y>=1 && y<=12 && xx>=1 && xx<=12){
      size_t idx = ((size_t)bd*16 + ci)*144 + (y-1)*12 + (xx-1);
      v = pm[idx];
    }
    ins[i] = v;
  }
  for (int i = t; i < 9216; i += 256){
    int c = i & 63, k = i >> 6;
    wT[i] = w[c*144 + k];
  }
  __syncthreads();
  int c = t & 63, pg = t >> 6;
  float acc[36];
  #pragma unroll
  for (int pp=0;pp<36;pp++) acc[pp]=0.f;
  for (int k=0; k<144; k++){
    int ci = k/9, kk = k - ci*9, kh = kk/3, kw = kk - kh*3;
    float wv = wT[k*64 + c];
    const float* ip = &ins[ci*196];
    #pragma unroll
    for (int pp=0;pp<36;pp++){
      int y = pg*3 + pp/12, xx = pp%12;
      acc[pp] += ip[(y+kh)*14 + (xx+kw)] * wv;
    }
  }
  float g=bn[c], be=bn[64+c], m=bn[128+c], vv=bn[192+c];
  float s = g*rsqrtf(vv + 1e-5f);
  float bi = bias[c];
  float sS = 0.f, sF = 0.f;
  #pragma unroll
  for (int pp=0;pp<36;pp++){
    float f = (acc[pp] + bi - m)*s + be;
    float sg = sigmf(f);
    sS += sg; sF += f*sg;
  }
  redS[c*4+pg] = sS; redF[c*4+pg] = sF;
  __syncthreads();
  if (t < 64){
    float S = redS[t*4]+redS[t*4+1]+redS[t*4+2]+redS[t*4+3];
    float F = redF[t*4]+redF[t*4+1]+redF[t*4+2]+redF[t*4+3];
    sig[(size_t)bd*64 + t] = 0.5f*F/S;
  }
}

// c1 1x1 conv: sig[b,t,64] -> h[b,256,256] (channel-major). block=(b,o). grid 512.
__global__ __launch_bounds__(256) void k_c1(const float* __restrict__ sig,
    const float* __restrict__ w, const float* __restrict__ bias,
    float* __restrict__ h){
  int b = blockIdx.x >> 8, o = blockIdx.x & 255, tt = threadIdx.x;
  __shared__ float wl[64];
  if (tt < 64) wl[tt] = w[o*64 + tt];
  __syncthreads();
  const float4* sp = (const float4*)(sig + ((size_t)(b*256 + tt))*64);
  const float4* wp = (const float4*)wl;
  float a = bias[o];
  #pragma unroll
  for (int i=0;i<16;i++){
    float4 s4 = sp[i]; float4 w4 = wp[i];
    a += s4.x*w4.x + s4.y*w4.y + s4.z*w4.z + s4.w*w4.w;
  }
  h[((size_t)b*256 + o)*256 + tt] = fmaxf(a, 0.f);
}

// conv1d 256->256 k3 p1 + relu. 512 blocks (8 outch each) for 2 blocks/CU.
// mode: 0=none 1=acc:=out 2=acc+=out.
__global__ __launch_bounds__(256) void k_conv1d(const float* __restrict__ hin,
    const float* __restrict__ w, const float* __restrict__ bias,
    float* __restrict__ hout, float* __restrict__ accb, int mode){
  __shared__ float ins[256*34];
  __shared__ float ws[8*256*4];    // 8 outch, padded stride-4 taps (32KB)
  int bx = blockIdx.x;
  int b = bx >> 8;
  int rem = bx & 255;
  int og = rem >> 3;               // 32 groups of 8 outch
  int tg = rem & 7;
  int tid = threadIdx.x;
  int t0 = tg*32;
  for (int idx = tid; idx < 256*34; idx += 256){
    int ii = idx/34, jj = idx - ii*34;
    int tglob = t0 - 1 + jj;
    float v = 0.f;
    if (tglob >= 0 && tglob < 256) v = hin[((size_t)b*256 + ii)*256 + tglob];
    ins[idx] = v;
  }
  for (int idx = tid; idx < 6144; idx += 256){
    int q = idx/3;
    ws[q*4 + (idx - q*3)] = w[(size_t)og*6144 + idx];
  }
  __syncthreads();
  int ol = tid >> 5, tl = tid & 31;
  int o = og*8 + ol;
  float a1 = bias[o];
  const float4* w1q = (const float4*)(ws + (size_t)ol*1024);
  for (int i=0;i<256;i++){
    float v0 = ins[i*34 + tl];
    float v1 = ins[i*34 + tl + 1];
    float v2 = ins[i*34 + tl + 2];
    float4 wa = w1q[i];
    a1 += wa.x*v0 + wa.y*v1 + wa.z*v2;
  }
  a1 = fmaxf(a1, 0.f);
  size_t i1 = ((size_t)b*256 + o)*256 + t0 + tl;
  hout[i1] = a1;
  if (mode == 1) accb[i1] = a1;
  else if (mode == 2) accb[i1] += a1;
}

// Fused LN + projections + eta. One block per (b,t) row. grid 512.
__global__ __launch_bounds__(256) void k_lnproj(const float* __restrict__ acc,
    const float* __restrict__ g, const float* __restrict__ be,
    const float* __restrict__ wqp, const float* __restrict__ wkp,
    const float* __restrict__ wvp, const float* __restrict__ lrw,
    const float* __restrict__ lrb, float* __restrict__ xq,
    float* __restrict__ xk, float* __restrict__ xv,
    float* __restrict__ etalr){
  int b = blockIdx.x >> 8, tt = blockIdx.x & 255, c = threadIdx.x;
  __shared__ float hrow[256];
  __shared__ float rs[4];
  __shared__ float rq[4];
  __shared__ float epb[4][4];   // [wave][head]
  int wv_ = c >> 6, ln = c & 63;
  float v = acc[((size_t)b*256 + c)*256 + tt];
  float s1 = wsum64(v), s2 = wsum64(v*v);
  if (ln == 0){ rs[wv_]=s1; rq[wv_]=s2; }
  __syncthreads();
  float mu = (rs[0]+rs[1]+rs[2]+rs[3])*(1.f/256.f);
  float msq = (rq[0]+rq[1]+rq[2]+rq[3])*(1.f/256.f);
  float var = msq - mu*mu;
  float hv = (v-mu)*rsqrtf(var + 1e-5f)*g[c] + be[c];
  hrow[c] = hv;
  __syncthreads();
  {
    float p0 = hv*lrw[c];
    float p1 = hv*lrw[256 + c];
    float p2 = hv*lrw[512 + c];
    float p3 = hv*lrw[768 + c];
    p0 = wsum64(p0); p1 = wsum64(p1); p2 = wsum64(p2); p3 = wsum64(p3);
    if (ln == 0){ epb[wv_][0]=p0; epb[wv_][1]=p1; epb[wv_][2]=p2; epb[wv_][3]=p3; }
  }
  float aq = 0.f, ak = 0.f, av = 0.f;
  for (int k=0;k<256;k++){
    float hk = hrow[k];
    aq += hk*wqp[(size_t)k*256 + c];
    ak += hk*wkp[(size_t)k*256 + c];
    av += hk*wvp[(size_t)k*256 + c];
  }
  size_t row = (size_t)blockIdx.x;
  xq[row*256 + c] = aq;
  xk[row*256 + c] = ak;
  xv[row*256 + c] = av;
  __syncthreads();
  if (c < 4){
    float a = lrb[c] + epb[0][c] + epb[1][c] + epb[2][c] + epb[3][c];
    etalr[((size_t)(b*4 + c))*256 + tt] = 0.1f*sigmf(a)*(1.f/64.f);
  }
}

// TTT-MLP scan, 512 threads. Role/K-split: Z1 producer split (h0: z1 all
// rows; h1: qW1 all rows, qw exchange via qwx), gZ1 split-K halves with
// exchange aliased on pzs. W1/b1 updates moved to phase D for balance.
__global__ __launch_bounds__(512) void k_ttt(
    const float* __restrict__ xq, const float* __restrict__ xk,
    const float* __restrict__ xv, const float* __restrict__ etalr,
    const float* __restrict__ tib, const float* __restrict__ lnw,
    const float* __restrict__ lnb, const float* __restrict__ W1g,
    const float* __restrict__ B1g, const float* __restrict__ W2g,
    const float* __restrict__ B2g, float* __restrict__ out){
  __shared__ float W1s[64*256];                 // [d][j]
  __shared__ float W2L[256*65];                 // [r][c] pitch 65
  __shared__ __align__(16) float k_pk[256];     // [d=64][slot4]
  __shared__ __align__(16) float q_pk[256];
  __shared__ __align__(16) float v_pk[256];
  __shared__ __align__(16) float x2_pk[1024];   // [j=256][slot4]
  __shared__ __align__(16) float x2b_pk[1024];
  __shared__ __align__(16) float gb_pk[1024];   // gelu_bwd(Z1) factors
  __shared__ __align__(16) float gz2_pk[256];   // [cl=64][slot4]
  __shared__ __align__(16) float pzs[4*576];    // partials; aliased as gzx
  __shared__ float qwx[512];                    // qw slots 0,1 exchange
  __shared__ float a2w[64];
  __shared__ float coefs[16];                   // row-indexed [i*4+r]
  __shared__ float coef2s[16];
  __shared__ float els[4];
  __shared__ float toks_s[4];

  int b = blockIdx.x >> 2, h = blockIdx.x & 3;
  int tid = threadIdx.x;
  int j = tid & 255;
  int i2 = tid >> 8;
  int iw = j >> 6, cl = j & 63;
  int ps_iw = ((iw & 1) << 1) | (iw >> 1);      // pslot(iw)

  const float* W1b = W1g + (size_t)h*16384;
  const float* W2b = W2g + (size_t)h*16384;
  for (int i = tid; i < 16384; i += 512) W1s[i] = W1b[i];
  for (int i = tid; i < 16384; i += 512){
    int r = i >> 6, c = i & 63;
    W2L[r*65 + c] = W2b[i];
  }
  float b1r = B1g[h*256 + j];
  float b2r = B2g[h*64 + cl];
  float gr = lnw[h*64 + cl], br = lnb[h*64 + cl];
  if (tid < 4) toks_s[tid] = fmaxf(1.f/(float)(tid+1) + tib[tid], 0.f);
  __syncthreads();
  float tok3 = toks_s[3];
  float tik = toks_s[iw];

  const float* xqp = xq + (size_t)b*65536 + h*64;
  const float* xkp = xk + (size_t)b*65536 + h*64;
  const float* xvp = xv + (size_t)b*65536 + h*64;
  const float* ep  = etalr + (size_t)(b*4 + h)*256;

  float qv=0.f, kv=0.f, vv=0.f, elv=0.f;
  if (i2 == 0){ qv = xqp[(size_t)iw*256 + cl]; kv = xkp[(size_t)iw*256 + cl]; }
  else        { vv = xvp[(size_t)iw*256 + cl]; }
  if (tid < 4) elv = ep[tid];

  for (int n=0; n<64; n++){
    // --- phase 0: stage ---
    if (i2 == 0){ k_pk[cl*4 + ps_iw] = kv; q_pk[cl*4 + ps_iw] = qv; }
    else        { v_pk[cl*4 + ps_iw] = vv; }
    if (tid < 4) els[tid] = elv;
    __syncthreads();                              // A
    // --- A1 (half0 waves; wave iw = row iw) ---
    if (i2 == 0){
      float4 k4a = *(const float4*)&k_pk[cl*4];   // slots = rows 0,2,1,3
      float a0 = wsum64(qv*k4a.x);
      float a1 = wsum64(qv*k4a.y);
      float a2 = wsum64(qv*k4a.z);
      float a3 = wsum64(qv*k4a.w);
      if (cl == 0){
        coefs[iw*4+0] = tik*els[0]*(a0+1.f);
        coefs[iw*4+2] = (iw>=2) ? tik*els[2]*(a1+1.f) : 0.f;
        coefs[iw*4+1] = (iw>=1) ? tik*els[1]*(a2+1.f) : 0.f;
        coefs[iw*4+3] = (iw>=3) ? tik*els[3]*(a3+1.f) : 0.f;
      }
    }
    // --- Z1 producer split: h0 -> z1 (4 slots), h1 -> qw (4 slots) ---
    float acc0=b1r, acc1=b1r, acc2=b1r, acc3=b1r;
    {
      const float* src = (i2 == 0) ? k_pk : q_pk;
      #pragma unroll 8
      for (int d=0; d<64; d++){
        float4 s4 = *(const float4*)&src[d*4];
        float w = W1s[d*256 + j];
        acc0 += s4.x*w; acc1 += s4.y*w; acc2 += s4.z*w; acc3 += s4.w*w;
      }
    }
    float x2o0=0.f, x2o1=0.f, qw0r=0.f, qw1r=0.f;
    if (i2 == 0){
      float g0 = geluf(acc0), g1 = geluf(acc1), g2 = geluf(acc2), g3 = geluf(acc3);
      { float4 t4; t4.x=g0; t4.y=g1; t4.z=g2; t4.w=g3;
        *(float4*)&x2_pk[j*4] = t4; }
      { float4 t4; t4.x=gelu_bwdf(acc0); t4.y=gelu_bwdf(acc1);
        t4.z=gelu_bwdf(acc2); t4.w=gelu_bwdf(acc3);
        *(float4*)&gb_pk[j*4] = t4; }
      x2o0 = g0; x2o1 = g1;                       // own rows 0,2 (slots 0,1)
    } else {
      qwx[j*2]   = acc0;                          // qw slot0 (row0) for h0
      qwx[j*2+1] = acc1;                          // qw slot1 (row2) for h0
      qw0r = acc2; qw1r = acc3;                   // own rows 1,3 (slots 2,3)
    }
    __syncthreads();                              // B
    if (i2 == 0){ qw0r = qwx[j*2]; qw1r = qwx[j*2+1]; }
    else { float2 xo = *(const float2*)&x2_pk[j*4+2]; x2o0 = xo.x; x2o1 = xo.y; }
    // --- prefetch next step ---
    float qn=0.f, kn=0.f, vn=0.f, eln=0.f;
    if (n < 63){
      int l2 = (n+1)*4 + iw;
      if (i2 == 0){ qn = xqp[(size_t)l2*256 + cl]; kn = xkp[(size_t)l2*256 + cl]; }
      else        { vn = xvp[(size_t)l2*256 + cl]; }
      if (tid < 4) eln = ep[(n+1)*4 + tid];
    }
    // --- Z2 split-K: seg = iw*2+i2, 32 d's, all 4 rows via slots ---
    {
      int d0 = (iw*2 + i2)*32;
      int seg = iw*2 + i2;
      float p0=0.f,p1=0.f,p2=0.f,p3=0.f;
      #pragma unroll 8
      for (int dd=0; dd<32; dd++){
        float4 x4 = *(const float4*)&x2_pk[(d0+dd)*4];
        float w = W2L[(d0+dd)*65 + cl];
        p0 += x4.x*w; p1 += x4.y*w; p2 += x4.z*w; p3 += x4.w*w;
      }
      pzs[0*576 + cl*9 + seg] = p0;   // slot0 = row0
      pzs[2*576 + cl*9 + seg] = p1;   // slot1 = row2
      pzs[1*576 + cl*9 + seg] = p2;   // slot2 = row1
      pzs[3*576 + cl*9 + seg] = p3;   // slot3 = row3
    }
    __syncthreads();                              // C
    // --- fused LN-L2 backward (half0 wave iw = row iw) ---
    if (i2 == 0){
      float z2 = b2r;
      #pragma unroll
      for (int sg=0; sg<8; sg++) z2 += pzs[iw*576 + cl*9 + sg];
      float mu = wsum64(z2)*(1.f/64.f);
      float df = z2 - mu;
      float var = wsum64(df*df)*(1.f/64.f);
      float stdv = sqrtf(var + 1e-6f);
      float xhat = df/stdv;
      float tgt = v_pk[cl*4 + ps_iw] - kv;
      float gxh = (gr*xhat + br - tgt)*gr;
      float sg1 = wsum64(gxh);
      float sg2 = wsum64(gxh*xhat);
      float gz2 = (64.f*gxh - sg1 - xhat*sg2)*(1.f/(64.f*stdv));
      gz2_pk[cl*4 + ps_iw] = gz2;
    }
    __syncthreads();                              // D0
    // --- gZ1 split-K: half i2 covers c in [i2*32, i2*32+32) ---
    float gd0=0.f, gd1=0.f, gd2=0.f, gd3=0.f;
    {
      int cb = i2*32;
      #pragma unroll 8
      for (int cc=0; cc<32; cc++){
        float4 g4 = *(const float4*)&gz2_pk[(cb+cc)*4];
        float w = W2L[j*65 + cb + cc];
        gd0 += g4.x*w; gd1 += g4.y*w; gd2 += g4.z*w; gd3 += g4.w*w;
      }
      float4 t4; t4.x=gd0; t4.y=gd1; t4.z=gd2; t4.w=gd3;
      *(float4*)&pzs[i2*1024 + j*4] = t4;         // gzx alias on pzs
    }
    __syncthreads();                              // D1
    {
      float4 po = *(const float4*)&pzs[(1-i2)*1024 + j*4];
      gd0 += po.x; gd1 += po.y; gd2 += po.z; gd3 += po.w;
    }
    float4 gb4 = *(const float4*)&gb_pk[j*4];
    float4 gz14;
    gz14.x = gd0*gb4.x; gz14.y = gd1*gb4.y;
    gz14.z = gd2*gb4.z; gz14.w = gd3*gb4.w;       // slots 0,2,1,3
    // --- Z1b/X2b rows (i2, i2+2) ---
    int R0 = i2, R1 = i2 + 2;
    float zb0 = qw0r - (coefs[R0*4+0]*gz14.x + coefs[R0*4+2]*gz14.y
                      + coefs[R0*4+1]*gz14.z + coefs[R0*4+3]*gz14.w);
    float zb1 = qw1r - (coefs[R1*4+0]*gz14.x + coefs[R1*4+2]*gz14.y
                      + coefs[R1*4+1]*gz14.z + coefs[R1*4+3]*gz14.w);
    float xb0 = geluf(zb0), xb1 = geluf(zb1);
    { float2 t; t.x=xb0; t.y=xb1; *(float2*)&x2b_pk[j*4 + i2*2] = t; }
    // --- W1 + b1 update (moved here; W1s next read at Z1 after barrier G) ---
    float le_s0 = tok3*els[0], le_s1 = tok3*els[2], le_s2 = tok3*els[1], le_s3 = tok3*els[3];
    {
      float lg0 = le_s0*gz14.x, lg1v = le_s1*gz14.y, lg2 = le_s2*gz14.z, lg3 = le_s3*gz14.w;
      int d0 = i2*32;
      #pragma unroll 8
      for (int dd=0; dd<32; dd++){
        float4 k4 = *(const float4*)&k_pk[(d0+dd)*4];
        W1s[(d0+dd)*256 + j] -= lg0*k4.x + lg1v*k4.y + lg2*k4.z + lg3*k4.w;
      }
      b1r -= lg0 + lg1v + lg2 + lg3;
    }
    // --- A2 masked products, split 4/6 across halves ---
    if (i2 == 0){
      float xo1 = x2_pk[j*4 + 2];                 // row1
      float s00 = wsum64(xb0*x2o0);               // (0,0)
      float s20 = wsum64(xb1*x2o0);               // (2,0)
      float s22 = wsum64(xb1*x2o1);               // (2,2)
      float s21 = wsum64(xb1*xo1);                // (2,1)
      if (cl == 0){
        a2w[iw*16+0]  = s00;
        a2w[iw*16+8]  = s20;
        a2w[iw*16+10] = s22;
        a2w[iw*16+9]  = s21;
      }
    } else {
      float2 xo02 = *(const float2*)&x2_pk[j*4];  // rows 0,2
      float s11 = wsum64(xb0*x2o0);               // (1,1)
      float s10 = wsum64(xb0*xo02.x);             // (1,0)
      float s31 = wsum64(xb1*x2o0);               // (3,1)
      float s33 = wsum64(xb1*x2o1);               // (3,3)
      float s30 = wsum64(xb1*xo02.x);             // (3,0)
      float s32 = wsum64(xb1*xo02.y);             // (3,2)
      if (cl == 0){
        a2w[iw*16+5]  = s11;
        a2w[iw*16+4]  = s10;
        a2w[iw*16+13] = s31;
        a2w[iw*16+15] = s33;
        a2w[iw*16+12] = s30;
        a2w[iw*16+14] = s32;
      }
    }
    __syncthreads();                              // E
    if (tid < 16){
      int ii = tid >> 2, rr = tid & 3;
      float s = a2w[tid] + a2w[16+tid] + a2w[32+tid] + a2w[48+tid];
      coef2s[tid] = (rr <= ii) ? toks_s[ii]*els[rr]*(s + 1.f) : 0.f;
    }
    // --- Z2b split-K ---
    {
      int d0 = (iw*2 + i2)*32;
      int seg = iw*2 + i2;
      float p0=0.f,p1=0.f,p2=0.f,p3=0.f;
      #pragma unroll 8
      for (int dd=0; dd<32; dd++){
        float4 x4 = *(const float4*)&x2b_pk[(d0+dd)*4];
        float w = W2L[(d0+dd)*65 + cl];
        p0 += x4.x*w; p1 += x4.y*w; p2 += x4.z*w; p3 += x4.w*w;
      }
      pzs[0*576 + cl*9 + seg] = p0;
      pzs[2*576 + cl*9 + seg] = p1;
      pzs[1*576 + cl*9 + seg] = p2;
      pzs[3*576 + cl*9 + seg] = p3;
    }
    __syncthreads();                              // F
    // --- ln_fwd + output (half0) ---
    if (i2 == 0){
      float z2b = b2r;
      #pragma unroll
      for (int sg=0; sg<8; sg++) z2b += pzs[iw*576 + cl*9 + sg];
      float4 g4r = *(const float4*)&gz2_pk[cl*4];
      z2b -= coef2s[iw*4+0]*g4r.x + coef2s[iw*4+2]*g4r.y
           + coef2s[iw*4+1]*g4r.z + coef2s[iw*4+3]*g4r.w;
      float mu2 = wsum64(z2b)*(1.f/64.f);
      float df2 = z2b - mu2;
      float var2 = wsum64(df2*df2)*(1.f/64.f);
      float lnv = gr*df2*rsqrtf(var2 + 1e-6f) + br;
      out[((size_t)b*256 + n*4 + iw)*256 + h*64 + cl] = qv + lnv;
    }
    // --- W2 + b2 update ---
    float4 xb4 = *(const float4*)&x2b_pk[j*4];    // slots
    float lx0 = le_s0*xb4.x, lx1 = le_s1*xb4.y, lx2 = le_s2*xb4.z, lx3 = le_s3*xb4.w;
    {
      int c0 = i2*32;
      #pragma unroll 8
      for (int cc=0; cc<32; cc++){
        float4 g4 = *(const float4*)&gz2_pk[(c0+cc)*4];
        W2L[j*65 + c0+cc] -= lx0*g4.x + lx1*g4.y + lx2*g4.z + lx3*g4.w;
      }
    }
    {
      float4 g4r = *(const float4*)&gz2_pk[cl*4];
      b2r -= le_s0*g4r.x + le_s1*g4r.y + le_s2*g4r.z + le_s3*g4r.w;
    }
    __syncthreads();                              // G
    qv = qn; kv = kn; vv = vn; elv = eln;
  }
}

// Fused head: LN(post) -> @wo -> LN(ln) -> fc1 -> fc2 -> fc3. grid 512 rows.
__global__ __launch_bounds__(256) void k_head(const float* __restrict__ hid2,
    const float* __restrict__ pg, const float* __restrict__ pb,
    const float* __restrict__ wo, const float* __restrict__ lg,
    const float* __restrict__ lb, const float* __restrict__ fcw,
    const float* __restrict__ fcb, const float* __restrict__ fc2w,
    const float* __restrict__ fc2b, const float* __restrict__ fc3w,
    const float* __restrict__ fc3b, float* __restrict__ outp){
  int row = blockIdx.x, c = threadIdx.x;
  __shared__ float t1[256];
  __shared__ float t3[256];
  __shared__ float t4[128];
  __shared__ float t5[64];
  __shared__ float rs[4];
  __shared__ float rq[4];
  int wv = c >> 6, ln = c & 63;
  float v = hid2[(size_t)row*256 + c];
  float s1 = wsum64(v), s2 = wsum64(v*v);
  if (ln == 0){ rs[wv]=s1; rq[wv]=s2; }
  __syncthreads();
  float mu = (rs[0]+rs[1]+rs[2]+rs[3])*(1.f/256.f);
  float msq = (rq[0]+rq[1]+rq[2]+rq[3])*(1.f/256.f);
  float var = msq - mu*mu;
  t1[c] = (v-mu)*rsqrtf(var + 1e-5f)*pg[c] + pb[c];
  __syncthreads();
  float a = 0.f;
  for (int k=0;k<256;k++) a += t1[k]*wo[(size_t)k*256 + c];
  float u1 = wsum64(a), u2 = wsum64(a*a);
  if (ln == 0){ rs[wv]=u1; rq[wv]=u2; }
  __syncthreads();
  mu = (rs[0]+rs[1]+rs[2]+rs[3])*(1.f/256.f);
  msq = (rq[0]+rq[1]+rq[2]+rq[3])*(1.f/256.f);
  var = msq - mu*mu;
  t3[c] = (a-mu)*rsqrtf(var + 1e-5f)*lg[c] + lb[c];
  __syncthreads();
  if (c < 128){
    float s = fcb[c];
    for (int k=0;k<256;k++) s += t3[k]*fcw[(size_t)k*128 + c];
    t4[c] = s;
  }
  __syncthreads();
  if (c < 64){
    float s = fc2b[c];
    for (int k=0;k<128;k++) s += t4[k]*fc2w[(size_t)k*64 + c];
    t5[c] = s;
  }
  __syncthreads();
  if (c < 64){
    float p = t5[c]*fc3w[c];
    p = wsum64(p);
    if (c == 0) outp[row] = p + fc3b[0];
  }
}

extern "C" void kernel_launch(void* const* d_in, const int* in_sizes, int n_in,
                              void* d_out, int out_size, void* d_ws, size_t ws_size,
                              hipStream_t stream){
  (void)in_sizes; (void)n_in; (void)out_size; (void)ws_size;
  const float* x       = (const float*)d_in[0];
  const float* s11_w   = (const float*)d_in[1];
  const float* s11_b   = (const float*)d_in[2];
  const float* bn11    = (const float*)d_in[3];
  const float* s12_w   = (const float*)d_in[4];
  const float* s12_b   = (const float*)d_in[5];
  const float* bn12    = (const float*)d_in[6];
  const float* s21_w   = (const float*)d_in[7];
  const float* s21_b   = (const float*)d_in[8];
  const float* bn21    = (const float*)d_in[9];
  const float* s22_w   = (const float*)d_in[10];
  const float* s22_b   = (const float*)d_in[11];
  const float* bn22    = (const float*)d_in[12];
  const float* s3_w    = (const float*)d_in[13];
  const float* s3_b    = (const float*)d_in[14];
  const float* bn3     = (const float*)d_in[15];
  const float* c1_w    = (const float*)d_in[16];
  const float* c1_b    = (const float*)d_in[17];
  const float* cb_w    = (const float*)d_in[18];
  const float* cb_b    = (const float*)d_in[19];
  const float* ln_g    = (const float*)d_in[20];
  const float* ln_b    = (const float*)d_in[21];
  const float* wq      = (const float*)d_in[22];
  const float* wk      = (const float*)d_in[23];
  const float* wv      = (const float*)d_in[24];
  const float* wo      = (const float*)d_in[25];
  const float* lr_w    = (const float*)d_in[26];
  const float* lr_b    = (const float*)d_in[27];
  const float* tib     = (const float*)d_in[28];
  const float* tlnw    = (const float*)d_in[29];
  const float* tlnb    = (const float*)d_in[30];
  const float* W1      = (const float*)d_in[31];
  const float* B1      = (const float*)d_in[32];
  const float* W2      = (const float*)d_in[33];
  const float* B2      = (const float*)d_in[34];
  const float* post_g  = (const float*)d_in[35];
  const float* post_b  = (const float*)d_in[36];
  const float* fc_w    = (const float*)d_in[37];
  const float* fc_b    = (const float*)d_in[38];
  const float* fc2_w   = (const float*)d_in[39];
  const float* fc2_b   = (const float*)d_in[40];
  const float* fc3_w   = (const float*)d_in[41];
  const float* fc3_b   = (const float*)d_in[42];

  float* ws = (float*)d_ws;
  float* xs   = ws;                       // 2359296
  float* xd   = ws + 2359296;             // 2359296
  float* p1   = ws + 4718592;             // 1179648 (pm)
  float* sig  = ws + 7077888;             // 32768
  float* buf0 = ws + 7110656;             // 131072
  float* buf1 = ws + 7241728;             // 131072
  float* accb = ws + 7372800;             // 131072
  float* xqb  = ws + 7634944;             // 131072
  float* xkb  = ws + 7766016;             // 131072
  float* xvb  = ws + 7897088;             // 131072
  float* eta  = ws + 8028160;             // 2048
  float* hid2 = ws + 8030208;             // 131072

  k_stem<<<3072, 192, 0, stream>>>(x, s11_w, s11_b, bn11, xs,
                                   s12_w, s12_b, bn12, xd);
  k_s2m<<<512, 256, 0, stream>>>(xs, xd, s21_w, s21_b, bn21,
                                 s22_w, s22_b, bn22, p1);
  k_s3<<<512, 256, 0, stream>>>(p1, s3_w, s3_b, bn3, sig);
  k_c1<<<512, 256, 0, stream>>>(sig, c1_w, c1_b, buf0);
  {
    float* cin = buf0; float* cout = buf1;
    for (int l=0; l<8; l++){
      int mode = (l == 1) ? 1 : ((l & 1) ? 2 : 0);
      k_conv1d<<<512, 256, 0, stream>>>(cin, cb_w + (size_t)l*196608,
                                        cb_b + l*256, cout, accb, mode);
      float* tmp = cin; cin = cout; cout = tmp;
    }
  }
  k_lnproj<<<512, 256, 0, stream>>>(accb, ln_g, ln_b, wq, wk, wv,
                                    lr_w, lr_b, xqb, xkb, xvb, eta);
  k_ttt<<<8, 512, 0, stream>>>(xqb, xkb, xvb, eta, tib, tlnw, tlnb,
                               W1, B1, W2, B2, hid2);
  k_head<<<512, 256, 0, stream>>>(hid2, post_g, post_b, wo, ln_g, ln_b,
                                  fc_w, fc_b, fc2_w, fc2_b, fc3_w, fc3_b,
                                  (float*)d_out);
}

// Round 12
// 1693.746 us; speedup vs baseline: 1.0416x; 1.0298x over previous
//
#include <hip/hip_runtime.h>
#include <hip/hip_bf16.h>
#include <math.h>

#define DEV __device__ __forceinline__

DEV float wsum64(float v){
  #pragma unroll
  for (int off = 32; off; off >>= 1) v += __shfl_xor(v, off, 64);
  return v;
}
DEV float geluf(float x){
  return 0.5f*x*(1.f + tanhf(0.7978845608028654f*(x + 0.044715f*x*x*x)));
}
DEV float gelu_bwdf(float x){
  float x2 = x*x;
  float t = tanhf(0.79788456f*x*(1.f + 0.044715f*x2));
  return 0.5f*x*((1.f - t*t)*(0.79788456f + 0.1070322243f*x2)) + 0.5f*(1.f + t);
}
DEV float sigmf(float x){ return 1.f/(1.f + expf(-x)); }

// ---------------------------------------------------------------------------
// Merged stem: blocks [0,1536) run s11 (conv on x), [1536,3072) run s12
// (conv on frame-diffs).
__global__ __launch_bounds__(192) void k_stem(const float* __restrict__ x,
    const float* __restrict__ w11, const float* __restrict__ b11,
    const float* __restrict__ bn11p, float* __restrict__ xs,
    const float* __restrict__ w12, const float* __restrict__ b12,
    const float* __restrict__ bn12p, float* __restrict__ xd){
  __shared__ float st[3*37*2*53];   // 11766 floats
  __shared__ float wl[49*12*8];     // 4704 (s11 uses first 1176)
  int t = threadIdx.x;
  if (blockIdx.x < 1536){
    // ---------------- s11 ----------------
    int bx = blockIdx.x;
    int bd = bx / 3, g = bx - bd*3;
    for (int e = t; e < 1176; e += 192){
      int tap = e / 24, r = e - tap*24, ci = r >> 3, c = r & 7;
      wl[e] = w11[(c*3 + ci)*49 + tap];
    }
    const float* xb = x + (size_t)bd*3*9216;
    for (int e = t; e < 3*37*102; e += 192){
      int ci = e / 3774, r2 = e - ci*3774;
      int ihl = r2 / 102, pi = r2 - ihl*102;
      int ih = ihl + 32*g - 3, iw = pi - 3;
      float v = 0.f;
      if (ih>=0 && ih<96 && iw>=0 && iw<96) v = xb[(size_t)ci*9216 + ih*96 + iw];
      st[((ci*37 + ihl)*2 + (pi&1))*53 + (pi>>1)] = v;
    }
    __syncthreads();
    int pr = t / 24, pc = t - pr*24;
    float a00[8], a01[8], a10[8], a11[8];
    #pragma unroll
    for (int c=0;c<8;c++){ a00[c]=0.f; a01[c]=0.f; a10[c]=0.f; a11[c]=0.f; }
    for (int ci=0; ci<3; ci++){
      for (int kh=0; kh<7; kh++){
        int rb0 = (ci*37 + 4*pr + kh)*106 + 2*pc;
        int rb1 = rb0 + 212;
        #pragma unroll
        for (int kw=0; kw<7; kw++){
          int off = (kw&1)*53 + (kw>>1);
          float v00 = st[rb0+off], v01 = st[rb0+off+1];
          float v10 = st[rb1+off], v11 = st[rb1+off+1];
          const float4* wp = (const float4*)&wl[((kh*7+kw)*3 + ci)*8];
          float wv[8];
          *(float4*)&wv[0] = wp[0]; *(float4*)&wv[4] = wp[1];
          #pragma unroll
          for (int c=0;c<8;c++){
            a00[c] += v00*wv[c]; a01[c] += v01*wv[c];
            a10[c] += v10*wv[c]; a11[c] += v11*wv[c];
          }
        }
      }
    }
    int pos = (g*8 + pr)*24 + pc;
    #pragma unroll
    for (int c=0;c<8;c++){
      float gg=bn11p[c], be=bn11p[8+c], m=bn11p[16+c], vv=bn11p[24+c];
      float s = gg*rsqrtf(vv + 1e-5f);
      float bi = b11[c];
      float mx = 0.f;
      mx = fmaxf(mx, (a00[c]+bi-m)*s+be);
      mx = fmaxf(mx, (a01[c]+bi-m)*s+be);
      mx = fmaxf(mx, (a10[c]+bi-m)*s+be);
      mx = fmaxf(mx, (a11[c]+bi-m)*s+be);
      xs[((size_t)bd*8 + c)*576 + pos] = mx;
    }
  } else {
    // ---------------- s12 ----------------
    int bx = blockIdx.x - 1536;
    int bd = bx / 3, g = bx - bd*3;
    int b = bd >> 8, dd = bd & 255;
    for (int e = t; e < 4704; e += 192){
      int tap = e / 96, r = e - tap*96, ci = r >> 3, c = r & 7;
      wl[e] = w12[(c*12 + ci)*49 + tap];
    }
    int fa[4], fb[4];
    fa[0] = dd>=2 ? dd-1 : 0;     fb[0] = dd>=2 ? dd-2 : 0;
    fa[1] = dd;                   fb[1] = dd>=1 ? dd-1 : 0;
    fa[2] = dd<=254 ? dd+1 : 255; fb[2] = dd;
    fa[3] = dd<=253 ? dd+2 : 255; fb[3] = dd<=254 ? dd+1 : 255;
    int pr = t / 24, pc = t - pr*24;
    float a00[8], a01[8], a10[8], a11[8];
    #pragma unroll
    for (int c=0;c<8;c++){ a00[c]=0.f; a01[c]=0.f; a10[c]=0.f; a11[c]=0.f; }
    for (int g4=0; g4<4; g4++){
      if (fa[g4] == fb[g4]) continue;   // zero diff, uniform per block
      __syncthreads();
      const float* xa = x + ((size_t)(b*256 + fa[g4]))*3*9216;
      const float* xbp= x + ((size_t)(b*256 + fb[g4]))*3*9216;
      for (int e = t; e < 3*37*102; e += 192){
        int ci = e / 3774, r2 = e - ci*3774;
        int ihl = r2 / 102, pi = r2 - ihl*102;
        int ih = ihl + 32*g - 3, iw = pi - 3;
        float v = 0.f;
        if (ih>=0 && ih<96 && iw>=0 && iw<96){
          size_t off = (size_t)ci*9216 + ih*96 + iw;
          v = xa[off] - xbp[off];
        }
        st[((ci*37 + ihl)*2 + (pi&1))*53 + (pi>>1)] = v;
      }
      __syncthreads();
      for (int ci=0; ci<3; ci++){
        int gch = g4*3 + ci;
        for (int kh=0; kh<7; kh++){
          int rb0 = (ci*37 + 4*pr + kh)*106 + 2*pc;
          int rb1 = rb0 + 212;
          #pragma unroll
          for (int kw=0; kw<7; kw++){
            int off = (kw&1)*53 + (kw>>1);
            float v00 = st[rb0+off], v01 = st[rb0+off+1];
            float v10 = st[rb1+off], v11 = st[rb1+off+1];
            const float4* wp = (const float4*)&wl[((kh*7+kw)*12 + gch)*8];
            float wv[8];
            *(float4*)&wv[0] = wp[0]; *(float4*)&wv[4] = wp[1];
            #pragma unroll
            for (int c=0;c<8;c++){
              a00[c] += v00*wv[c]; a01[c] += v01*wv[c];
              a10[c] += v10*wv[c]; a11[c] += v11*wv[c];
            }
          }
        }
      }
    }
    int pos = (g*8 + pr)*24 + pc;
    #pragma unroll
    for (int c=0;c<8;c++){
      float gg=bn12p[c], be=bn12p[8+c], m=bn12p[16+c], vv=bn12p[24+c];
      float s = gg*rsqrtf(vv + 1e-5f);
      float bi = b12[c];
      float mx = 0.f;
      mx = fmaxf(mx, (a00[c]+bi-m)*s+be);
      mx = fmaxf(mx, (a01[c]+bi-m)*s+be);
      mx = fmaxf(mx, (a10[c]+bi-m)*s+be);
      mx = fmaxf(mx, (a11[c]+bi-m)*s+be);
      xd[((size_t)bd*8 + c)*576 + pos] = mx;
    }
  }
}

// Merged s21+s22, 576 threads = 144 pos x 4 channel-quads (all active).
// conv1 on 0.5*(xs+xd), conv2 on xd; writes pm = 0.5*(p1+p2). One block/bd.
__global__ __launch_bounds__(576) void k_s2m(const float* __restrict__ xs,
    const float* __restrict__ xd,
    const float* __restrict__ w1, const float* __restrict__ b1,
    const float* __restrict__ bn1,
    const float* __restrict__ w2, const float* __restrict__ b2,
    const float* __restrict__ bn2, float* __restrict__ pm){
  __shared__ float st[8*30*33];     // 7920
  __shared__ float wl[49*8*16];     // 6272
  int bd = blockIdx.x;
  int t = threadIdx.x;
  int quad = t / 144;               // 0..3 -> channels quad*4..quad*4+3
  int pos = t - quad*144;
  int pr = pos / 12, pc = pos - pr*12;
  const float* pa = xs + (size_t)bd*8*576;
  const float* pb = xd + (size_t)bd*8*576;
  float r1[4];
  // ---- phase 1: conv s21 on 0.5*(xs+xd) ----
  for (int e = t; e < 6272; e += 576){
    int tap = e >> 7, r = e & 127, ci = r >> 4, c = r & 15;
    wl[e] = w1[(c*8 + ci)*49 + tap];
  }
  for (int e = t; e < 7920; e += 576){
    int ci = e / 990, r2 = e - ci*990;
    int r = r2 / 33, cc = r2 - r*33;
    int ih = r - 3, iw = cc - 3;
    float v = 0.f;
    if (ih>=0 && ih<24 && iw>=0 && iw<24){
      int off = ci*576 + ih*24 + iw;
      v = 0.5f*(pa[off] + pb[off]);
    }
    st[(ci*30 + r)*33 + cc] = v;
  }
  __syncthreads();
  {
    float a00[4], a01[4], a10[4], a11[4];
    #pragma unroll
    for (int c=0;c<4;c++){ a00[c]=0.f; a01[c]=0.f; a10[c]=0.f; a11[c]=0.f; }
    for (int ci=0; ci<8; ci++){
      for (int kh=0; kh<7; kh++){
        int rb = (ci*30 + 2*pr + kh)*33 + 2*pc;
        #pragma unroll
        for (int kw=0; kw<7; kw++){
          float v00 = st[rb+kw],    v01 = st[rb+kw+1];
          float v10 = st[rb+33+kw], v11 = st[rb+34+kw];
          float4 w4 = *(const float4*)&wl[((kh*7+kw)*8 + ci)*16 + quad*4];
          float wv[4];
          *(float4*)&wv[0] = w4;
          #pragma unroll
          for (int c=0;c<4;c++){
            a00[c] += v00*wv[c]; a01[c] += v01*wv[c];
            a10[c] += v10*wv[c]; a11[c] += v11*wv[c];
          }
        }
      }
    }
    #pragma unroll
    for (int c=0;c<4;c++){
      int c2 = quad*4 + c;
      float gg=bn1[c2], be=bn1[16+c2], m=bn1[32+c2], vv=bn1[48+c2];
      float s = gg*rsqrtf(vv + 1e-5f);
      float bi = b1[c2];
      float mx = 0.f;
      mx = fmaxf(mx, (a00[c]+bi-m)*s+be);
      mx = fmaxf(mx, (a01[c]+bi-m)*s+be);
      mx = fmaxf(mx, (a10[c]+bi-m)*s+be);
      mx = fmaxf(mx, (a11[c]+bi-m)*s+be);
      r1[c] = mx;
    }
  }
  __syncthreads();
  // ---- phase 2: conv s22 on xd ----
  for (int e = t; e < 6272; e += 576){
    int tap = e >> 7, r = e & 127, ci = r >> 4, c = r & 15;
    wl[e] = w2[(c*8 + ci)*49 + tap];
  }
  for (int e = t; e < 7920; e += 576){
    int ci = e / 990, r2 = e - ci*990;
    int r = r2 / 33, cc = r2 - r*33;
    int ih = r - 3, iw = cc - 3;
    float v = 0.f;
    if (ih>=0 && ih<24 && iw>=0 && iw<24)
      v = pb[ci*576 + ih*24 + iw];
    st[(ci*30 + r)*33 + cc] = v;
  }
  __syncthreads();
  {
    float a00[4], a01[4], a10[4], a11[4];
    #pragma unroll
    for (int c=0;c<4;c++){ a00[c]=0.f; a01[c]=0.f; a10[c]=0.f; a11[c]=0.f; }
    for (int ci=0; ci<8; ci++){
      for (int kh=0; kh<7; kh++){
        int rb = (ci*30 + 2*pr + kh)*33 + 2*pc;
        #pragma unroll
        for (int kw=0; kw<7; kw++){
          float v00 = st[rb+kw],    v01 = st[rb+kw+1];
          float v10 = st[rb+33+kw], v11 = st[rb+34+kw];
          float4 w4 = *(const float4*)&wl[((kh*7+kw)*8 + ci)*16 + quad*4];
          float wv[4];
          *(float4*)&wv[0] = w4;
          #pragma unroll
          for (int c=0;c<4;c++){
            a00[c] += v00*wv[c]; a01[c] += v01*wv[c];
            a10[c] += v10*wv[c]; a11[c] += v11*wv[c];
          }
        }
      }
    }
    #pragma unroll
    for (int c=0;c<4;c++){
      int c2 = quad*4 + c;
      float gg=bn2[c2], be=bn2[16+c2], m=bn2[32+c2], vv=bn2[48+c2];
      float s = gg*rsqrtf(vv + 1e-5f);
      float bi = b2[c2];
      float mx = 0.f;
      mx = fmaxf(mx, (a00[c]+bi-m)*s+be);
      mx = fmaxf(mx, (a01[c]+bi-m)*s+be);
      mx = fmaxf(mx, (a10[c]+bi-m)*s+be);
      mx = fmaxf(mx, (a11[c]+bi-m)*s+be);
      pm[((size_t)bd*16 + c2)*144 + pr*12 + pc] = 0.5f*(r1[c] + mx);
    }
  }
}

// s3 conv3x3 p1 + BN + attention-mask pooled signal. Input pm (pre-averaged).
__global__ __launch_bounds__(256) void k_s3(const float* __restrict__ pm,
    const float* __restrict__ w,
    const float* __restrict__ bias, const float* __restrict__ bn,
    float* __restrict__ sig){
  __shared__ float ins[16*14*14];
  __shared__ float wT[144*64];
  __shared__ float redS[64*4];
  __shared__ float redF[64*4];
  int bd = blockIdx.x;
  int t = threadIdx.x;
  for (int i = t; i < 16*196; i += 256){
    int ci = i/196, r = i - ci*196, y = r/14, xx = r - y*14;
    float v = 0.f;
    if (y>=1 && y<=12 && xx>=1 && xx<=12){
      size_t idx = ((size_t)bd*16 + ci)*144 + (y-1)*12 + (xx-1);
      v = pm[idx];
    }
    ins[i] = v;
  }
  for (int i = t; i < 9216; i += 256){
    int c = i & 63, k = i >> 6;
    wT[i] = w[c*144 + k];
  }
  __syncthreads();
  int c = t & 63, pg = t >> 6;
  float acc[36];
  #pragma unroll
  for (int pp=0;pp<36;pp++) acc[pp]=0.f;
  for (int k=0; k<144; k++){
    int ci = k/9, kk = k - ci*9, kh = kk/3, kw = kk - kh*3;
    float wv = wT[k*64 + c];
    const float* ip = &ins[ci*196];
    #pragma unroll
    for (int pp=0;pp<36;pp++){
      int y = pg*3 + pp/12, xx = pp%12;
      acc[pp] += ip[(y+kh)*14 + (xx+kw)] * wv;
    }
  }
  float g=bn[c], be=bn[64+c], m=bn[128+c], vv=bn[192+c];
  float s = g*rsqrtf(vv + 1e-5f);
  float bi = bias[c];
  float sS = 0.f, sF = 0.f;
  #pragma unroll
  for (int pp=0;pp<36;pp++){
    float f = (acc[pp] + bi - m)*s + be;
    float sg = sigmf(f);
    sS += sg; sF += f*sg;
  }
  redS[c*4+pg] = sS; redF[c*4+pg] = sF;
  __syncthreads();
  if (t < 64){
    float S = redS[t*4]+redS[t*4+1]+redS[t*4+2]+redS[t*4+3];
    float F = redF[t*4]+redF[t*4+1]+redF[t*4+2]+redF[t*4+3];
    sig[(size_t)bd*64 + t] = 0.5f*F/S;
  }
}

// c1 1x1 conv: sig[b,t,64] -> h[b,256,256] (channel-major). block=(b,o). grid 512.
__global__ __launch_bounds__(256) void k_c1(const float* __restrict__ sig,
    const float* __restrict__ w, const float* __restrict__ bias,
    float* __restrict__ h){
  int b = blockIdx.x >> 8, o = blockIdx.x & 255, tt = threadIdx.x;
  __shared__ float wl[64];
  if (tt < 64) wl[tt] = w[o*64 + tt];
  __syncthreads();
  const float4* sp = (const float4*)(sig + ((size_t)(b*256 + tt))*64);
  const float4* wp = (const float4*)wl;
  float a = bias[o];
  #pragma unroll
  for (int i=0;i<16;i++){
    float4 s4 = sp[i]; float4 w4 = wp[i];
    a += s4.x*w4.x + s4.y*w4.y + s4.z*w4.z + s4.w*w4.w;
  }
  h[((size_t)b*256 + o)*256 + tt] = fmaxf(a, 0.f);
}

// conv1d 256->256 k3 p1 + relu. 512 blocks (8 outch each) for 2 blocks/CU.
// mode: 0=none 1=acc:=out 2=acc+=out.
__global__ __launch_bounds__(256) void k_conv1d(const float* __restrict__ hin,
    const float* __restrict__ w, const float* __restrict__ bias,
    float* __restrict__ hout, float* __restrict__ accb, int mode){
  __shared__ float ins[256*34];
  __shared__ float ws[8*256*4];    // 8 outch, padded stride-4 taps (32KB)
  int bx = blockIdx.x;
  int b = bx >> 8;
  int rem = bx & 255;
  int og = rem >> 3;               // 32 groups of 8 outch
  int tg = rem & 7;
  int tid = threadIdx.x;
  int t0 = tg*32;
  for (int idx = tid; idx < 256*34; idx += 256){
    int ii = idx/34, jj = idx - ii*34;
    int tglob = t0 - 1 + jj;
    float v = 0.f;
    if (tglob >= 0 && tglob < 256) v = hin[((size_t)b*256 + ii)*256 + tglob];
    ins[idx] = v;
  }
  for (int idx = tid; idx < 6144; idx += 256){
    int q = idx/3;
    ws[q*4 + (idx - q*3)] = w[(size_t)og*6144 + idx];
  }
  __syncthreads();
  int ol = tid >> 5, tl = tid & 31;
  int o = og*8 + ol;
  float a1 = bias[o];
  const float4* w1q = (const float4*)(ws + (size_t)ol*1024);
  for (int i=0;i<256;i++){
    float v0 = ins[i*34 + tl];
    float v1 = ins[i*34 + tl + 1];
    float v2 = ins[i*34 + tl + 2];
    float4 wa = w1q[i];
    a1 += wa.x*v0 + wa.y*v1 + wa.z*v2;
  }
  a1 = fmaxf(a1, 0.f);
  size_t i1 = ((size_t)b*256 + o)*256 + t0 + tl;
  hout[i1] = a1;
  if (mode == 1) accb[i1] = a1;
  else if (mode == 2) accb[i1] += a1;
}

// Fused LN + projections + eta. One block per (b,t) row. grid 512.
__global__ __launch_bounds__(256) void k_lnproj(const float* __restrict__ acc,
    const float* __restrict__ g, const float* __restrict__ be,
    const float* __restrict__ wqp, const float* __restrict__ wkp,
    const float* __restrict__ wvp, const float* __restrict__ lrw,
    const float* __restrict__ lrb, float* __restrict__ xq,
    float* __restrict__ xk, float* __restrict__ xv,
    float* __restrict__ etalr){
  int b = blockIdx.x >> 8, tt = blockIdx.x & 255, c = threadIdx.x;
  __shared__ float hrow[256];
  __shared__ float rs[4];
  __shared__ float rq[4];
  __shared__ float epb[4][4];   // [wave][head]
  int wv_ = c >> 6, ln = c & 63;
  float v = acc[((size_t)b*256 + c)*256 + tt];
  float s1 = wsum64(v), s2 = wsum64(v*v);
  if (ln == 0){ rs[wv_]=s1; rq[wv_]=s2; }
  __syncthreads();
  float mu = (rs[0]+rs[1]+rs[2]+rs[3])*(1.f/256.f);
  float msq = (rq[0]+rq[1]+rq[2]+rq[3])*(1.f/256.f);
  float var = msq - mu*mu;
  float hv = (v-mu)*rsqrtf(var + 1e-5f)*g[c] + be[c];
  hrow[c] = hv;
  __syncthreads();
  {
    float p0 = hv*lrw[c];
    float p1 = hv*lrw[256 + c];
    float p2 = hv*lrw[512 + c];
    float p3 = hv*lrw[768 + c];
    p0 = wsum64(p0); p1 = wsum64(p1); p2 = wsum64(p2); p3 = wsum64(p3);
    if (ln == 0){ epb[wv_][0]=p0; epb[wv_][1]=p1; epb[wv_][2]=p2; epb[wv_][3]=p3; }
  }
  float aq = 0.f, ak = 0.f, av = 0.f;
  for (int k=0;k<256;k++){
    float hk = hrow[k];
    aq += hk*wqp[(size_t)k*256 + c];
    ak += hk*wkp[(size_t)k*256 + c];
    av += hk*wvp[(size_t)k*256 + c];
  }
  size_t row = (size_t)blockIdx.x;
  xq[row*256 + c] = aq;
  xk[row*256 + c] = ak;
  xv[row*256 + c] = av;
  __syncthreads();
  if (c < 4){
    float a = lrb[c] + epb[0][c] + epb[1][c] + epb[2][c] + epb[3][c];
    etalr[((size_t)(b*4 + c))*256 + tt] = 0.1f*sigmf(a)*(1.f/64.f);
  }
}

// TTT-MLP scan, 512 threads. Role/K-split (R11 structure, unchanged).
__global__ __launch_bounds__(512) void k_ttt(
    const float* __restrict__ xq, const float* __restrict__ xk,
    const float* __restrict__ xv, const float* __restrict__ etalr,
    const float* __restrict__ tib, const float* __restrict__ lnw,
    const float* __restrict__ lnb, const float* __restrict__ W1g,
    const float* __restrict__ B1g, const float* __restrict__ W2g,
    const float* __restrict__ B2g, float* __restrict__ out){
  __shared__ float W1s[64*256];                 // [d][j]
  __shared__ float W2L[256*65];                 // [r][c] pitch 65
  __shared__ __align__(16) float k_pk[256];     // [d=64][slot4]
  __shared__ __align__(16) float q_pk[256];
  __shared__ __align__(16) float v_pk[256];
  __shared__ __align__(16) float x2_pk[1024];   // [j=256][slot4]
  __shared__ __align__(16) float x2b_pk[1024];
  __shared__ __align__(16) float gb_pk[1024];   // gelu_bwd(Z1) factors
  __shared__ __align__(16) float gz2_pk[256];   // [cl=64][slot4]
  __shared__ __align__(16) float pzs[4*576];    // partials; aliased as gzx
  __shared__ float qwx[512];                    // qw slots 0,1 exchange
  __shared__ float a2w[64];
  __shared__ float coefs[16];                   // row-indexed [i*4+r]
  __shared__ float coef2s[16];
  __shared__ float els[4];
  __shared__ float toks_s[4];

  int b = blockIdx.x >> 2, h = blockIdx.x & 3;
  int tid = threadIdx.x;
  int j = tid & 255;
  int i2 = tid >> 8;
  int iw = j >> 6, cl = j & 63;
  int ps_iw = ((iw & 1) << 1) | (iw >> 1);      // pslot(iw)

  const float* W1b = W1g + (size_t)h*16384;
  const float* W2b = W2g + (size_t)h*16384;
  for (int i = tid; i < 16384; i += 512) W1s[i] = W1b[i];
  for (int i = tid; i < 16384; i += 512){
    int r = i >> 6, c = i & 63;
    W2L[r*65 + c] = W2b[i];
  }
  float b1r = B1g[h*256 + j];
  float b2r = B2g[h*64 + cl];
  float gr = lnw[h*64 + cl], br = lnb[h*64 + cl];
  if (tid < 4) toks_s[tid] = fmaxf(1.f/(float)(tid+1) + tib[tid], 0.f);
  __syncthreads();
  float tok3 = toks_s[3];
  float tik = toks_s[iw];

  const float* xqp = xq + (size_t)b*65536 + h*64;
  const float* xkp = xk + (size_t)b*65536 + h*64;
  const float* xvp = xv + (size_t)b*65536 + h*64;
  const float* ep  = etalr + (size_t)(b*4 + h)*256;

  float qv=0.f, kv=0.f, vv=0.f, elv=0.f;
  if (i2 == 0){ qv = xqp[(size_t)iw*256 + cl]; kv = xkp[(size_t)iw*256 + cl]; }
  else        { vv = xvp[(size_t)iw*256 + cl]; }
  if (tid < 4) elv = ep[tid];

  for (int n=0; n<64; n++){
    // --- phase 0: stage ---
    if (i2 == 0){ k_pk[cl*4 + ps_iw] = kv; q_pk[cl*4 + ps_iw] = qv; }
    else        { v_pk[cl*4 + ps_iw] = vv; }
    if (tid < 4) els[tid] = elv;
    __syncthreads();                              // A
    // --- A1 (half0 waves; wave iw = row iw) ---
    if (i2 == 0){
      float4 k4a = *(const float4*)&k_pk[cl*4];   // slots = rows 0,2,1,3
      float a0 = wsum64(qv*k4a.x);
      float a1 = wsum64(qv*k4a.y);
      float a2 = wsum64(qv*k4a.z);
      float a3 = wsum64(qv*k4a.w);
      if (cl == 0){
        coefs[iw*4+0] = tik*els[0]*(a0+1.f);
        coefs[iw*4+2] = (iw>=2) ? tik*els[2]*(a1+1.f) : 0.f;
        coefs[iw*4+1] = (iw>=1) ? tik*els[1]*(a2+1.f) : 0.f;
        coefs[iw*4+3] = (iw>=3) ? tik*els[3]*(a3+1.f) : 0.f;
      }
    }
    // --- Z1 producer split: h0 -> z1 (4 slots), h1 -> qw (4 slots) ---
    float acc0=b1r, acc1=b1r, acc2=b1r, acc3=b1r;
    {
      const float* src = (i2 == 0) ? k_pk : q_pk;
      #pragma unroll 8
      for (int d=0; d<64; d++){
        float4 s4 = *(const float4*)&src[d*4];
        float w = W1s[d*256 + j];
        acc0 += s4.x*w; acc1 += s4.y*w; acc2 += s4.z*w; acc3 += s4.w*w;
      }
    }
    float x2o0=0.f, x2o1=0.f, qw0r=0.f, qw1r=0.f;
    if (i2 == 0){
      float g0 = geluf(acc0), g1 = geluf(acc1), g2 = geluf(acc2), g3 = geluf(acc3);
      { float4 t4; t4.x=g0; t4.y=g1; t4.z=g2; t4.w=g3;
        *(float4*)&x2_pk[j*4] = t4; }
      { float4 t4; t4.x=gelu_bwdf(acc0); t4.y=gelu_bwdf(acc1);
        t4.z=gelu_bwdf(acc2); t4.w=gelu_bwdf(acc3);
        *(float4*)&gb_pk[j*4] = t4; }
      x2o0 = g0; x2o1 = g1;                       // own rows 0,2 (slots 0,1)
    } else {
      qwx[j*2]   = acc0;                          // qw slot0 (row0) for h0
      qwx[j*2+1] = acc1;                          // qw slot1 (row2) for h0
      qw0r = acc2; qw1r = acc3;                   // own rows 1,3 (slots 2,3)
    }
    __syncthreads();                              // B
    if (i2 == 0){ qw0r = qwx[j*2]; qw1r = qwx[j*2+1]; }
    else { float2 xo = *(const float2*)&x2_pk[j*4+2]; x2o0 = xo.x; x2o1 = xo.y; }
    // --- prefetch next step ---
    float qn=0.f, kn=0.f, vn=0.f, eln=0.f;
    if (n < 63){
      int l2 = (n+1)*4 + iw;
      if (i2 == 0){ qn = xqp[(size_t)l2*256 + cl]; kn = xkp[(size_t)l2*256 + cl]; }
      else        { vn = xvp[(size_t)l2*256 + cl]; }
      if (tid < 4) eln = ep[(n+1)*4 + tid];
    }
    // --- Z2 split-K: seg = iw*2+i2, 32 d's, all 4 rows via slots ---
    {
      int d0 = (iw*2 + i2)*32;
      int seg = iw*2 + i2;
      float p0=0.f,p1=0.f,p2=0.f,p3=0.f;
      #pragma unroll 8
      for (int dd=0; dd<32; dd++){
        float4 x4 = *(const float4*)&x2_pk[(d0+dd)*4];
        float w = W2L[(d0+dd)*65 + cl];
        p0 += x4.x*w; p1 += x4.y*w; p2 += x4.z*w; p3 += x4.w*w;
      }
      pzs[0*576 + cl*9 + seg] = p0;   // slot0 = row0
      pzs[2*576 + cl*9 + seg] = p1;   // slot1 = row2
      pzs[1*576 + cl*9 + seg] = p2;   // slot2 = row1
      pzs[3*576 + cl*9 + seg] = p3;   // slot3 = row3
    }
    __syncthreads();                              // C
    // --- fused LN-L2 backward (half0 wave iw = row iw) ---
    if (i2 == 0){
      float z2 = b2r;
      #pragma unroll
      for (int sg=0; sg<8; sg++) z2 += pzs[iw*576 + cl*9 + sg];
      float mu = wsum64(z2)*(1.f/64.f);
      float df = z2 - mu;
      float var = wsum64(df*df)*(1.f/64.f);
      float stdv = sqrtf(var + 1e-6f);
      float xhat = df/stdv;
      float tgt = v_pk[cl*4 + ps_iw] - kv;
      float gxh = (gr*xhat + br - tgt)*gr;
      float sg1 = wsum64(gxh);
      float sg2 = wsum64(gxh*xhat);
      float gz2 = (64.f*gxh - sg1 - xhat*sg2)*(1.f/(64.f*stdv));
      gz2_pk[cl*4 + ps_iw] = gz2;
    }
    __syncthreads();                              // D0
    // --- gZ1 split-K: half i2 covers c in [i2*32, i2*32+32) ---
    float gd0=0.f, gd1=0.f, gd2=0.f, gd3=0.f;
    {
      int cb = i2*32;
      #pragma unroll 8
      for (int cc=0; cc<32; cc++){
        float4 g4 = *(const float4*)&gz2_pk[(cb+cc)*4];
        float w = W2L[j*65 + cb + cc];
        gd0 += g4.x*w; gd1 += g4.y*w; gd2 += g4.z*w; gd3 += g4.w*w;
      }
      float4 t4; t4.x=gd0; t4.y=gd1; t4.z=gd2; t4.w=gd3;
      *(float4*)&pzs[i2*1024 + j*4] = t4;         // gzx alias on pzs
    }
    __syncthreads();                              // D1
    {
      float4 po = *(const float4*)&pzs[(1-i2)*1024 + j*4];
      gd0 += po.x; gd1 += po.y; gd2 += po.z; gd3 += po.w;
    }
    float4 gb4 = *(const float4*)&gb_pk[j*4];
    float4 gz14;
    gz14.x = gd0*gb4.x; gz14.y = gd1*gb4.y;
    gz14.z = gd2*gb4.z; gz14.w = gd3*gb4.w;       // slots 0,2,1,3
    // --- Z1b/X2b rows (i2, i2+2) ---
    int R0 = i2, R1 = i2 + 2;
    float zb0 = qw0r - (coefs[R0*4+0]*gz14.x + coefs[R0*4+2]*gz14.y
                      + coefs[R0*4+1]*gz14.z + coefs[R0*4+3]*gz14.w);
    float zb1 = qw1r - (coefs[R1*4+0]*gz14.x + coefs[R1*4+2]*gz14.y
                      + coefs[R1*4+1]*gz14.z + coefs[R1*4+3]*gz14.w);
    float xb0 = geluf(zb0), xb1 = geluf(zb1);
    { float2 t; t.x=xb0; t.y=xb1; *(float2*)&x2b_pk[j*4 + i2*2] = t; }
    // --- W1 + b1 update ---
    float le_s0 = tok3*els[0], le_s1 = tok3*els[2], le_s2 = tok3*els[1], le_s3 = tok3*els[3];
    {
      float lg0 = le_s0*gz14.x, lg1v = le_s1*gz14.y, lg2 = le_s2*gz14.z, lg3 = le_s3*gz14.w;
      int d0 = i2*32;
      #pragma unroll 8
      for (int dd=0; dd<32; dd++){
        float4 k4 = *(const float4*)&k_pk[(d0+dd)*4];
        W1s[(d0+dd)*256 + j] -= lg0*k4.x + lg1v*k4.y + lg2*k4.z + lg3*k4.w;
      }
      b1r -= lg0 + lg1v + lg2 + lg3;
    }
    // --- A2 masked products, split 4/6 across halves ---
    if (i2 == 0){
      float xo1 = x2_pk[j*4 + 2];                 // row1
      float s00 = wsum64(xb0*x2o0);               // (0,0)
      float s20 = wsum64(xb1*x2o0);               // (2,0)
      float s22 = wsum64(xb1*x2o1);               // (2,2)
      float s21 = wsum64(xb1*xo1);                // (2,1)
      if (cl == 0){
        a2w[iw*16+0]  = s00;
        a2w[iw*16+8]  = s20;
        a2w[iw*16+10] = s22;
        a2w[iw*16+9]  = s21;
      }
    } else {
      float2 xo02 = *(const float2*)&x2_pk[j*4];  // rows 0,2
      float s11 = wsum64(xb0*x2o0);               // (1,1)
      float s10 = wsum64(xb0*xo02.x);             // (1,0)
      float s31 = wsum64(xb1*x2o0);               // (3,1)
      float s33 = wsum64(xb1*x2o1);               // (3,3)
      float s30 = wsum64(xb1*xo02.x);             // (3,0)
      float s32 = wsum64(xb1*xo02.y);             // (3,2)
      if (cl == 0){
        a2w[iw*16+5]  = s11;
        a2w[iw*16+4]  = s10;
        a2w[iw*16+13] = s31;
        a2w[iw*16+15] = s33;
        a2w[iw*16+12] = s30;
        a2w[iw*16+14] = s32;
      }
    }
    __syncthreads();                              // E
    if (tid < 16){
      int ii = tid >> 2, rr = tid & 3;
      float s = a2w[tid] + a2w[16+tid] + a2w[32+tid] + a2w[48+tid];
      coef2s[tid] = (rr <= ii) ? toks_s[ii]*els[rr]*(s + 1.f) : 0.f;
    }
    // --- Z2b split-K ---
    {
      int d0 = (iw*2 + i2)*32;
      int seg = iw*2 + i2;
      float p0=0.f,p1=0.f,p2=0.f,p3=0.f;
      #pragma unroll 8
      for (int dd=0; dd<32; dd++){
        float4 x4 = *(const float4*)&x2b_pk[(d0+dd)*4];
        float w = W2L[(d0+dd)*65 + cl];
        p0 += x4.x*w; p1 += x4.y*w; p2 += x4.z*w; p3 += x4.w*w;
      }
      pzs[0*576 + cl*9 + seg] = p0;
      pzs[2*576 + cl*9 + seg] = p1;
      pzs[1*576 + cl*9 + seg] = p2;
      pzs[3*576 + cl*9 + seg] = p3;
    }
    __syncthreads();                              // F
    // --- ln_fwd + output (half0) ---
    if (i2 == 0){
      float z2b = b2r;
      #pragma unroll
      for (int sg=0; sg<8; sg++) z2b += pzs[iw*576 + cl*9 + sg];
      float4 g4r = *(const float4*)&gz2_pk[cl*4];
      z2b -= coef2s[iw*4+0]*g4r.x + coef2s[iw*4+2]*g4r.y
           + coef2s[iw*4+1]*g4r.z + coef2s[iw*4+3]*g4r.w;
      float mu2 = wsum64(z2b)*(1.f/64.f);
      float df2 = z2b - mu2;
      float var2 = wsum64(df2*df2)*(1.f/64.f);
      float lnv = gr*df2*rsqrtf(var2 + 1e-6f) + br;
      out[((size_t)b*256 + n*4 + iw)*256 + h*64 + cl] = qv + lnv;
    }
    // --- W2 + b2 update ---
    float4 xb4 = *(const float4*)&x2b_pk[j*4];    // slots
    float lx0 = le_s0*xb4.x, lx1 = le_s1*xb4.y, lx2 = le_s2*xb4.z, lx3 = le_s3*xb4.w;
    {
      int c0 = i2*32;
      #pragma unroll 8
      for (int cc=0; cc<32; cc++){
        float4 g4 = *(const float4*)&gz2_pk[(c0+cc)*4];
        W2L[j*65 + c0+cc] -= lx0*g4.x + lx1*g4.y + lx2*g4.z + lx3*g4.w;
      }
    }
    {
      float4 g4r = *(const float4*)&gz2_pk[cl*4];
      b2r -= le_s0*g4r.x + le_s1*g4r.y + le_s2*g4r.z + le_s3*g4r.w;
    }
    __syncthreads();                              // G
    qv = qn; kv = kn; vv = vn; elv = eln;
  }
}

// Fused head: LN(post) -> @wo -> LN(ln) -> fc1 -> fc2 -> fc3. grid 512 rows.
__global__ __launch_bounds__(256) void k_head(const float* __restrict__ hid2,
    const float* __restrict__ pg, const float* __restrict__ pb,
    const float* __restrict__ wo, const float* __restrict__ lg,
    const float* __restrict__ lb, const float* __restrict__ fcw,
    const float* __restrict__ fcb, const float* __restrict__ fc2w,
    const float* __restrict__ fc2b, const float* __restrict__ fc3w,
    const float* __restrict__ fc3b, float* __restrict__ outp){
  int row = blockIdx.x, c = threadIdx.x;
  __shared__ float t1[256];
  __shared__ float t3[256];
  __shared__ float t4[128];
  __shared__ float t5[64];
  __shared__ float rs[4];
  __shared__ float rq[4];
  int wv = c >> 6, ln = c & 63;
  float v = hid2[(size_t)row*256 + c];
  float s1 = wsum64(v), s2 = wsum64(v*v);
  if (ln == 0){ rs[wv]=s1; rq[wv]=s2; }
  __syncthreads();
  float mu = (rs[0]+rs[1]+rs[2]+rs[3])*(1.f/256.f);
  float msq = (rq[0]+rq[1]+rq[2]+rq[3])*(1.f/256.f);
  float var = msq - mu*mu;
  t1[c] = (v-mu)*rsqrtf(var + 1e-5f)*pg[c] + pb[c];
  __syncthreads();
  float a = 0.f;
  for (int k=0;k<256;k++) a += t1[k]*wo[(size_t)k*256 + c];
  float u1 = wsum64(a), u2 = wsum64(a*a);
  if (ln == 0){ rs[wv]=u1; rq[wv]=u2; }
  __syncthreads();
  mu = (rs[0]+rs[1]+rs[2]+rs[3])*(1.f/256.f);
  msq = (rq[0]+rq[1]+rq[2]+rq[3])*(1.f/256.f);
  var = msq - mu*mu;
  t3[c] = (a-mu)*rsqrtf(var + 1e-5f)*lg[c] + lb[c];
  __syncthreads();
  if (c < 128){
    float s = fcb[c];
    for (int k=0;k<256;k++) s += t3[k]*fcw[(size_t)k*128 + c];
    t4[c] = s;
  }
  __syncthreads();
  if (c < 64){
    float s = fc2b[c];
    for (int k=0;k<128;k++) s += t4[k]*fc2w[(size_t)k*64 + c];
    t5[c] = s;
  }
  __syncthreads();
  if (c < 64){
    float p = t5[c]*fc3w[c];
    p = wsum64(p);
    if (c == 0) outp[row] = p + fc3b[0];
  }
}

extern "C" void kernel_launch(void* const* d_in, const int* in_sizes, int n_in,
                              void* d_out, int out_size, void* d_ws, size_t ws_size,
                              hipStream_t stream){
  (void)in_sizes; (void)n_in; (void)out_size; (void)ws_size;
  const float* x       = (const float*)d_in[0];
  const float* s11_w   = (const float*)d_in[1];
  const float* s11_b   = (const float*)d_in[2];
  const float* bn11    = (const float*)d_in[3];
  const float* s12_w   = (const float*)d_in[4];
  const float* s12_b   = (const float*)d_in[5];
  const float* bn12    = (const float*)d_in[6];
  const float* s21_w   = (const float*)d_in[7];
  const float* s21_b   = (const float*)d_in[8];
  const float* bn21    = (const float*)d_in[9];
  const float* s22_w   = (const float*)d_in[10];
  const float* s22_b   = (const float*)d_in[11];
  const float* bn22    = (const float*)d_in[12];
  const float* s3_w    = (const float*)d_in[13];
  const float* s3_b    = (const float*)d_in[14];
  const float* bn3     = (const float*)d_in[15];
  const float* c1_w    = (const float*)d_in[16];
  const float* c1_b    = (const float*)d_in[17];
  const float* cb_w    = (const float*)d_in[18];
  const float* cb_b    = (const float*)d_in[19];
  const float* ln_g    = (const float*)d_in[20];
  const float* ln_b    = (const float*)d_in[21];
  const float* wq      = (const float*)d_in[22];
  const float* wk      = (const float*)d_in[23];
  const float* wv      = (const float*)d_in[24];
  const float* wo      = (const float*)d_in[25];
  const float* lr_w    = (const float*)d_in[26];
  const float* lr_b    = (const float*)d_in[27];
  const float* tib     = (const float*)d_in[28];
  const float* tlnw    = (const float*)d_in[29];
  const float* tlnb    = (const float*)d_in[30];
  const float* W1      = (const float*)d_in[31];
  const float* B1      = (const float*)d_in[32];
  const float* W2      = (const float*)d_in[33];
  const float* B2      = (const float*)d_in[34];
  const float* post_g  = (const float*)d_in[35];
  const float* post_b  = (const float*)d_in[36];
  const float* fc_w    = (const float*)d_in[37];
  const float* fc_b    = (const float*)d_in[38];
  const float* fc2_w   = (const float*)d_in[39];
  const float* fc2_b   = (const float*)d_in[40];
  const float* fc3_w   = (const float*)d_in[41];
  const float* fc3_b   = (const float*)d_in[42];

  float* ws = (float*)d_ws;
  float* xs   = ws;                       // 2359296
  float* xd   = ws + 2359296;             // 2359296
  float* p1   = ws + 4718592;             // 1179648 (pm)
  float* sig  = ws + 7077888;             // 32768
  float* buf0 = ws + 7110656;             // 131072
  float* buf1 = ws + 7241728;             // 131072
  float* accb = ws + 7372800;             // 131072
  float* xqb  = ws + 7634944;             // 131072
  float* xkb  = ws + 7766016;             // 131072
  float* xvb  = ws + 7897088;             // 131072
  float* eta  = ws + 8028160;             // 2048
  float* hid2 = ws + 8030208;             // 131072

  k_stem<<<3072, 192, 0, stream>>>(x, s11_w, s11_b, bn11, xs,
                                   s12_w, s12_b, bn12, xd);
  k_s2m<<<512, 576, 0, stream>>>(xs, xd, s21_w, s21_b, bn21,
                                 s22_w, s22_b, bn22, p1);
  k_s3<<<512, 256, 0, stream>>>(p1, s3_w, s3_b, bn3, sig);
  k_c1<<<512, 256, 0, stream>>>(sig, c1_w, c1_b, buf0);
  {
    float* cin = buf0; float* cout = buf1;
    for (int l=0; l<8; l++){
      int mode = (l == 1) ? 1 : ((l & 1) ? 2 : 0);
      k_conv1d<<<512, 256, 0, stream>>>(cin, cb_w + (size_t)l*196608,
                                        cb_b + l*256, cout, accb, mode);
      float* tmp = cin; cin = cout; cout = tmp;
    }
  }
  k_lnproj<<<512, 256, 0, stream>>>(accb, ln_g, ln_b, wq, wk, wv,
                                    lr_w, lr_b, xqb, xkb, xvb, eta);
  k_ttt<<<8, 512, 0, stream>>>(xqb, xkb, xvb, eta, tib, tlnw, tlnb,
                               W1, B1, W2, B2, hid2);
  k_head<<<512, 256, 0, stream>>>(hid2, post_g, post_b, wo, ln_g, ln_b,
                                  fc_w, fc_b, fc2_w, fc2_b, fc3_w, fc3_b,
                                  (float*)d_out);
}

// Round 13
// 1656.084 us; speedup vs baseline: 1.0652x; 1.0227x over previous
//
#include <hip/hip_runtime.h>
#include <hip/hip_bf16.h>
#include <math.h>

#define DEV __device__ __forceinline__

DEV float wsum64(float v){
  #pragma unroll
  for (int off = 32; off; off >>= 1) v += __shfl_xor(v, off, 64);
  return v;
}
DEV float geluf(float x){
  return 0.5f*x*(1.f + tanhf(0.7978845608028654f*(x + 0.044715f*x*x*x)));
}
DEV float gelu_bwdf(float x){
  float x2 = x*x;
  float t = tanhf(0.79788456f*x*(1.f + 0.044715f*x2));
  return 0.5f*x*((1.f - t*t)*(0.79788456f + 0.1070322243f*x2)) + 0.5f*(1.f + t);
}
DEV float sigmf(float x){ return 1.f/(1.f + expf(-x)); }

// ---------------------------------------------------------------------------
// Merged stem: blocks [0,1536) run s11 (conv on x), [1536,3072) run s12
// (conv on frame-diffs). Phase-split planes at pitch 54 (8B-aligned), row
// pitch 108; conv data reads via float2.
__global__ __launch_bounds__(192) void k_stem(const float* __restrict__ x,
    const float* __restrict__ w11, const float* __restrict__ b11,
    const float* __restrict__ bn11p, float* __restrict__ xs,
    const float* __restrict__ w12, const float* __restrict__ b12,
    const float* __restrict__ bn12p, float* __restrict__ xd){
  __shared__ float st[3*37*108];    // 11988 floats
  __shared__ float wl[49*12*8];     // 4704 (s11 uses first 1176)
  int t = threadIdx.x;
  if (blockIdx.x < 1536){
    // ---------------- s11 ----------------
    int bx = blockIdx.x;
    int bd = bx / 3, g = bx - bd*3;
    for (int e = t; e < 1176; e += 192){
      int tap = e / 24, r = e - tap*24, ci = r >> 3, c = r & 7;
      wl[e] = w11[(c*3 + ci)*49 + tap];
    }
    const float* xb = x + (size_t)bd*3*9216;
    for (int e = t; e < 3*37*102; e += 192){
      int ci = e / 3774, r2 = e - ci*3774;
      int ihl = r2 / 102, pi = r2 - ihl*102;
      int ih = ihl + 32*g - 3, iw = pi - 3;
      float v = 0.f;
      if (ih>=0 && ih<96 && iw>=0 && iw<96) v = xb[(size_t)ci*9216 + ih*96 + iw];
      st[(ci*37 + ihl)*108 + (pi&1)*54 + (pi>>1)] = v;
    }
    __syncthreads();
    int pr = t / 24, pc = t - pr*24;
    float a00[8], a01[8], a10[8], a11[8];
    #pragma unroll
    for (int c=0;c<8;c++){ a00[c]=0.f; a01[c]=0.f; a10[c]=0.f; a11[c]=0.f; }
    for (int ci=0; ci<3; ci++){
      for (int kh=0; kh<7; kh++){
        int rb0 = (ci*37 + 4*pr + kh)*108 + 2*pc;
        int rb1 = rb0 + 216;
        float2 A0 = *(const float2*)&st[rb0];
        float2 A1 = *(const float2*)&st[rb0+2];
        float  A2 = st[rb0+4];
        float2 B0 = *(const float2*)&st[rb0+54];
        float2 B1 = *(const float2*)&st[rb0+56];
        float2 C0 = *(const float2*)&st[rb1];
        float2 C1 = *(const float2*)&st[rb1+2];
        float  C2 = st[rb1+4];
        float2 D0 = *(const float2*)&st[rb1+54];
        float2 D1 = *(const float2*)&st[rb1+56];
        float v00[7], v01[7], v10[7], v11[7];
        v00[0]=A0.x; v01[0]=A0.y; v10[0]=C0.x; v11[0]=C0.y;
        v00[1]=B0.x; v01[1]=B0.y; v10[1]=D0.x; v11[1]=D0.y;
        v00[2]=A0.y; v01[2]=A1.x; v10[2]=C0.y; v11[2]=C1.x;
        v00[3]=B0.y; v01[3]=B1.x; v10[3]=D0.y; v11[3]=D1.x;
        v00[4]=A1.x; v01[4]=A1.y; v10[4]=C1.x; v11[4]=C1.y;
        v00[5]=B1.x; v01[5]=B1.y; v10[5]=D1.x; v11[5]=D1.y;
        v00[6]=A1.y; v01[6]=A2;   v10[6]=C1.y; v11[6]=C2;
        #pragma unroll
        for (int kw=0; kw<7; kw++){
          const float4* wp = (const float4*)&wl[((kh*7+kw)*3 + ci)*8];
          float wv[8];
          *(float4*)&wv[0] = wp[0]; *(float4*)&wv[4] = wp[1];
          #pragma unroll
          for (int c=0;c<8;c++){
            a00[c] += v00[kw]*wv[c]; a01[c] += v01[kw]*wv[c];
            a10[c] += v10[kw]*wv[c]; a11[c] += v11[kw]*wv[c];
          }
        }
      }
    }
    int pos = (g*8 + pr)*24 + pc;
    #pragma unroll
    for (int c=0;c<8;c++){
      float gg=bn11p[c], be=bn11p[8+c], m=bn11p[16+c], vv=bn11p[24+c];
      float s = gg*rsqrtf(vv + 1e-5f);
      float bi = b11[c];
      float mx = 0.f;
      mx = fmaxf(mx, (a00[c]+bi-m)*s+be);
      mx = fmaxf(mx, (a01[c]+bi-m)*s+be);
      mx = fmaxf(mx, (a10[c]+bi-m)*s+be);
      mx = fmaxf(mx, (a11[c]+bi-m)*s+be);
      xs[((size_t)bd*8 + c)*576 + pos] = mx;
    }
  } else {
    // ---------------- s12 ----------------
    int bx = blockIdx.x - 1536;
    int bd = bx / 3, g = bx - bd*3;
    int b = bd >> 8, dd = bd & 255;
    for (int e = t; e < 4704; e += 192){
      int tap = e / 96, r = e - tap*96, ci = r >> 3, c = r & 7;
      wl[e] = w12[(c*12 + ci)*49 + tap];
    }
    int fa[4], fb[4];
    fa[0] = dd>=2 ? dd-1 : 0;     fb[0] = dd>=2 ? dd-2 : 0;
    fa[1] = dd;                   fb[1] = dd>=1 ? dd-1 : 0;
    fa[2] = dd<=254 ? dd+1 : 255; fb[2] = dd;
    fa[3] = dd<=253 ? dd+2 : 255; fb[3] = dd<=254 ? dd+1 : 255;
    int pr = t / 24, pc = t - pr*24;
    float a00[8], a01[8], a10[8], a11[8];
    #pragma unroll
    for (int c=0;c<8;c++){ a00[c]=0.f; a01[c]=0.f; a10[c]=0.f; a11[c]=0.f; }
    for (int g4=0; g4<4; g4++){
      if (fa[g4] == fb[g4]) continue;   // zero diff, uniform per block
      __syncthreads();
      const float* xa = x + ((size_t)(b*256 + fa[g4]))*3*9216;
      const float* xbp= x + ((size_t)(b*256 + fb[g4]))*3*9216;
      for (int e = t; e < 3*37*102; e += 192){
        int ci = e / 3774, r2 = e - ci*3774;
        int ihl = r2 / 102, pi = r2 - ihl*102;
        int ih = ihl + 32*g - 3, iw = pi - 3;
        float v = 0.f;
        if (ih>=0 && ih<96 && iw>=0 && iw<96){
          size_t off = (size_t)ci*9216 + ih*96 + iw;
          v = xa[off] - xbp[off];
        }
        st[(ci*37 + ihl)*108 + (pi&1)*54 + (pi>>1)] = v;
      }
      __syncthreads();
      for (int ci=0; ci<3; ci++){
        int gch = g4*3 + ci;
        for (int kh=0; kh<7; kh++){
          int rb0 = (ci*37 + 4*pr + kh)*108 + 2*pc;
          int rb1 = rb0 + 216;
          float2 A0 = *(const float2*)&st[rb0];
          float2 A1 = *(const float2*)&st[rb0+2];
          float  A2 = st[rb0+4];
          float2 B0 = *(const float2*)&st[rb0+54];
          float2 B1 = *(const float2*)&st[rb0+56];
          float2 C0 = *(const float2*)&st[rb1];
          float2 C1 = *(const float2*)&st[rb1+2];
          float  C2 = st[rb1+4];
          float2 D0 = *(const float2*)&st[rb1+54];
          float2 D1 = *(const float2*)&st[rb1+56];
          float v00[7], v01[7], v10[7], v11[7];
          v00[0]=A0.x; v01[0]=A0.y; v10[0]=C0.x; v11[0]=C0.y;
          v00[1]=B0.x; v01[1]=B0.y; v10[1]=D0.x; v11[1]=D0.y;
          v00[2]=A0.y; v01[2]=A1.x; v10[2]=C0.y; v11[2]=C1.x;
          v00[3]=B0.y; v01[3]=B1.x; v10[3]=D0.y; v11[3]=D1.x;
          v00[4]=A1.x; v01[4]=A1.y; v10[4]=C1.x; v11[4]=C1.y;
          v00[5]=B1.x; v01[5]=B1.y; v10[5]=D1.x; v11[5]=D1.y;
          v00[6]=A1.y; v01[6]=A2;   v10[6]=C1.y; v11[6]=C2;
          #pragma unroll
          for (int kw=0; kw<7; kw++){
            const float4* wp = (const float4*)&wl[((kh*7+kw)*12 + gch)*8];
            float wv[8];
            *(float4*)&wv[0] = wp[0]; *(float4*)&wv[4] = wp[1];
            #pragma unroll
            for (int c=0;c<8;c++){
              a00[c] += v00[kw]*wv[c]; a01[c] += v01[kw]*wv[c];
              a10[c] += v10[kw]*wv[c]; a11[c] += v11[kw]*wv[c];
            }
          }
        }
      }
    }
    int pos = (g*8 + pr)*24 + pc;
    #pragma unroll
    for (int c=0;c<8;c++){
      float gg=bn12p[c], be=bn12p[8+c], m=bn12p[16+c], vv=bn12p[24+c];
      float s = gg*rsqrtf(vv + 1e-5f);
      float bi = b12[c];
      float mx = 0.f;
      mx = fmaxf(mx, (a00[c]+bi-m)*s+be);
      mx = fmaxf(mx, (a01[c]+bi-m)*s+be);
      mx = fmaxf(mx, (a10[c]+bi-m)*s+be);
      mx = fmaxf(mx, (a11[c]+bi-m)*s+be);
      xd[((size_t)bd*8 + c)*576 + pos] = mx;
    }
  }
}

// Merged s21+s22, 576 threads = 144 pos x 4 channel-quads. Tile stride 34
// (even -> float2-aligned conv reads). conv1 on 0.5*(xs+xd), conv2 on xd;
// writes pm = 0.5*(p1+p2). One block/bd.
__global__ __launch_bounds__(576) void k_s2m(const float* __restrict__ xs,
    const float* __restrict__ xd,
    const float* __restrict__ w1, const float* __restrict__ b1,
    const float* __restrict__ bn1,
    const float* __restrict__ w2, const float* __restrict__ b2,
    const float* __restrict__ bn2, float* __restrict__ pm){
  __shared__ float st[8*30*34];     // 8160
  __shared__ float wl[49*8*16];     // 6272
  int bd = blockIdx.x;
  int t = threadIdx.x;
  int quad = t / 144;               // 0..3 -> channels quad*4..quad*4+3
  int pos = t - quad*144;
  int pr = pos / 12, pc = pos - pr*12;
  const float* pa = xs + (size_t)bd*8*576;
  const float* pb = xd + (size_t)bd*8*576;
  float r1[4];
  // ---- phase 1: conv s21 on 0.5*(xs+xd) ----
  for (int e = t; e < 6272; e += 576){
    int tap = e >> 7, r = e & 127, ci = r >> 4, c = r & 15;
    wl[e] = w1[(c*8 + ci)*49 + tap];
  }
  for (int e = t; e < 8160; e += 576){
    int ci = e / 1020, r2 = e - ci*1020;
    int r = r2 / 34, cc = r2 - r*34;
    int ih = r - 3, iw = cc - 3;
    float v = 0.f;
    if (ih>=0 && ih<24 && iw>=0 && iw<24){
      int off = ci*576 + ih*24 + iw;
      v = 0.5f*(pa[off] + pb[off]);
    }
    st[(ci*30 + r)*34 + cc] = v;
  }
  __syncthreads();
  {
    float a00[4], a01[4], a10[4], a11[4];
    #pragma unroll
    for (int c=0;c<4;c++){ a00[c]=0.f; a01[c]=0.f; a10[c]=0.f; a11[c]=0.f; }
    for (int ci=0; ci<8; ci++){
      for (int kh=0; kh<7; kh++){
        int rb = (ci*30 + 2*pr + kh)*34 + 2*pc;
        float2 E0 = *(const float2*)&st[rb];
        float2 E1 = *(const float2*)&st[rb+2];
        float2 E2 = *(const float2*)&st[rb+4];
        float2 E3 = *(const float2*)&st[rb+6];
        float2 F0 = *(const float2*)&st[rb+34];
        float2 F1 = *(const float2*)&st[rb+36];
        float2 F2 = *(const float2*)&st[rb+38];
        float2 F3 = *(const float2*)&st[rb+40];
        float v00[7], v01[7], v10[7], v11[7];
        v00[0]=E0.x; v01[0]=E0.y; v10[0]=F0.x; v11[0]=F0.y;
        v00[1]=E0.y; v01[1]=E1.x; v10[1]=F0.y; v11[1]=F1.x;
        v00[2]=E1.x; v01[2]=E1.y; v10[2]=F1.x; v11[2]=F1.y;
        v00[3]=E1.y; v01[3]=E2.x; v10[3]=F1.y; v11[3]=F2.x;
        v00[4]=E2.x; v01[4]=E2.y; v10[4]=F2.x; v11[4]=F2.y;
        v00[5]=E2.y; v01[5]=E3.x; v10[5]=F2.y; v11[5]=F3.x;
        v00[6]=E3.x; v01[6]=E3.y; v10[6]=F3.x; v11[6]=F3.y;
        #pragma unroll
        for (int kw=0; kw<7; kw++){
          float4 w4 = *(const float4*)&wl[((kh*7+kw)*8 + ci)*16 + quad*4];
          float wv[4];
          *(float4*)&wv[0] = w4;
          #pragma unroll
          for (int c=0;c<4;c++){
            a00[c] += v00[kw]*wv[c]; a01[c] += v01[kw]*wv[c];
            a10[c] += v10[kw]*wv[c]; a11[c] += v11[kw]*wv[c];
          }
        }
      }
    }
    #pragma unroll
    for (int c=0;c<4;c++){
      int c2 = quad*4 + c;
      float gg=bn1[c2], be=bn1[16+c2], m=bn1[32+c2], vv=bn1[48+c2];
      float s = gg*rsqrtf(vv + 1e-5f);
      float bi = b1[c2];
      float mx = 0.f;
      mx = fmaxf(mx, (a00[c]+bi-m)*s+be);
      mx = fmaxf(mx, (a01[c]+bi-m)*s+be);
      mx = fmaxf(mx, (a10[c]+bi-m)*s+be);
      mx = fmaxf(mx, (a11[c]+bi-m)*s+be);
      r1[c] = mx;
    }
  }
  __syncthreads();
  // ---- phase 2: conv s22 on xd ----
  for (int e = t; e < 6272; e += 576){
    int tap = e >> 7, r = e & 127, ci = r >> 4, c = r & 15;
    wl[e] = w2[(c*8 + ci)*49 + tap];
  }
  for (int e = t; e < 8160; e += 576){
    int ci = e / 1020, r2 = e - ci*1020;
    int r = r2 / 34, cc = r2 - r*34;
    int ih = r - 3, iw = cc - 3;
    float v = 0.f;
    if (ih>=0 && ih<24 && iw>=0 && iw<24)
      v = pb[ci*576 + ih*24 + iw];
    st[(ci*30 + r)*34 + cc] = v;
  }
  __syncthreads();
  {
    float a00[4], a01[4], a10[4], a11[4];
    #pragma unroll
    for (int c=0;c<4;c++){ a00[c]=0.f; a01[c]=0.f; a10[c]=0.f; a11[c]=0.f; }
    for (int ci=0; ci<8; ci++){
      for (int kh=0; kh<7; kh++){
        int rb = (ci*30 + 2*pr + kh)*34 + 2*pc;
        float2 E0 = *(const float2*)&st[rb];
        float2 E1 = *(const float2*)&st[rb+2];
        float2 E2 = *(const float2*)&st[rb+4];
        float2 E3 = *(const float2*)&st[rb+6];
        float2 F0 = *(const float2*)&st[rb+34];
        float2 F1 = *(const float2*)&st[rb+36];
        float2 F2 = *(const float2*)&st[rb+38];
        float2 F3 = *(const float2*)&st[rb+40];
        float v00[7], v01[7], v10[7], v11[7];
        v00[0]=E0.x; v01[0]=E0.y; v10[0]=F0.x; v11[0]=F0.y;
        v00[1]=E0.y; v01[1]=E1.x; v10[1]=F0.y; v11[1]=F1.x;
        v00[2]=E1.x; v01[2]=E1.y; v10[2]=F1.x; v11[2]=F1.y;
        v00[3]=E1.y; v01[3]=E2.x; v10[3]=F1.y; v11[3]=F2.x;
        v00[4]=E2.x; v01[4]=E2.y; v10[4]=F2.x; v11[4]=F2.y;
        v00[5]=E2.y; v01[5]=E3.x; v10[5]=F2.y; v11[5]=F3.x;
        v00[6]=E3.x; v01[6]=E3.y; v10[6]=F3.x; v11[6]=F3.y;
        #pragma unroll
        for (int kw=0; kw<7; kw++){
          float4 w4 = *(const float4*)&wl[((kh*7+kw)*8 + ci)*16 + quad*4];
          float wv[4];
          *(float4*)&wv[0] = w4;
          #pragma unroll
          for (int c=0;c<4;c++){
            a00[c] += v00[kw]*wv[c]; a01[c] += v01[kw]*wv[c];
            a10[c] += v10[kw]*wv[c]; a11[c] += v11[kw]*wv[c];
          }
        }
      }
    }
    #pragma unroll
    for (int c=0;c<4;c++){
      int c2 = quad*4 + c;
      float gg=bn2[c2], be=bn2[16+c2], m=bn2[32+c2], vv=bn2[48+c2];
      float s = gg*rsqrtf(vv + 1e-5f);
      float bi = b2[c2];
      float mx = 0.f;
      mx = fmaxf(mx, (a00[c]+bi-m)*s+be);
      mx = fmaxf(mx, (a01[c]+bi-m)*s+be);
      mx = fmaxf(mx, (a10[c]+bi-m)*s+be);
      mx = fmaxf(mx, (a11[c]+bi-m)*s+be);
      pm[((size_t)bd*16 + c2)*144 + pr*12 + pc] = 0.5f*(r1[c] + mx);
    }
  }
}

// s3 conv3x3 p1 + BN + attention-mask pooled signal. Input pm (pre-averaged).
__global__ __launch_bounds__(256) void k_s3(const float* __restrict__ pm,
    const float* __restrict__ w,
    const float* __restrict__ bias, const float* __restrict__ bn,
    float* __restrict__ sig){
  __shared__ float ins[16*14*14];
  __shared__ float wT[144*64];
  __shared__ float redS[64*4];
  __shared__ float redF[64*4];
  int bd = blockIdx.x;
  int t = threadIdx.x;
  for (int i = t; i < 16*196; i += 256){
    int ci = i/196, r = i - ci*196, y = r/14, xx = r - y*14;
    float v = 0.f;
    if (y>=1 && y<=12 && xx>=1 && xx<=12){
      size_t idx = ((size_t)bd*16 + ci)*144 + (y-1)*12 + (xx-1);
      v = pm[idx];
    }
    ins[i] = v;
  }
  for (int i = t; i < 9216; i += 256){
    int c = i & 63, k = i >> 6;
    wT[i] = w[c*144 + k];
  }
  __syncthreads();
  int c = t & 63, pg = t >> 6;
  float acc[36];
  #pragma unroll
  for (int pp=0;pp<36;pp++) acc[pp]=0.f;
  for (int k=0; k<144; k++){
    int ci = k/9, kk = k - ci*9, kh = kk/3, kw = kk - kh*3;
    float wv = wT[k*64 + c];
    const float* ip = &ins[ci*196];
    #pragma unroll
    for (int pp=0;pp<36;pp++){
      int y = pg*3 + pp/12, xx = pp%12;
      acc[pp] += ip[(y+kh)*14 + (xx+kw)] * wv;
    }
  }
  float g=bn[c], be=bn[64+c], m=bn[128+c], vv=bn[192+c];
  float s = g*rsqrtf(vv + 1e-5f);
  float bi = bias[c];
  float sS = 0.f, sF = 0.f;
  #pragma unroll
  for (int pp=0;pp<36;pp++){
    float f = (acc[pp] + bi - m)*s + be;
    float sg = sigmf(f);
    sS += sg; sF += f*sg;
  }
  redS[c*4+pg] = sS; redF[c*4+pg] = sF;
  __syncthreads();
  if (t < 64){
    float S = redS[t*4]+redS[t*4+1]+redS[t*4+2]+redS[t*4+3];
    float F = redF[t*4]+redF[t*4+1]+redF[t*4+2]+redF[t*4+3];
    sig[(size_t)bd*64 + t] = 0.5f*F/S;
  }
}

// c1 1x1 conv: sig[b,t,64] -> h[b,256,256] (channel-major). block=(b,o). grid 512.
__global__ __launch_bounds__(256) void k_c1(const float* __restrict__ sig,
    const float* __restrict__ w, const float* __restrict__ bias,
    float* __restrict__ h){
  int b = blockIdx.x >> 8, o = blockIdx.x & 255, tt = threadIdx.x;
  __shared__ float wl[64];
  if (tt < 64) wl[tt] = w[o*64 + tt];
  __syncthreads();
  const float4* sp = (const float4*)(sig + ((size_t)(b*256 + tt))*64);
  const float4* wp = (const float4*)wl;
  float a = bias[o];
  #pragma unroll
  for (int i=0;i<16;i++){
    float4 s4 = sp[i]; float4 w4 = wp[i];
    a += s4.x*w4.x + s4.y*w4.y + s4.z*w4.z + s4.w*w4.w;
  }
  h[((size_t)b*256 + o)*256 + tt] = fmaxf(a, 0.f);
}

// conv1d 256->256 k3 p1 + relu. 512 blocks (8 outch each) for 2 blocks/CU.
// mode: 0=none 1=acc:=out 2=acc+=out.
__global__ __launch_bounds__(256) void k_conv1d(const float* __restrict__ hin,
    const float* __restrict__ w, const float* __restrict__ bias,
    float* __restrict__ hout, float* __restrict__ accb, int mode){
  __shared__ float ins[256*34];
  __shared__ float ws[8*256*4];    // 8 outch, padded stride-4 taps (32KB)
  int bx = blockIdx.x;
  int b = bx >> 8;
  int rem = bx & 255;
  int og = rem >> 3;               // 32 groups of 8 outch
  int tg = rem & 7;
  int tid = threadIdx.x;
  int t0 = tg*32;
  for (int idx = tid; idx < 256*34; idx += 256){
    int ii = idx/34, jj = idx - ii*34;
    int tglob = t0 - 1 + jj;
    float v = 0.f;
    if (tglob >= 0 && tglob < 256) v = hin[((size_t)b*256 + ii)*256 + tglob];
    ins[idx] = v;
  }
  for (int idx = tid; idx < 6144; idx += 256){
    int q = idx/3;
    ws[q*4 + (idx - q*3)] = w[(size_t)og*6144 + idx];
  }
  __syncthreads();
  int ol = tid >> 5, tl = tid & 31;
  int o = og*8 + ol;
  float a1 = bias[o];
  const float4* w1q = (const float4*)(ws + (size_t)ol*1024);
  for (int i=0;i<256;i++){
    float v0 = ins[i*34 + tl];
    float v1 = ins[i*34 + tl + 1];
    float v2 = ins[i*34 + tl + 2];
    float4 wa = w1q[i];
    a1 += wa.x*v0 + wa.y*v1 + wa.z*v2;
  }
  a1 = fmaxf(a1, 0.f);
  size_t i1 = ((size_t)b*256 + o)*256 + t0 + tl;
  hout[i1] = a1;
  if (mode == 1) accb[i1] = a1;
  else if (mode == 2) accb[i1] += a1;
}

// Fused LN + projections + eta. One block per (b,t) row. grid 512.
__global__ __launch_bounds__(256) void k_lnproj(const float* __restrict__ acc,
    const float* __restrict__ g, const float* __restrict__ be,
    const float* __restrict__ wqp, const float* __restrict__ wkp,
    const float* __restrict__ wvp, const float* __restrict__ lrw,
    const float* __restrict__ lrb, float* __restrict__ xq,
    float* __restrict__ xk, float* __restrict__ xv,
    float* __restrict__ etalr){
  int b = blockIdx.x >> 8, tt = blockIdx.x & 255, c = threadIdx.x;
  __shared__ float hrow[256];
  __shared__ float rs[4];
  __shared__ float rq[4];
  __shared__ float epb[4][4];   // [wave][head]
  int wv_ = c >> 6, ln = c & 63;
  float v = acc[((size_t)b*256 + c)*256 + tt];
  float s1 = wsum64(v), s2 = wsum64(v*v);
  if (ln == 0){ rs[wv_]=s1; rq[wv_]=s2; }
  __syncthreads();
  float mu = (rs[0]+rs[1]+rs[2]+rs[3])*(1.f/256.f);
  float msq = (rq[0]+rq[1]+rq[2]+rq[3])*(1.f/256.f);
  float var = msq - mu*mu;
  float hv = (v-mu)*rsqrtf(var + 1e-5f)*g[c] + be[c];
  hrow[c] = hv;
  __syncthreads();
  {
    float p0 = hv*lrw[c];
    float p1 = hv*lrw[256 + c];
    float p2 = hv*lrw[512 + c];
    float p3 = hv*lrw[768 + c];
    p0 = wsum64(p0); p1 = wsum64(p1); p2 = wsum64(p2); p3 = wsum64(p3);
    if (ln == 0){ epb[wv_][0]=p0; epb[wv_][1]=p1; epb[wv_][2]=p2; epb[wv_][3]=p3; }
  }
  float aq = 0.f, ak = 0.f, av = 0.f;
  for (int k=0;k<256;k++){
    float hk = hrow[k];
    aq += hk*wqp[(size_t)k*256 + c];
    ak += hk*wkp[(size_t)k*256 + c];
    av += hk*wvp[(size_t)k*256 + c];
  }
  size_t row = (size_t)blockIdx.x;
  xq[row*256 + c] = aq;
  xk[row*256 + c] = ak;
  xv[row*256 + c] = av;
  __syncthreads();
  if (c < 4){
    float a = lrb[c] + epb[0][c] + epb[1][c] + epb[2][c] + epb[3][c];
    etalr[((size_t)(b*4 + c))*256 + tt] = 0.1f*sigmf(a)*(1.f/64.f);
  }
}

// TTT-MLP scan, 512 threads. Role/K-split (R11 structure, unchanged).
__global__ __launch_bounds__(512) void k_ttt(
    const float* __restrict__ xq, const float* __restrict__ xk,
    const float* __restrict__ xv, const float* __restrict__ etalr,
    const float* __restrict__ tib, const float* __restrict__ lnw,
    const float* __restrict__ lnb, const float* __restrict__ W1g,
    const float* __restrict__ B1g, const float* __restrict__ W2g,
    const float* __restrict__ B2g, float* __restrict__ out){
  __shared__ float W1s[64*256];                 // [d][j]
  __shared__ float W2L[256*65];                 // [r][c] pitch 65
  __shared__ __align__(16) float k_pk[256];     // [d=64][slot4]
  __shared__ __align__(16) float q_pk[256];
  __shared__ __align__(16) float v_pk[256];
  __shared__ __align__(16) float x2_pk[1024];   // [j=256][slot4]
  __shared__ __align__(16) float x2b_pk[1024];
  __shared__ __align__(16) float gb_pk[1024];   // gelu_bwd(Z1) factors
  __shared__ __align__(16) float gz2_pk[256];   // [cl=64][slot4]
  __shared__ __align__(16) float pzs[4*576];    // partials; aliased as gzx
  __shared__ float qwx[512];                    // qw slots 0,1 exchange
  __shared__ float a2w[64];
  __shared__ float coefs[16];                   // row-indexed [i*4+r]
  __shared__ float coef2s[16];
  __shared__ float els[4];
  __shared__ float toks_s[4];

  int b = blockIdx.x >> 2, h = blockIdx.x & 3;
  int tid = threadIdx.x;
  int j = tid & 255;
  int i2 = tid >> 8;
  int iw = j >> 6, cl = j & 63;
  int ps_iw = ((iw & 1) << 1) | (iw >> 1);      // pslot(iw)

  const float* W1b = W1g + (size_t)h*16384;
  const float* W2b = W2g + (size_t)h*16384;
  for (int i = tid; i < 16384; i += 512) W1s[i] = W1b[i];
  for (int i = tid; i < 16384; i += 512){
    int r = i >> 6, c = i & 63;
    W2L[r*65 + c] = W2b[i];
  }
  float b1r = B1g[h*256 + j];
  float b2r = B2g[h*64 + cl];
  float gr = lnw[h*64 + cl], br = lnb[h*64 + cl];
  if (tid < 4) toks_s[tid] = fmaxf(1.f/(float)(tid+1) + tib[tid], 0.f);
  __syncthreads();
  float tok3 = toks_s[3];
  float tik = toks_s[iw];

  const float* xqp = xq + (size_t)b*65536 + h*64;
  const float* xkp = xk + (size_t)b*65536 + h*64;
  const float* xvp = xv + (size_t)b*65536 + h*64;
  const float* ep  = etalr + (size_t)(b*4 + h)*256;

  float qv=0.f, kv=0.f, vv=0.f, elv=0.f;
  if (i2 == 0){ qv = xqp[(size_t)iw*256 + cl]; kv = xkp[(size_t)iw*256 + cl]; }
  else        { vv = xvp[(size_t)iw*256 + cl]; }
  if (tid < 4) elv = ep[tid];

  for (int n=0; n<64; n++){
    // --- phase 0: stage ---
    if (i2 == 0){ k_pk[cl*4 + ps_iw] = kv; q_pk[cl*4 + ps_iw] = qv; }
    else        { v_pk[cl*4 + ps_iw] = vv; }
    if (tid < 4) els[tid] = elv;
    __syncthreads();                              // A
    // --- A1 (half0 waves; wave iw = row iw) ---
    if (i2 == 0){
      float4 k4a = *(const float4*)&k_pk[cl*4];   // slots = rows 0,2,1,3
      float a0 = wsum64(qv*k4a.x);
      float a1 = wsum64(qv*k4a.y);
      float a2 = wsum64(qv*k4a.z);
      float a3 = wsum64(qv*k4a.w);
      if (cl == 0){
        coefs[iw*4+0] = tik*els[0]*(a0+1.f);
        coefs[iw*4+2] = (iw>=2) ? tik*els[2]*(a1+1.f) : 0.f;
        coefs[iw*4+1] = (iw>=1) ? tik*els[1]*(a2+1.f) : 0.f;
        coefs[iw*4+3] = (iw>=3) ? tik*els[3]*(a3+1.f) : 0.f;
      }
    }
    // --- Z1 producer split: h0 -> z1 (4 slots), h1 -> qw (4 slots) ---
    float acc0=b1r, acc1=b1r, acc2=b1r, acc3=b1r;
    {
      const float* src = (i2 == 0) ? k_pk : q_pk;
      #pragma unroll 8
      for (int d=0; d<64; d++){
        float4 s4 = *(const float4*)&src[d*4];
        float w = W1s[d*256 + j];
        acc0 += s4.x*w; acc1 += s4.y*w; acc2 += s4.z*w; acc3 += s4.w*w;
      }
    }
    float x2o0=0.f, x2o1=0.f, qw0r=0.f, qw1r=0.f;
    if (i2 == 0){
      float g0 = geluf(acc0), g1 = geluf(acc1), g2 = geluf(acc2), g3 = geluf(acc3);
      { float4 t4; t4.x=g0; t4.y=g1; t4.z=g2; t4.w=g3;
        *(float4*)&x2_pk[j*4] = t4; }
      { float4 t4; t4.x=gelu_bwdf(acc0); t4.y=gelu_bwdf(acc1);
        t4.z=gelu_bwdf(acc2); t4.w=gelu_bwdf(acc3);
        *(float4*)&gb_pk[j*4] = t4; }
      x2o0 = g0; x2o1 = g1;                       // own rows 0,2 (slots 0,1)
    } else {
      qwx[j*2]   = acc0;                          // qw slot0 (row0) for h0
      qwx[j*2+1] = acc1;                          // qw slot1 (row2) for h0
      qw0r = acc2; qw1r = acc3;                   // own rows 1,3 (slots 2,3)
    }
    __syncthreads();                              // B
    if (i2 == 0){ qw0r = qwx[j*2]; qw1r = qwx[j*2+1]; }
    else { float2 xo = *(const float2*)&x2_pk[j*4+2]; x2o0 = xo.x; x2o1 = xo.y; }
    // --- prefetch next step ---
    float qn=0.f, kn=0.f, vn=0.f, eln=0.f;
    if (n < 63){
      int l2 = (n+1)*4 + iw;
      if (i2 == 0){ qn = xqp[(size_t)l2*256 + cl]; kn = xkp[(size_t)l2*256 + cl]; }
      else        { vn = xvp[(size_t)l2*256 + cl]; }
      if (tid < 4) eln = ep[(n+1)*4 + tid];
    }
    // --- Z2 split-K: seg = iw*2+i2, 32 d's, all 4 rows via slots ---
    {
      int d0 = (iw*2 + i2)*32;
      int seg = iw*2 + i2;
      float p0=0.f,p1=0.f,p2=0.f,p3=0.f;
      #pragma unroll 8
      for (int dd=0; dd<32; dd++){
        float4 x4 = *(const float4*)&x2_pk[(d0+dd)*4];
        float w = W2L[(d0+dd)*65 + cl];
        p0 += x4.x*w; p1 += x4.y*w; p2 += x4.z*w; p3 += x4.w*w;
      }
      pzs[0*576 + cl*9 + seg] = p0;   // slot0 = row0
      pzs[2*576 + cl*9 + seg] = p1;   // slot1 = row2
      pzs[1*576 + cl*9 + seg] = p2;   // slot2 = row1
      pzs[3*576 + cl*9 + seg] = p3;   // slot3 = row3
    }
    __syncthreads();                              // C
    // --- fused LN-L2 backward (half0 wave iw = row iw) ---
    if (i2 == 0){
      float z2 = b2r;
      #pragma unroll
      for (int sg=0; sg<8; sg++) z2 += pzs[iw*576 + cl*9 + sg];
      float mu = wsum64(z2)*(1.f/64.f);
      float df = z2 - mu;
      float var = wsum64(df*df)*(1.f/64.f);
      float stdv = sqrtf(var + 1e-6f);
      float xhat = df/stdv;
      float tgt = v_pk[cl*4 + ps_iw] - kv;
      float gxh = (gr*xhat + br - tgt)*gr;
      float sg1 = wsum64(gxh);
      float sg2 = wsum64(gxh*xhat);
      float gz2 = (64.f*gxh - sg1 - xhat*sg2)*(1.f/(64.f*stdv));
      gz2_pk[cl*4 + ps_iw] = gz2;
    }
    __syncthreads();                              // D0
    // --- gZ1 split-K: half i2 covers c in [i2*32, i2*32+32) ---
    float gd0=0.f, gd1=0.f, gd2=0.f, gd3=0.f;
    {
      int cb = i2*32;
      #pragma unroll 8
      for (int cc=0; cc<32; cc++){
        float4 g4 = *(const float4*)&gz2_pk[(cb+cc)*4];
        float w = W2L[j*65 + cb + cc];
        gd0 += g4.x*w; gd1 += g4.y*w; gd2 += g4.z*w; gd3 += g4.w*w;
      }
      float4 t4; t4.x=gd0; t4.y=gd1; t4.z=gd2; t4.w=gd3;
      *(float4*)&pzs[i2*1024 + j*4] = t4;         // gzx alias on pzs
    }
    __syncthreads();                              // D1
    {
      float4 po = *(const float4*)&pzs[(1-i2)*1024 + j*4];
      gd0 += po.x; gd1 += po.y; gd2 += po.z; gd3 += po.w;
    }
    float4 gb4 = *(const float4*)&gb_pk[j*4];
    float4 gz14;
    gz14.x = gd0*gb4.x; gz14.y = gd1*gb4.y;
    gz14.z = gd2*gb4.z; gz14.w = gd3*gb4.w;       // slots 0,2,1,3
    // --- Z1b/X2b rows (i2, i2+2) ---
    int R0 = i2, R1 = i2 + 2;
    float zb0 = qw0r - (coefs[R0*4+0]*gz14.x + coefs[R0*4+2]*gz14.y
                      + coefs[R0*4+1]*gz14.z + coefs[R0*4+3]*gz14.w);
    float zb1 = qw1r - (coefs[R1*4+0]*gz14.x + coefs[R1*4+2]*gz14.y
                      + coefs[R1*4+1]*gz14.z + coefs[R1*4+3]*gz14.w);
    float xb0 = geluf(zb0), xb1 = geluf(zb1);
    { float2 t; t.x=xb0; t.y=xb1; *(float2*)&x2b_pk[j*4 + i2*2] = t; }
    // --- W1 + b1 update ---
    float le_s0 = tok3*els[0], le_s1 = tok3*els[2], le_s2 = tok3*els[1], le_s3 = tok3*els[3];
    {
      float lg0 = le_s0*gz14.x, lg1v = le_s1*gz14.y, lg2 = le_s2*gz14.z, lg3 = le_s3*gz14.w;
      int d0 = i2*32;
      #pragma unroll 8
      for (int dd=0; dd<32; dd++){
        float4 k4 = *(const float4*)&k_pk[(d0+dd)*4];
        W1s[(d0+dd)*256 + j] -= lg0*k4.x + lg1v*k4.y + lg2*k4.z + lg3*k4.w;
      }
      b1r -= lg0 + lg1v + lg2 + lg3;
    }
    // --- A2 masked products, split 4/6 across halves ---
    if (i2 == 0){
      float xo1 = x2_pk[j*4 + 2];                 // row1
      float s00 = wsum64(xb0*x2o0);               // (0,0)
      float s20 = wsum64(xb1*x2o0);               // (2,0)
      float s22 = wsum64(xb1*x2o1);               // (2,2)
      float s21 = wsum64(xb1*xo1);                // (2,1)
      if (cl == 0){
        a2w[iw*16+0]  = s00;
        a2w[iw*16+8]  = s20;
        a2w[iw*16+10] = s22;
        a2w[iw*16+9]  = s21;
      }
    } else {
      float2 xo02 = *(const float2*)&x2_pk[j*4];  // rows 0,2
      float s11 = wsum64(xb0*x2o0);               // (1,1)
      float s10 = wsum64(xb0*xo02.x);             // (1,0)
      float s31 = wsum64(xb1*x2o0);               // (3,1)
      float s33 = wsum64(xb1*x2o1);               // (3,3)
      float s30 = wsum64(xb1*xo02.x);             // (3,0)
      float s32 = wsum64(xb1*xo02.y);             // (3,2)
      if (cl == 0){
        a2w[iw*16+5]  = s11;
        a2w[iw*16+4]  = s10;
        a2w[iw*16+13] = s31;
        a2w[iw*16+15] = s33;
        a2w[iw*16+12] = s30;
        a2w[iw*16+14] = s32;
      }
    }
    __syncthreads();                              // E
    if (tid < 16){
      int ii = tid >> 2, rr = tid & 3;
      float s = a2w[tid] + a2w[16+tid] + a2w[32+tid] + a2w[48+tid];
      coef2s[tid] = (rr <= ii) ? toks_s[ii]*els[rr]*(s + 1.f) : 0.f;
    }
    // --- Z2b split-K ---
    {
      int d0 = (iw*2 + i2)*32;
      int seg = iw*2 + i2;
      float p0=0.f,p1=0.f,p2=0.f,p3=0.f;
      #pragma unroll 8
      for (int dd=0; dd<32; dd++){
        float4 x4 = *(const float4*)&x2b_pk[(d0+dd)*4];
        float w = W2L[(d0+dd)*65 + cl];
        p0 += x4.x*w; p1 += x4.y*w; p2 += x4.z*w; p3 += x4.w*w;
      }
      pzs[0*576 + cl*9 + seg] = p0;
      pzs[2*576 + cl*9 + seg] = p1;
      pzs[1*576 + cl*9 + seg] = p2;
      pzs[3*576 + cl*9 + seg] = p3;
    }
    __syncthreads();                              // F
    // --- ln_fwd + output (half0) ---
    if (i2 == 0){
      float z2b = b2r;
      #pragma unroll
      for (int sg=0; sg<8; sg++) z2b += pzs[iw*576 + cl*9 + sg];
      float4 g4r = *(const float4*)&gz2_pk[cl*4];
      z2b -= coef2s[iw*4+0]*g4r.x + coef2s[iw*4+2]*g4r.y
           + coef2s[iw*4+1]*g4r.z + coef2s[iw*4+3]*g4r.w;
      float mu2 = wsum64(z2b)*(1.f/64.f);
      float df2 = z2b - mu2;
      float var2 = wsum64(df2*df2)*(1.f/64.f);
      float lnv = gr*df2*rsqrtf(var2 + 1e-6f) + br;
      out[((size_t)b*256 + n*4 + iw)*256 + h*64 + cl] = qv + lnv;
    }
    // --- W2 + b2 update ---
    float4 xb4 = *(const float4*)&x2b_pk[j*4];    // slots
    float lx0 = le_s0*xb4.x, lx1 = le_s1*xb4.y, lx2 = le_s2*xb4.z, lx3 = le_s3*xb4.w;
    {
      int c0 = i2*32;
      #pragma unroll 8
      for (int cc=0; cc<32; cc++){
        float4 g4 = *(const float4*)&gz2_pk[(c0+cc)*4];
        W2L[j*65 + c0+cc] -= lx0*g4.x + lx1*g4.y + lx2*g4.z + lx3*g4.w;
      }
    }
    {
      float4 g4r = *(const float4*)&gz2_pk[cl*4];
      b2r -= le_s0*g4r.x + le_s1*g4r.y + le_s2*g4r.z + le_s3*g4r.w;
    }
    __syncthreads();                              // G
    qv = qn; kv = kn; vv = vn; elv = eln;
  }
}

// Fused head: LN(post) -> @wo -> LN(ln) -> fc1 -> fc2 -> fc3. grid 512 rows.
__global__ __launch_bounds__(256) void k_head(const float* __restrict__ hid2,
    const float* __restrict__ pg, const float* __restrict__ pb,
    const float* __restrict__ wo, const float* __restrict__ lg,
    const float* __restrict__ lb, const float* __restrict__ fcw,
    const float* __restrict__ fcb, const float* __restrict__ fc2w,
    const float* __restrict__ fc2b, const float* __restrict__ fc3w,
    const float* __restrict__ fc3b, float* __restrict__ outp){
  int row = blockIdx.x, c = threadIdx.x;
  __shared__ float t1[256];
  __shared__ float t3[256];
  __shared__ float t4[128];
  __shared__ float t5[64];
  __shared__ float rs[4];
  __shared__ float rq[4];
  int wv = c >> 6, ln = c & 63;
  float v = hid2[(size_t)row*256 + c];
  float s1 = wsum64(v), s2 = wsum64(v*v);
  if (ln == 0){ rs[wv]=s1; rq[wv]=s2; }
  __syncthreads();
  float mu = (rs[0]+rs[1]+rs[2]+rs[3])*(1.f/256.f);
  float msq = (rq[0]+rq[1]+rq[2]+rq[3])*(1.f/256.f);
  float var = msq - mu*mu;
  t1[c] = (v-mu)*rsqrtf(var + 1e-5f)*pg[c] + pb[c];
  __syncthreads();
  float a = 0.f;
  for (int k=0;k<256;k++) a += t1[k]*wo[(size_t)k*256 + c];
  float u1 = wsum64(a), u2 = wsum64(a*a);
  if (ln == 0){ rs[wv]=u1; rq[wv]=u2; }
  __syncthreads();
  mu = (rs[0]+rs[1]+rs[2]+rs[3])*(1.f/256.f);
  msq = (rq[0]+rq[1]+rq[2]+rq[3])*(1.f/256.f);
  var = msq - mu*mu;
  t3[c] = (a-mu)*rsqrtf(var + 1e-5f)*lg[c] + lb[c];
  __syncthreads();
  if (c < 128){
    float s = fcb[c];
    for (int k=0;k<256;k++) s += t3[k]*fcw[(size_t)k*128 + c];
    t4[c] = s;
  }
  __syncthreads();
  if (c < 64){
    float s = fc2b[c];
    for (int k=0;k<128;k++) s += t4[k]*fc2w[(size_t)k*64 + c];
    t5[c] = s;
  }
  __syncthreads();
  if (c < 64){
    float p = t5[c]*fc3w[c];
    p = wsum64(p);
    if (c == 0) outp[row] = p + fc3b[0];
  }
}

extern "C" void kernel_launch(void* const* d_in, const int* in_sizes, int n_in,
                              void* d_out, int out_size, void* d_ws, size_t ws_size,
                              hipStream_t stream){
  (void)in_sizes; (void)n_in; (void)out_size; (void)ws_size;
  const float* x       = (const float*)d_in[0];
  const float* s11_w   = (const float*)d_in[1];
  const float* s11_b   = (const float*)d_in[2];
  const float* bn11    = (const float*)d_in[3];
  const float* s12_w   = (const float*)d_in[4];
  const float* s12_b   = (const float*)d_in[5];
  const float* bn12    = (const float*)d_in[6];
  const float* s21_w   = (const float*)d_in[7];
  const float* s21_b   = (const float*)d_in[8];
  const float* bn21    = (const float*)d_in[9];
  const float* s22_w   = (const float*)d_in[10];
  const float* s22_b   = (const float*)d_in[11];
  const float* bn22    = (const float*)d_in[12];
  const float* s3_w    = (const float*)d_in[13];
  const float* s3_b    = (const float*)d_in[14];
  const float* bn3     = (const float*)d_in[15];
  const float* c1_w    = (const float*)d_in[16];
  const float* c1_b    = (const float*)d_in[17];
  const float* cb_w    = (const float*)d_in[18];
  const float* cb_b    = (const float*)d_in[19];
  const float* ln_g    = (const float*)d_in[20];
  const float* ln_b    = (const float*)d_in[21];
  const float* wq      = (const float*)d_in[22];
  const float* wk      = (const float*)d_in[23];
  const float* wv      = (const float*)d_in[24];
  const float* wo      = (const float*)d_in[25];
  const float* lr_w    = (const float*)d_in[26];
  const float* lr_b    = (const float*)d_in[27];
  const float* tib     = (const float*)d_in[28];
  const float* tlnw    = (const float*)d_in[29];
  const float* tlnb    = (const float*)d_in[30];
  const float* W1      = (const float*)d_in[31];
  const float* B1      = (const float*)d_in[32];
  const float* W2      = (const float*)d_in[33];
  const float* B2      = (const float*)d_in[34];
  const float* post_g  = (const float*)d_in[35];
  const float* post_b  = (const float*)d_in[36];
  const float* fc_w    = (const float*)d_in[37];
  const float* fc_b    = (const float*)d_in[38];
  const float* fc2_w   = (const float*)d_in[39];
  const float* fc2_b   = (const float*)d_in[40];
  const float* fc3_w   = (const float*)d_in[41];
  const float* fc3_b   = (const float*)d_in[42];

  float* ws = (float*)d_ws;
  float* xs   = ws;                       // 2359296
  float* xd   = ws + 2359296;             // 2359296
  float* p1   = ws + 4718592;             // 1179648 (pm)
  float* sig  = ws + 7077888;             // 32768
  float* buf0 = ws + 7110656;             // 131072
  float* buf1 = ws + 7241728;             // 131072
  float* accb = ws + 7372800;             // 131072
  float* xqb  = ws + 7634944;             // 131072
  float* xkb  = ws + 7766016;             // 131072
  float* xvb  = ws + 7897088;             // 131072
  float* eta  = ws + 8028160;             // 2048
  float* hid2 = ws + 8030208;             // 131072

  k_stem<<<3072, 192, 0, stream>>>(x, s11_w, s11_b, bn11, xs,
                                   s12_w, s12_b, bn12, xd);
  k_s2m<<<512, 576, 0, stream>>>(xs, xd, s21_w, s21_b, bn21,
                                 s22_w, s22_b, bn22, p1);
  k_s3<<<512, 256, 0, stream>>>(p1, s3_w, s3_b, bn3, sig);
  k_c1<<<512, 256, 0, stream>>>(sig, c1_w, c1_b, buf0);
  {
    float* cin = buf0; float* cout = buf1;
    for (int l=0; l<8; l++){
      int mode = (l == 1) ? 1 : ((l & 1) ? 2 : 0);
      k_conv1d<<<512, 256, 0, stream>>>(cin, cb_w + (size_t)l*196608,
                                        cb_b + l*256, cout, accb, mode);
      float* tmp = cin; cin = cout; cout = tmp;
    }
  }
  k_lnproj<<<512, 256, 0, stream>>>(accb, ln_g, ln_b, wq, wk, wv,
                                    lr_w, lr_b, xqb, xkb, xvb, eta);
  k_ttt<<<8, 512, 0, stream>>>(xqb, xkb, xvb, eta, tib, tlnw, tlnb,
                               W1, B1, W2, B2, hid2);
  k_head<<<512, 256, 0, stream>>>(hid2, post_g, post_b, wo, ln_g, ln_b,
                                  fc_w, fc_b, fc2_w, fc2_b, fc3_w, fc3_b,
                                  (float*)d_out);
}

// Round 14
// 1477.676 us; speedup vs baseline: 1.1939x; 1.1207x over previous
//
#include <hip/hip_runtime.h>
#include <hip/hip_bf16.h>
#include <math.h>

#define DEV __device__ __forceinline__

DEV float wsum64(float v){
  #pragma unroll
  for (int off = 32; off; off >>= 1) v += __shfl_xor(v, off, 64);
  return v;
}
DEV float geluf(float x){
  return 0.5f*x*(1.f + tanhf(0.7978845608028654f*(x + 0.044715f*x*x*x)));
}
DEV float gelu_bwdf(float x){
  float x2 = x*x;
  float t = tanhf(0.79788456f*x*(1.f + 0.044715f*x2));
  return 0.5f*x*((1.f - t*t)*(0.79788456f + 0.1070322243f*x2)) + 0.5f*(1.f + t);
}
DEV float sigmf(float x){ return 1.f/(1.f + expf(-x)); }

// ---------------------------------------------------------------------------
// Merged stem, per-channel staging (st = one channel: 37x108, 16KB ->
// 4 blocks/CU). Blocks [0,1536): s11; [1536,3072): s12 on frame diffs.
__global__ __launch_bounds__(192) void k_stem(const float* __restrict__ x,
    const float* __restrict__ w11, const float* __restrict__ b11,
    const float* __restrict__ bn11p, float* __restrict__ xs,
    const float* __restrict__ w12, const float* __restrict__ b12,
    const float* __restrict__ bn12p, float* __restrict__ xd){
  __shared__ float st[37*108];      // 3996 floats (one channel)
  __shared__ float wl[49*12*8];     // 4704 (s11 uses first 1176)
  int t = threadIdx.x;
  int pr = t / 24, pc = t - pr*24;
  float a00[8], a01[8], a10[8], a11[8];
  #pragma unroll
  for (int c=0;c<8;c++){ a00[c]=0.f; a01[c]=0.f; a10[c]=0.f; a11[c]=0.f; }
  if (blockIdx.x < 1536){
    // ---------------- s11 ----------------
    int bx = blockIdx.x;
    int bd = bx / 3, g = bx - bd*3;
    for (int e = t; e < 1176; e += 192){
      int tap = e / 24, r = e - tap*24, ci = r >> 3, c = r & 7;
      wl[e] = w11[(c*3 + ci)*49 + tap];
    }
    const float* xb = x + (size_t)bd*3*9216;
    for (int ci=0; ci<3; ci++){
      __syncthreads();
      for (int e = t; e < 37*102; e += 192){
        int ihl = e / 102, pi = e - ihl*102;
        int ih = ihl + 32*g - 3, iw = pi - 3;
        float v = 0.f;
        if (ih>=0 && ih<96 && iw>=0 && iw<96) v = xb[(size_t)ci*9216 + ih*96 + iw];
        st[ihl*108 + (pi&1)*54 + (pi>>1)] = v;
      }
      __syncthreads();
      for (int kh=0; kh<7; kh++){
        int rb0 = (4*pr + kh)*108 + 2*pc;
        int rb1 = rb0 + 216;
        float2 A0 = *(const float2*)&st[rb0];
        float2 A1 = *(const float2*)&st[rb0+2];
        float  A2 = st[rb0+4];
        float2 B0 = *(const float2*)&st[rb0+54];
        float2 B1 = *(const float2*)&st[rb0+56];
        float2 C0 = *(const float2*)&st[rb1];
        float2 C1 = *(const float2*)&st[rb1+2];
        float  C2 = st[rb1+4];
        float2 D0 = *(const float2*)&st[rb1+54];
        float2 D1 = *(const float2*)&st[rb1+56];
        float v00[7], v01[7], v10[7], v11[7];
        v00[0]=A0.x; v01[0]=A0.y; v10[0]=C0.x; v11[0]=C0.y;
        v00[1]=B0.x; v01[1]=B0.y; v10[1]=D0.x; v11[1]=D0.y;
        v00[2]=A0.y; v01[2]=A1.x; v10[2]=C0.y; v11[2]=C1.x;
        v00[3]=B0.y; v01[3]=B1.x; v10[3]=D0.y; v11[3]=D1.x;
        v00[4]=A1.x; v01[4]=A1.y; v10[4]=C1.x; v11[4]=C1.y;
        v00[5]=B1.x; v01[5]=B1.y; v10[5]=D1.x; v11[5]=D1.y;
        v00[6]=A1.y; v01[6]=A2;   v10[6]=C1.y; v11[6]=C2;
        #pragma unroll
        for (int kw=0; kw<7; kw++){
          const float4* wp = (const float4*)&wl[((kh*7+kw)*3 + ci)*8];
          float wv[8];
          *(float4*)&wv[0] = wp[0]; *(float4*)&wv[4] = wp[1];
          #pragma unroll
          for (int c=0;c<8;c++){
            a00[c] += v00[kw]*wv[c]; a01[c] += v01[kw]*wv[c];
            a10[c] += v10[kw]*wv[c]; a11[c] += v11[kw]*wv[c];
          }
        }
      }
    }
    int pos = (g*8 + pr)*24 + pc;
    #pragma unroll
    for (int c=0;c<8;c++){
      float gg=bn11p[c], be=bn11p[8+c], m=bn11p[16+c], vv=bn11p[24+c];
      float s = gg*rsqrtf(vv + 1e-5f);
      float bi = b11[c];
      float mx = 0.f;
      mx = fmaxf(mx, (a00[c]+bi-m)*s+be);
      mx = fmaxf(mx, (a01[c]+bi-m)*s+be);
      mx = fmaxf(mx, (a10[c]+bi-m)*s+be);
      mx = fmaxf(mx, (a11[c]+bi-m)*s+be);
      xs[((size_t)bd*8 + c)*576 + pos] = mx;
    }
  } else {
    // ---------------- s12 ----------------
    int bx = blockIdx.x - 1536;
    int bd = bx / 3, g = bx - bd*3;
    int b = bd >> 8, dd = bd & 255;
    for (int e = t; e < 4704; e += 192){
      int tap = e / 96, r = e - tap*96, ci = r >> 3, c = r & 7;
      wl[e] = w12[(c*12 + ci)*49 + tap];
    }
    int fa[4], fb[4];
    fa[0] = dd>=2 ? dd-1 : 0;     fb[0] = dd>=2 ? dd-2 : 0;
    fa[1] = dd;                   fb[1] = dd>=1 ? dd-1 : 0;
    fa[2] = dd<=254 ? dd+1 : 255; fb[2] = dd;
    fa[3] = dd<=253 ? dd+2 : 255; fb[3] = dd<=254 ? dd+1 : 255;
    for (int g4=0; g4<4; g4++){
      if (fa[g4] == fb[g4]) continue;   // zero diff, uniform per block
      const float* xa = x + ((size_t)(b*256 + fa[g4]))*3*9216;
      const float* xbp= x + ((size_t)(b*256 + fb[g4]))*3*9216;
      for (int rgb=0; rgb<3; rgb++){
        int gch = g4*3 + rgb;
        __syncthreads();
        for (int e = t; e < 37*102; e += 192){
          int ihl = e / 102, pi = e - ihl*102;
          int ih = ihl + 32*g - 3, iw = pi - 3;
          float v = 0.f;
          if (ih>=0 && ih<96 && iw>=0 && iw<96){
            size_t off = (size_t)rgb*9216 + ih*96 + iw;
            v = xa[off] - xbp[off];
          }
          st[ihl*108 + (pi&1)*54 + (pi>>1)] = v;
        }
        __syncthreads();
        for (int kh=0; kh<7; kh++){
          int rb0 = (4*pr + kh)*108 + 2*pc;
          int rb1 = rb0 + 216;
          float2 A0 = *(const float2*)&st[rb0];
          float2 A1 = *(const float2*)&st[rb0+2];
          float  A2 = st[rb0+4];
          float2 B0 = *(const float2*)&st[rb0+54];
          float2 B1 = *(const float2*)&st[rb0+56];
          float2 C0 = *(const float2*)&st[rb1];
          float2 C1 = *(const float2*)&st[rb1+2];
          float  C2 = st[rb1+4];
          float2 D0 = *(const float2*)&st[rb1+54];
          float2 D1 = *(const float2*)&st[rb1+56];
          float v00[7], v01[7], v10[7], v11[7];
          v00[0]=A0.x; v01[0]=A0.y; v10[0]=C0.x; v11[0]=C0.y;
          v00[1]=B0.x; v01[1]=B0.y; v10[1]=D0.x; v11[1]=D0.y;
          v00[2]=A0.y; v01[2]=A1.x; v10[2]=C0.y; v11[2]=C1.x;
          v00[3]=B0.y; v01[3]=B1.x; v10[3]=D0.y; v11[3]=D1.x;
          v00[4]=A1.x; v01[4]=A1.y; v10[4]=C1.x; v11[4]=C1.y;
          v00[5]=B1.x; v01[5]=B1.y; v10[5]=D1.x; v11[5]=D1.y;
          v00[6]=A1.y; v01[6]=A2;   v10[6]=C1.y; v11[6]=C2;
          #pragma unroll
          for (int kw=0; kw<7; kw++){
            const float4* wp = (const float4*)&wl[((kh*7+kw)*12 + gch)*8];
            float wv[8];
            *(float4*)&wv[0] = wp[0]; *(float4*)&wv[4] = wp[1];
            #pragma unroll
            for (int c=0;c<8;c++){
              a00[c] += v00[kw]*wv[c]; a01[c] += v01[kw]*wv[c];
              a10[c] += v10[kw]*wv[c]; a11[c] += v11[kw]*wv[c];
            }
          }
        }
      }
    }
    int pos = (g*8 + pr)*24 + pc;
    #pragma unroll
    for (int c=0;c<8;c++){
      float gg=bn12p[c], be=bn12p[8+c], m=bn12p[16+c], vv=bn12p[24+c];
      float s = gg*rsqrtf(vv + 1e-5f);
      float bi = b12[c];
      float mx = 0.f;
      mx = fmaxf(mx, (a00[c]+bi-m)*s+be);
      mx = fmaxf(mx, (a01[c]+bi-m)*s+be);
      mx = fmaxf(mx, (a10[c]+bi-m)*s+be);
      mx = fmaxf(mx, (a11[c]+bi-m)*s+be);
      xd[((size_t)bd*8 + c)*576 + pos] = mx;
    }
  }
}

// Merged s21+s22, 576 threads = 144 pos x 4 channel-quads. Tile stride 34.
__global__ __launch_bounds__(576) void k_s2m(const float* __restrict__ xs,
    const float* __restrict__ xd,
    const float* __restrict__ w1, const float* __restrict__ b1,
    const float* __restrict__ bn1,
    const float* __restrict__ w2, const float* __restrict__ b2,
    const float* __restrict__ bn2, float* __restrict__ pm){
  __shared__ float st[8*30*34];     // 8160
  __shared__ float wl[49*8*16];     // 6272
  int bd = blockIdx.x;
  int t = threadIdx.x;
  int quad = t / 144;
  int pos = t - quad*144;
  int pr = pos / 12, pc = pos - pr*12;
  const float* pa = xs + (size_t)bd*8*576;
  const float* pb = xd + (size_t)bd*8*576;
  float r1[4];
  for (int e = t; e < 6272; e += 576){
    int tap = e >> 7, r = e & 127, ci = r >> 4, c = r & 15;
    wl[e] = w1[(c*8 + ci)*49 + tap];
  }
  for (int e = t; e < 8160; e += 576){
    int ci = e / 1020, r2 = e - ci*1020;
    int r = r2 / 34, cc = r2 - r*34;
    int ih = r - 3, iw = cc - 3;
    float v = 0.f;
    if (ih>=0 && ih<24 && iw>=0 && iw<24){
      int off = ci*576 + ih*24 + iw;
      v = 0.5f*(pa[off] + pb[off]);
    }
    st[(ci*30 + r)*34 + cc] = v;
  }
  __syncthreads();
  {
    float a00[4], a01[4], a10[4], a11[4];
    #pragma unroll
    for (int c=0;c<4;c++){ a00[c]=0.f; a01[c]=0.f; a10[c]=0.f; a11[c]=0.f; }
    for (int ci=0; ci<8; ci++){
      for (int kh=0; kh<7; kh++){
        int rb = (ci*30 + 2*pr + kh)*34 + 2*pc;
        float2 E0 = *(const float2*)&st[rb];
        float2 E1 = *(const float2*)&st[rb+2];
        float2 E2 = *(const float2*)&st[rb+4];
        float2 E3 = *(const float2*)&st[rb+6];
        float2 F0 = *(const float2*)&st[rb+34];
        float2 F1 = *(const float2*)&st[rb+36];
        float2 F2 = *(const float2*)&st[rb+38];
        float2 F3 = *(const float2*)&st[rb+40];
        float v00[7], v01[7], v10[7], v11[7];
        v00[0]=E0.x; v01[0]=E0.y; v10[0]=F0.x; v11[0]=F0.y;
        v00[1]=E0.y; v01[1]=E1.x; v10[1]=F0.y; v11[1]=F1.x;
        v00[2]=E1.x; v01[2]=E1.y; v10[2]=F1.x; v11[2]=F1.y;
        v00[3]=E1.y; v01[3]=E2.x; v10[3]=F1.y; v11[3]=F2.x;
        v00[4]=E2.x; v01[4]=E2.y; v10[4]=F2.x; v11[4]=F2.y;
        v00[5]=E2.y; v01[5]=E3.x; v10[5]=F2.y; v11[5]=F3.x;
        v00[6]=E3.x; v01[6]=E3.y; v10[6]=F3.x; v11[6]=F3.y;
        #pragma unroll
        for (int kw=0; kw<7; kw++){
          float4 w4 = *(const float4*)&wl[((kh*7+kw)*8 + ci)*16 + quad*4];
          float wv[4];
          *(float4*)&wv[0] = w4;
          #pragma unroll
          for (int c=0;c<4;c++){
            a00[c] += v00[kw]*wv[c]; a01[c] += v01[kw]*wv[c];
            a10[c] += v10[kw]*wv[c]; a11[c] += v11[kw]*wv[c];
          }
        }
      }
    }
    #pragma unroll
    for (int c=0;c<4;c++){
      int c2 = quad*4 + c;
      float gg=bn1[c2], be=bn1[16+c2], m=bn1[32+c2], vv=bn1[48+c2];
      float s = gg*rsqrtf(vv + 1e-5f);
      float bi = b1[c2];
      float mx = 0.f;
      mx = fmaxf(mx, (a00[c]+bi-m)*s+be);
      mx = fmaxf(mx, (a01[c]+bi-m)*s+be);
      mx = fmaxf(mx, (a10[c]+bi-m)*s+be);
      mx = fmaxf(mx, (a11[c]+bi-m)*s+be);
      r1[c] = mx;
    }
  }
  __syncthreads();
  for (int e = t; e < 6272; e += 576){
    int tap = e >> 7, r = e & 127, ci = r >> 4, c = r & 15;
    wl[e] = w2[(c*8 + ci)*49 + tap];
  }
  for (int e = t; e < 8160; e += 576){
    int ci = e / 1020, r2 = e - ci*1020;
    int r = r2 / 34, cc = r2 - r*34;
    int ih = r - 3, iw = cc - 3;
    float v = 0.f;
    if (ih>=0 && ih<24 && iw>=0 && iw<24)
      v = pb[ci*576 + ih*24 + iw];
    st[(ci*30 + r)*34 + cc] = v;
  }
  __syncthreads();
  {
    float a00[4], a01[4], a10[4], a11[4];
    #pragma unroll
    for (int c=0;c<4;c++){ a00[c]=0.f; a01[c]=0.f; a10[c]=0.f; a11[c]=0.f; }
    for (int ci=0; ci<8; ci++){
      for (int kh=0; kh<7; kh++){
        int rb = (ci*30 + 2*pr + kh)*34 + 2*pc;
        float2 E0 = *(const float2*)&st[rb];
        float2 E1 = *(const float2*)&st[rb+2];
        float2 E2 = *(const float2*)&st[rb+4];
        float2 E3 = *(const float2*)&st[rb+6];
        float2 F0 = *(const float2*)&st[rb+34];
        float2 F1 = *(const float2*)&st[rb+36];
        float2 F2 = *(const float2*)&st[rb+38];
        float2 F3 = *(const float2*)&st[rb+40];
        float v00[7], v01[7], v10[7], v11[7];
        v00[0]=E0.x; v01[0]=E0.y; v10[0]=F0.x; v11[0]=F0.y;
        v00[1]=E0.y; v01[1]=E1.x; v10[1]=F0.y; v11[1]=F1.x;
        v00[2]=E1.x; v01[2]=E1.y; v10[2]=F1.x; v11[2]=F1.y;
        v00[3]=E1.y; v01[3]=E2.x; v10[3]=F1.y; v11[3]=F2.x;
        v00[4]=E2.x; v01[4]=E2.y; v10[4]=F2.x; v11[4]=F2.y;
        v00[5]=E2.y; v01[5]=E3.x; v10[5]=F2.y; v11[5]=F3.x;
        v00[6]=E3.x; v01[6]=E3.y; v10[6]=F3.x; v11[6]=F3.y;
        #pragma unroll
        for (int kw=0; kw<7; kw++){
          float4 w4 = *(const float4*)&wl[((kh*7+kw)*8 + ci)*16 + quad*4];
          float wv[4];
          *(float4*)&wv[0] = w4;
          #pragma unroll
          for (int c=0;c<4;c++){
            a00[c] += v00[kw]*wv[c]; a01[c] += v01[kw]*wv[c];
            a10[c] += v10[kw]*wv[c]; a11[c] += v11[kw]*wv[c];
          }
        }
      }
    }
    #pragma unroll
    for (int c=0;c<4;c++){
      int c2 = quad*4 + c;
      float gg=bn2[c2], be=bn2[16+c2], m=bn2[32+c2], vv=bn2[48+c2];
      float s = gg*rsqrtf(vv + 1e-5f);
      float bi = b2[c2];
      float mx = 0.f;
      mx = fmaxf(mx, (a00[c]+bi-m)*s+be);
      mx = fmaxf(mx, (a01[c]+bi-m)*s+be);
      mx = fmaxf(mx, (a10[c]+bi-m)*s+be);
      mx = fmaxf(mx, (a11[c]+bi-m)*s+be);
      pm[((size_t)bd*16 + c2)*144 + pr*12 + pc] = 0.5f*(r1[c] + mx);
    }
  }
}

// s3 conv3x3 p1 + BN + attention-mask pooled signal. Input pm (pre-averaged).
__global__ __launch_bounds__(256) void k_s3(const float* __restrict__ pm,
    const float* __restrict__ w,
    const float* __restrict__ bias, const float* __restrict__ bn,
    float* __restrict__ sig){
  __shared__ float ins[16*14*14];
  __shared__ float wT[144*64];
  __shared__ float redS[64*4];
  __shared__ float redF[64*4];
  int bd = blockIdx.x;
  int t = threadIdx.x;
  for (int i = t; i < 16*196; i += 256){
    int ci = i/196, r = i - ci*196, y = r/14, xx = r - y*14;
    float v = 0.f;
    if (y>=1 && y<=12 && xx>=1 && xx<=12){
      size_t idx = ((size_t)bd*16 + ci)*144 + (y-1)*12 + (xx-1);
      v = pm[idx];
    }
    ins[i] = v;
  }
  for (int i = t; i < 9216; i += 256){
    int c = i & 63, k = i >> 6;
    wT[i] = w[c*144 + k];
  }
  __syncthreads();
  int c = t & 63, pg = t >> 6;
  float acc[36];
  #pragma unroll
  for (int pp=0;pp<36;pp++) acc[pp]=0.f;
  for (int k=0; k<144; k++){
    int ci = k/9, kk = k - ci*9, kh = kk/3, kw = kk - kh*3;
    float wv = wT[k*64 + c];
    const float* ip = &ins[ci*196];
    #pragma unroll
    for (int pp=0;pp<36;pp++){
      int y = pg*3 + pp/12, xx = pp%12;
      acc[pp] += ip[(y+kh)*14 + (xx+kw)] * wv;
    }
  }
  float g=bn[c], be=bn[64+c], m=bn[128+c], vv=bn[192+c];
  float s = g*rsqrtf(vv + 1e-5f);
  float bi = bias[c];
  float sS = 0.f, sF = 0.f;
  #pragma unroll
  for (int pp=0;pp<36;pp++){
    float f = (acc[pp] + bi - m)*s + be;
    float sg = sigmf(f);
    sS += sg; sF += f*sg;
  }
  redS[c*4+pg] = sS; redF[c*4+pg] = sF;
  __syncthreads();
  if (t < 64){
    float S = redS[t*4]+redS[t*4+1]+redS[t*4+2]+redS[t*4+3];
    float F = redF[t*4]+redF[t*4+1]+redF[t*4+2]+redF[t*4+3];
    sig[(size_t)bd*64 + t] = 0.5f*F/S;
  }
}

// c1 1x1 conv: sig[b,t,64] -> h[b,256,256] (channel-major). block=(b,o). grid 512.
__global__ __launch_bounds__(256) void k_c1(const float* __restrict__ sig,
    const float* __restrict__ w, const float* __restrict__ bias,
    float* __restrict__ h){
  int b = blockIdx.x >> 8, o = blockIdx.x & 255, tt = threadIdx.x;
  __shared__ float wl[64];
  if (tt < 64) wl[tt] = w[o*64 + tt];
  __syncthreads();
  const float4* sp = (const float4*)(sig + ((size_t)(b*256 + tt))*64);
  const float4* wp = (const float4*)wl;
  float a = bias[o];
  #pragma unroll
  for (int i=0;i<16;i++){
    float4 s4 = sp[i]; float4 w4 = wp[i];
    a += s4.x*w4.x + s4.y*w4.y + s4.z*w4.z + s4.w*w4.w;
  }
  h[((size_t)b*256 + o)*256 + tt] = fmaxf(a, 0.f);
}

// conv1d 256->256 k3 p1 + relu. 512 blocks (8 outch each) for 2 blocks/CU.
// mode: 0=none 1=acc:=out 2=acc+=out.
__global__ __launch_bounds__(256) void k_conv1d(const float* __restrict__ hin,
    const float* __restrict__ w, const float* __restrict__ bias,
    float* __restrict__ hout, float* __restrict__ accb, int mode){
  __shared__ float ins[256*34];
  __shared__ float ws[8*256*4];    // 8 outch, padded stride-4 taps (32KB)
  int bx = blockIdx.x;
  int b = bx >> 8;
  int rem = bx & 255;
  int og = rem >> 3;               // 32 groups of 8 outch
  int tg = rem & 7;
  int tid = threadIdx.x;
  int t0 = tg*32;
  for (int idx = tid; idx < 256*34; idx += 256){
    int ii = idx/34, jj = idx - ii*34;
    int tglob = t0 - 1 + jj;
    float v = 0.f;
    if (tglob >= 0 && tglob < 256) v = hin[((size_t)b*256 + ii)*256 + tglob];
    ins[idx] = v;
  }
  for (int idx = tid; idx < 6144; idx += 256){
    int q = idx/3;
    ws[q*4 + (idx - q*3)] = w[(size_t)og*6144 + idx];
  }
  __syncthreads();
  int ol = tid >> 5, tl = tid & 31;
  int o = og*8 + ol;
  float a1 = bias[o];
  const float4* w1q = (const float4*)(ws + (size_t)ol*1024);
  for (int i=0;i<256;i++){
    float v0 = ins[i*34 + tl];
    float v1 = ins[i*34 + tl + 1];
    float v2 = ins[i*34 + tl + 2];
    float4 wa = w1q[i];
    a1 += wa.x*v0 + wa.y*v1 + wa.z*v2;
  }
  a1 = fmaxf(a1, 0.f);
  size_t i1 = ((size_t)b*256 + o)*256 + t0 + tl;
  hout[i1] = a1;
  if (mode == 1) accb[i1] = a1;
  else if (mode == 2) accb[i1] += a1;
}

// Fused LN + projections + eta. One block per (b,t) row. grid 512.
__global__ __launch_bounds__(256) void k_lnproj(const float* __restrict__ acc,
    const float* __restrict__ g, const float* __restrict__ be,
    const float* __restrict__ wqp, const float* __restrict__ wkp,
    const float* __restrict__ wvp, const float* __restrict__ lrw,
    const float* __restrict__ lrb, float* __restrict__ xq,
    float* __restrict__ xk, float* __restrict__ xv,
    float* __restrict__ etalr){
  int b = blockIdx.x >> 8, tt = blockIdx.x & 255, c = threadIdx.x;
  __shared__ float hrow[256];
  __shared__ float rs[4];
  __shared__ float rq[4];
  __shared__ float epb[4][4];   // [wave][head]
  int wv_ = c >> 6, ln = c & 63;
  float v = acc[((size_t)b*256 + c)*256 + tt];
  float s1 = wsum64(v), s2 = wsum64(v*v);
  if (ln == 0){ rs[wv_]=s1; rq[wv_]=s2; }
  __syncthreads();
  float mu = (rs[0]+rs[1]+rs[2]+rs[3])*(1.f/256.f);
  float msq = (rq[0]+rq[1]+rq[2]+rq[3])*(1.f/256.f);
  float var = msq - mu*mu;
  float hv = (v-mu)*rsqrtf(var + 1e-5f)*g[c] + be[c];
  hrow[c] = hv;
  __syncthreads();
  {
    float p0 = hv*lrw[c];
    float p1 = hv*lrw[256 + c];
    float p2 = hv*lrw[512 + c];
    float p3 = hv*lrw[768 + c];
    p0 = wsum64(p0); p1 = wsum64(p1); p2 = wsum64(p2); p3 = wsum64(p3);
    if (ln == 0){ epb[wv_][0]=p0; epb[wv_][1]=p1; epb[wv_][2]=p2; epb[wv_][3]=p3; }
  }
  float aq = 0.f, ak = 0.f, av = 0.f;
  for (int k=0;k<256;k++){
    float hk = hrow[k];
    aq += hk*wqp[(size_t)k*256 + c];
    ak += hk*wkp[(size_t)k*256 + c];
    av += hk*wvp[(size_t)k*256 + c];
  }
  size_t row = (size_t)blockIdx.x;
  xq[row*256 + c] = aq;
  xk[row*256 + c] = ak;
  xv[row*256 + c] = av;
  __syncthreads();
  if (c < 4){
    float a = lrb[c] + epb[0][c] + epb[1][c] + epb[2][c] + epb[3][c];
    etalr[((size_t)(b*4 + c))*256 + tt] = 0.1f*sigmf(a)*(1.f/64.f);
  }
}

// TTT-MLP scan, 512 threads. Role/K-split (R11 structure, unchanged).
__global__ __launch_bounds__(512) void k_ttt(
    const float* __restrict__ xq, const float* __restrict__ xk,
    const float* __restrict__ xv, const float* __restrict__ etalr,
    const float* __restrict__ tib, const float* __restrict__ lnw,
    const float* __restrict__ lnb, const float* __restrict__ W1g,
    const float* __restrict__ B1g, const float* __restrict__ W2g,
    const float* __restrict__ B2g, float* __restrict__ out){
  __shared__ float W1s[64*256];                 // [d][j]
  __shared__ float W2L[256*65];                 // [r][c] pitch 65
  __shared__ __align__(16) float k_pk[256];     // [d=64][slot4]
  __shared__ __align__(16) float q_pk[256];
  __shared__ __align__(16) float v_pk[256];
  __shared__ __align__(16) float x2_pk[1024];   // [j=256][slot4]
  __shared__ __align__(16) float x2b_pk[1024];
  __shared__ __align__(16) float gb_pk[1024];   // gelu_bwd(Z1) factors
  __shared__ __align__(16) float gz2_pk[256];   // [cl=64][slot4]
  __shared__ __align__(16) float pzs[4*576];    // partials; aliased as gzx
  __shared__ float qwx[512];                    // qw slots 0,1 exchange
  __shared__ float a2w[64];
  __shared__ float coefs[16];                   // row-indexed [i*4+r]
  __shared__ float coef2s[16];
  __shared__ float els[4];
  __shared__ float toks_s[4];

  int b = blockIdx.x >> 2, h = blockIdx.x & 3;
  int tid = threadIdx.x;
  int j = tid & 255;
  int i2 = tid >> 8;
  int iw = j >> 6, cl = j & 63;
  int ps_iw = ((iw & 1) << 1) | (iw >> 1);      // pslot(iw)

  const float* W1b = W1g + (size_t)h*16384;
  const float* W2b = W2g + (size_t)h*16384;
  for (int i = tid; i < 16384; i += 512) W1s[i] = W1b[i];
  for (int i = tid; i < 16384; i += 512){
    int r = i >> 6, c = i & 63;
    W2L[r*65 + c] = W2b[i];
  }
  float b1r = B1g[h*256 + j];
  float b2r = B2g[h*64 + cl];
  float gr = lnw[h*64 + cl], br = lnb[h*64 + cl];
  if (tid < 4) toks_s[tid] = fmaxf(1.f/(float)(tid+1) + tib[tid], 0.f);
  __syncthreads();
  float tok3 = toks_s[3];
  float tik = toks_s[iw];

  const float* xqp = xq + (size_t)b*65536 + h*64;
  const float* xkp = xk + (size_t)b*65536 + h*64;
  const float* xvp = xv + (size_t)b*65536 + h*64;
  const float* ep  = etalr + (size_t)(b*4 + h)*256;

  float qv=0.f, kv=0.f, vv=0.f, elv=0.f;
  if (i2 == 0){ qv = xqp[(size_t)iw*256 + cl]; kv = xkp[(size_t)iw*256 + cl]; }
  else        { vv = xvp[(size_t)iw*256 + cl]; }
  if (tid < 4) elv = ep[tid];

  for (int n=0; n<64; n++){
    // --- phase 0: stage ---
    if (i2 == 0){ k_pk[cl*4 + ps_iw] = kv; q_pk[cl*4 + ps_iw] = qv; }
    else        { v_pk[cl*4 + ps_iw] = vv; }
    if (tid < 4) els[tid] = elv;
    __syncthreads();                              // A
    // --- A1 (half0 waves; wave iw = row iw) ---
    if (i2 == 0){
      float4 k4a = *(const float4*)&k_pk[cl*4];   // slots = rows 0,2,1,3
      float a0 = wsum64(qv*k4a.x);
      float a1 = wsum64(qv*k4a.y);
      float a2 = wsum64(qv*k4a.z);
      float a3 = wsum64(qv*k4a.w);
      if (cl == 0){
        coefs[iw*4+0] = tik*els[0]*(a0+1.f);
        coefs[iw*4+2] = (iw>=2) ? tik*els[2]*(a1+1.f) : 0.f;
        coefs[iw*4+1] = (iw>=1) ? tik*els[1]*(a2+1.f) : 0.f;
        coefs[iw*4+3] = (iw>=3) ? tik*els[3]*(a3+1.f) : 0.f;
      }
    }
    // --- Z1 producer split: h0 -> z1 (4 slots), h1 -> qw (4 slots) ---
    float acc0=b1r, acc1=b1r, acc2=b1r, acc3=b1r;
    {
      const float* src = (i2 == 0) ? k_pk : q_pk;
      #pragma unroll 8
      for (int d=0; d<64; d++){
        float4 s4 = *(const float4*)&src[d*4];
        float w = W1s[d*256 + j];
        acc0 += s4.x*w; acc1 += s4.y*w; acc2 += s4.z*w; acc3 += s4.w*w;
      }
    }
    float x2o0=0.f, x2o1=0.f, qw0r=0.f, qw1r=0.f;
    if (i2 == 0){
      float g0 = geluf(acc0), g1 = geluf(acc1), g2 = geluf(acc2), g3 = geluf(acc3);
      { float4 t4; t4.x=g0; t4.y=g1; t4.z=g2; t4.w=g3;
        *(float4*)&x2_pk[j*4] = t4; }
      { float4 t4; t4.x=gelu_bwdf(acc0); t4.y=gelu_bwdf(acc1);
        t4.z=gelu_bwdf(acc2); t4.w=gelu_bwdf(acc3);
        *(float4*)&gb_pk[j*4] = t4; }
      x2o0 = g0; x2o1 = g1;                       // own rows 0,2 (slots 0,1)
    } else {
      qwx[j*2]   = acc0;                          // qw slot0 (row0) for h0
      qwx[j*2+1] = acc1;                          // qw slot1 (row2) for h0
      qw0r = acc2; qw1r = acc3;                   // own rows 1,3 (slots 2,3)
    }
    __syncthreads();                              // B
    if (i2 == 0){ qw0r = qwx[j*2]; qw1r = qwx[j*2+1]; }
    else { float2 xo = *(const float2*)&x2_pk[j*4+2]; x2o0 = xo.x; x2o1 = xo.y; }
    // --- prefetch next step ---
    float qn=0.f, kn=0.f, vn=0.f, eln=0.f;
    if (n < 63){
      int l2 = (n+1)*4 + iw;
      if (i2 == 0){ qn = xqp[(size_t)l2*256 + cl]; kn = xkp[(size_t)l2*256 + cl]; }
      else        { vn = xvp[(size_t)l2*256 + cl]; }
      if (tid < 4) eln = ep[(n+1)*4 + tid];
    }
    // --- Z2 split-K: seg = iw*2+i2, 32 d's, all 4 rows via slots ---
    {
      int d0 = (iw*2 + i2)*32;
      int seg = iw*2 + i2;
      float p0=0.f,p1=0.f,p2=0.f,p3=0.f;
      #pragma unroll 8
      for (int dd=0; dd<32; dd++){
        float4 x4 = *(const float4*)&x2_pk[(d0+dd)*4];
        float w = W2L[(d0+dd)*65 + cl];
        p0 += x4.x*w; p1 += x4.y*w; p2 += x4.z*w; p3 += x4.w*w;
      }
      pzs[0*576 + cl*9 + seg] = p0;   // slot0 = row0
      pzs[2*576 + cl*9 + seg] = p1;   // slot1 = row2
      pzs[1*576 + cl*9 + seg] = p2;   // slot2 = row1
      pzs[3*576 + cl*9 + seg] = p3;   // slot3 = row3
    }
    __syncthreads();                              // C
    // --- fused LN-L2 backward (half0 wave iw = row iw) ---
    if (i2 == 0){
      float z2 = b2r;
      #pragma unroll
      for (int sg=0; sg<8; sg++) z2 += pzs[iw*576 + cl*9 + sg];
      float mu = wsum64(z2)*(1.f/64.f);
      float df = z2 - mu;
      float var = wsum64(df*df)*(1.f/64.f);
      float stdv = sqrtf(var + 1e-6f);
      float xhat = df/stdv;
      float tgt = v_pk[cl*4 + ps_iw] - kv;
      float gxh = (gr*xhat + br - tgt)*gr;
      float sg1 = wsum64(gxh);
      float sg2 = wsum64(gxh*xhat);
      float gz2 = (64.f*gxh - sg1 - xhat*sg2)*(1.f/(64.f*stdv));
      gz2_pk[cl*4 + ps_iw] = gz2;
    }
    __syncthreads();                              // D0
    // --- gZ1 split-K: half i2 covers c in [i2*32, i2*32+32) ---
    float gd0=0.f, gd1=0.f, gd2=0.f, gd3=0.f;
    {
      int cb = i2*32;
      #pragma unroll 8
      for (int cc=0; cc<32; cc++){
        float4 g4 = *(const float4*)&gz2_pk[(cb+cc)*4];
        float w = W2L[j*65 + cb + cc];
        gd0 += g4.x*w; gd1 += g4.y*w; gd2 += g4.z*w; gd3 += g4.w*w;
      }
      float4 t4; t4.x=gd0; t4.y=gd1; t4.z=gd2; t4.w=gd3;
      *(float4*)&pzs[i2*1024 + j*4] = t4;         // gzx alias on pzs
    }
    __syncthreads();                              // D1
    {
      float4 po = *(const float4*)&pzs[(1-i2)*1024 + j*4];
      gd0 += po.x; gd1 += po.y; gd2 += po.z; gd3 += po.w;
    }
    float4 gb4 = *(const float4*)&gb_pk[j*4];
    float4 gz14;
    gz14.x = gd0*gb4.x; gz14.y = gd1*gb4.y;
    gz14.z = gd2*gb4.z; gz14.w = gd3*gb4.w;       // slots 0,2,1,3
    // --- Z1b/X2b rows (i2, i2+2) ---
    int R0 = i2, R1 = i2 + 2;
    float zb0 = qw0r - (coefs[R0*4+0]*gz14.x + coefs[R0*4+2]*gz14.y
                      + coefs[R0*4+1]*gz14.z + coefs[R0*4+3]*gz14.w);
    float zb1 = qw1r - (coefs[R1*4+0]*gz14.x + coefs[R1*4+2]*gz14.y
                      + coefs[R1*4+1]*gz14.z + coefs[R1*4+3]*gz14.w);
    float xb0 = geluf(zb0), xb1 = geluf(zb1);
    { float2 t; t.x=xb0; t.y=xb1; *(float2*)&x2b_pk[j*4 + i2*2] = t; }
    // --- W1 + b1 update ---
    float le_s0 = tok3*els[0], le_s1 = tok3*els[2], le_s2 = tok3*els[1], le_s3 = tok3*els[3];
    {
      float lg0 = le_s0*gz14.x, lg1v = le_s1*gz14.y, lg2 = le_s2*gz14.z, lg3 = le_s3*gz14.w;
      int d0 = i2*32;
      #pragma unroll 8
      for (int dd=0; dd<32; dd++){
        float4 k4 = *(const float4*)&k_pk[(d0+dd)*4];
        W1s[(d0+dd)*256 + j] -= lg0*k4.x + lg1v*k4.y + lg2*k4.z + lg3*k4.w;
      }
      b1r -= lg0 + lg1v + lg2 + lg3;
    }
    // --- A2 masked products, split 4/6 across halves ---
    if (i2 == 0){
      float xo1 = x2_pk[j*4 + 2];                 // row1
      float s00 = wsum64(xb0*x2o0);               // (0,0)
      float s20 = wsum64(xb1*x2o0);               // (2,0)
      float s22 = wsum64(xb1*x2o1);               // (2,2)
      float s21 = wsum64(xb1*xo1);                // (2,1)
      if (cl == 0){
        a2w[iw*16+0]  = s00;
        a2w[iw*16+8]  = s20;
        a2w[iw*16+10] = s22;
        a2w[iw*16+9]  = s21;
      }
    } else {
      float2 xo02 = *(const float2*)&x2_pk[j*4];  // rows 0,2
      float s11 = wsum64(xb0*x2o0);               // (1,1)
      float s10 = wsum64(xb0*xo02.x);             // (1,0)
      float s31 = wsum64(xb1*x2o0);               // (3,1)
      float s33 = wsum64(xb1*x2o1);               // (3,3)
      float s30 = wsum64(xb1*xo02.x);             // (3,0)
      float s32 = wsum64(xb1*xo02.y);             // (3,2)
      if (cl == 0){
        a2w[iw*16+5]  = s11;
        a2w[iw*16+4]  = s10;
        a2w[iw*16+13] = s31;
        a2w[iw*16+15] = s33;
        a2w[iw*16+12] = s30;
        a2w[iw*16+14] = s32;
      }
    }
    __syncthreads();                              // E
    if (tid < 16){
      int ii = tid >> 2, rr = tid & 3;
      float s = a2w[tid] + a2w[16+tid] + a2w[32+tid] + a2w[48+tid];
      coef2s[tid] = (rr <= ii) ? toks_s[ii]*els[rr]*(s + 1.f) : 0.f;
    }
    // --- Z2b split-K ---
    {
      int d0 = (iw*2 + i2)*32;
      int seg = iw*2 + i2;
      float p0=0.f,p1=0.f,p2=0.f,p3=0.f;
      #pragma unroll 8
      for (int dd=0; dd<32; dd++){
        float4 x4 = *(const float4*)&x2b_pk[(d0+dd)*4];
        float w = W2L[(d0+dd)*65 + cl];
        p0 += x4.x*w; p1 += x4.y*w; p2 += x4.z*w; p3 += x4.w*w;
      }
      pzs[0*576 + cl*9 + seg] = p0;
      pzs[2*576 + cl*9 + seg] = p1;
      pzs[1*576 + cl*9 + seg] = p2;
      pzs[3*576 + cl*9 + seg] = p3;
    }
    __syncthreads();                              // F
    // --- ln_fwd + output (half0) ---
    if (i2 == 0){
      float z2b = b2r;
      #pragma unroll
      for (int sg=0; sg<8; sg++) z2b += pzs[iw*576 + cl*9 + sg];
      float4 g4r = *(const float4*)&gz2_pk[cl*4];
      z2b -= coef2s[iw*4+0]*g4r.x + coef2s[iw*4+2]*g4r.y
           + coef2s[iw*4+1]*g4r.z + coef2s[iw*4+3]*g4r.w;
      float mu2 = wsum64(z2b)*(1.f/64.f);
      float df2 = z2b - mu2;
      float var2 = wsum64(df2*df2)*(1.f/64.f);
      float lnv = gr*df2*rsqrtf(var2 + 1e-6f) + br;
      out[((size_t)b*256 + n*4 + iw)*256 + h*64 + cl] = qv + lnv;
    }
    // --- W2 + b2 update ---
    float4 xb4 = *(const float4*)&x2b_pk[j*4];    // slots
    float lx0 = le_s0*xb4.x, lx1 = le_s1*xb4.y, lx2 = le_s2*xb4.z, lx3 = le_s3*xb4.w;
    {
      int c0 = i2*32;
      #pragma unroll 8
      for (int cc=0; cc<32; cc++){
        float4 g4 = *(const float4*)&gz2_pk[(c0+cc)*4];
        W2L[j*65 + c0+cc] -= lx0*g4.x + lx1*g4.y + lx2*g4.z + lx3*g4.w;
      }
    }
    {
      float4 g4r = *(const float4*)&gz2_pk[cl*4];
      b2r -= le_s0*g4r.x + le_s1*g4r.y + le_s2*g4r.z + le_s3*g4r.w;
    }
    __syncthreads();                              // G
    qv = qn; kv = kn; vv = vn; elv = eln;
  }
}

// Fused head: LN(post) -> @wo -> LN(ln) -> fc1 -> fc2 -> fc3. grid 512 rows.
__global__ __launch_bounds__(256) void k_head(const float* __restrict__ hid2,
    const float* __restrict__ pg, const float* __restrict__ pb,
    const float* __restrict__ wo, const float* __restrict__ lg,
    const float* __restrict__ lb, const float* __restrict__ fcw,
    const float* __restrict__ fcb, const float* __restrict__ fc2w,
    const float* __restrict__ fc2b, const float* __restrict__ fc3w,
    const float* __restrict__ fc3b, float* __restrict__ outp){
  int row = blockIdx.x, c = threadIdx.x;
  __shared__ float t1[256];
  __shared__ float t3[256];
  __shared__ float t4[128];
  __shared__ float t5[64];
  __shared__ float rs[4];
  __shared__ float rq[4];
  int wv = c >> 6, ln = c & 63;
  float v = hid2[(size_t)row*256 + c];
  float s1 = wsum64(v), s2 = wsum64(v*v);
  if (ln == 0){ rs[wv]=s1; rq[wv]=s2; }
  __syncthreads();
  float mu = (rs[0]+rs[1]+rs[2]+rs[3])*(1.f/256.f);
  float msq = (rq[0]+rq[1]+rq[2]+rq[3])*(1.f/256.f);
  float var = msq - mu*mu;
  t1[c] = (v-mu)*rsqrtf(var + 1e-5f)*pg[c] + pb[c];
  __syncthreads();
  float a = 0.f;
  for (int k=0;k<256;k++) a += t1[k]*wo[(size_t)k*256 + c];
  float u1 = wsum64(a), u2 = wsum64(a*a);
  if (ln == 0){ rs[wv]=u1; rq[wv]=u2; }
  __syncthreads();
  mu = (rs[0]+rs[1]+rs[2]+rs[3])*(1.f/256.f);
  msq = (rq[0]+rq[1]+rq[2]+rq[3])*(1.f/256.f);
  var = msq - mu*mu;
  t3[c] = (a-mu)*rsqrtf(var + 1e-5f)*lg[c] + lb[c];
  __syncthreads();
  if (c < 128){
    float s = fcb[c];
    for (int k=0;k<256;k++) s += t3[k]*fcw[(size_t)k*128 + c];
    t4[c] = s;
  }
  __syncthreads();
  if (c < 64){
    float s = fc2b[c];
    for (int k=0;k<128;k++) s += t4[k]*fc2w[(size_t)k*64 + c];
    t5[c] = s;
  }
  __syncthreads();
  if (c < 64){
    float p = t5[c]*fc3w[c];
    p = wsum64(p);
    if (c == 0) outp[row] = p + fc3b[0];
  }
}

extern "C" void kernel_launch(void* const* d_in, const int* in_sizes, int n_in,
                              void* d_out, int out_size, void* d_ws, size_t ws_size,
                              hipStream_t stream){
  (void)in_sizes; (void)n_in; (void)out_size; (void)ws_size;
  const float* x       = (const float*)d_in[0];
  const float* s11_w   = (const float*)d_in[1];
  const float* s11_b   = (const float*)d_in[2];
  const float* bn11    = (const float*)d_in[3];
  const float* s12_w   = (const float*)d_in[4];
  const float* s12_b   = (const float*)d_in[5];
  const float* bn12    = (const float*)d_in[6];
  const float* s21_w   = (const float*)d_in[7];
  const float* s21_b   = (const float*)d_in[8];
  const float* bn21    = (const float*)d_in[9];
  const float* s22_w   = (const float*)d_in[10];
  const float* s22_b   = (const float*)d_in[11];
  const float* bn22    = (const float*)d_in[12];
  const float* s3_w    = (const float*)d_in[13];
  const float* s3_b    = (const float*)d_in[14];
  const float* bn3     = (const float*)d_in[15];
  const float* c1_w    = (const float*)d_in[16];
  const float* c1_b    = (const float*)d_in[17];
  const float* cb_w    = (const float*)d_in[18];
  const float* cb_b    = (const float*)d_in[19];
  const float* ln_g    = (const float*)d_in[20];
  const float* ln_b    = (const float*)d_in[21];
  const float* wq      = (const float*)d_in[22];
  const float* wk      = (const float*)d_in[23];
  const float* wv      = (const float*)d_in[24];
  const float* wo      = (const float*)d_in[25];
  const float* lr_w    = (const float*)d_in[26];
  const float* lr_b    = (const float*)d_in[27];
  const float* tib     = (const float*)d_in[28];
  const float* tlnw    = (const float*)d_in[29];
  const float* tlnb    = (const float*)d_in[30];
  const float* W1      = (const float*)d_in[31];
  const float* B1      = (const float*)d_in[32];
  const float* W2      = (const float*)d_in[33];
  const float* B2      = (const float*)d_in[34];
  const float* post_g  = (const float*)d_in[35];
  const float* post_b  = (const float*)d_in[36];
  const float* fc_w    = (const float*)d_in[37];
  const float* fc_b    = (const float*)d_in[38];
  const float* fc2_w   = (const float*)d_in[39];
  const float* fc2_b   = (const float*)d_in[40];
  const float* fc3_w   = (const float*)d_in[41];
  const float* fc3_b   = (const float*)d_in[42];

  float* ws = (float*)d_ws;
  float* xs   = ws;                       // 2359296
  float* xd   = ws + 2359296;             // 2359296
  float* p1   = ws + 4718592;             // 1179648 (pm)
  float* sig  = ws + 7077888;             // 32768
  float* buf0 = ws + 7110656;             // 131072
  float* buf1 = ws + 7241728;             // 131072
  float* accb = ws + 7372800;             // 131072
  float* xqb  = ws + 7634944;             // 131072
  float* xkb  = ws + 7766016;             // 131072
  float* xvb  = ws + 7897088;             // 131072
  float* eta  = ws + 8028160;             // 2048
  float* hid2 = ws + 8030208;             // 131072

  k_stem<<<3072, 192, 0, stream>>>(x, s11_w, s11_b, bn11, xs,
                                   s12_w, s12_b, bn12, xd);
  k_s2m<<<512, 576, 0, stream>>>(xs, xd, s21_w, s21_b, bn21,
                                 s22_w, s22_b, bn22, p1);
  k_s3<<<512, 256, 0, stream>>>(p1, s3_w, s3_b, bn3, sig);
  k_c1<<<512, 256, 0, stream>>>(sig, c1_w, c1_b, buf0);
  {
    float* cin = buf0; float* cout = buf1;
    for (int l=0; l<8; l++){
      int mode = (l == 1) ? 1 : ((l & 1) ? 2 : 0);
      k_conv1d<<<512, 256, 0, stream>>>(cin, cb_w + (size_t)l*196608,
                                        cb_b + l*256, cout, accb, mode);
      float* tmp = cin; cin = cout; cout = tmp;
    }
  }
  k_lnproj<<<512, 256, 0, stream>>>(accb, ln_g, ln_b, wq, wk, wv,
                                    lr_w, lr_b, xqb, xkb, xvb, eta);
  k_ttt<<<8, 512, 0, stream>>>(xqb, xkb, xvb, eta, tib, tlnw, tlnb,
                               W1, B1, W2, B2, hid2);
  k_head<<<512, 256, 0, stream>>>(hid2, post_g, post_b, wo, ln_g, ln_b,
                                  fc_w, fc_b, fc2_w, fc2_b, fc3_w, fc3_b,
                                  (float*)d_out);
}

// Round 15
// 1454.359 us; speedup vs baseline: 1.2130x; 1.0160x over previous
//
#include <hip/hip_runtime.h>
#include <hip/hip_bf16.h>
#include <math.h>

#define DEV __device__ __forceinline__

DEV float wsum64(float v){
  #pragma unroll
  for (int off = 32; off; off >>= 1) v += __shfl_xor(v, off, 64);
  return v;
}
DEV float geluf(float x){
  return 0.5f*x*(1.f + tanhf(0.7978845608028654f*(x + 0.044715f*x*x*x)));
}
DEV float gelu_bwdf(float x){
  float x2 = x*x;
  float t = tanhf(0.79788456f*x*(1.f + 0.044715f*x2));
  return 0.5f*x*((1.f - t*t)*(0.79788456f + 0.1070322243f*x2)) + 0.5f*(1.f + t);
}
DEV float sigmf(float x){ return 1.f/(1.f + expf(-x)); }

// ---------------------------------------------------------------------------
// Merged stem, per-channel staging (st = one channel: 37x108, 16KB ->
// 4 blocks/CU). Blocks [0,1536): s11; [1536,3072): s12 on frame diffs.
__global__ __launch_bounds__(192) void k_stem(const float* __restrict__ x,
    const float* __restrict__ w11, const float* __restrict__ b11,
    const float* __restrict__ bn11p, float* __restrict__ xs,
    const float* __restrict__ w12, const float* __restrict__ b12,
    const float* __restrict__ bn12p, float* __restrict__ xd){
  __shared__ float st[37*108];      // 3996 floats (one channel)
  __shared__ float wl[49*12*8];     // 4704 (s11 uses first 1176)
  int t = threadIdx.x;
  int pr = t / 24, pc = t - pr*24;
  float a00[8], a01[8], a10[8], a11[8];
  #pragma unroll
  for (int c=0;c<8;c++){ a00[c]=0.f; a01[c]=0.f; a10[c]=0.f; a11[c]=0.f; }
  if (blockIdx.x < 1536){
    // ---------------- s11 ----------------
    int bx = blockIdx.x;
    int bd = bx / 3, g = bx - bd*3;
    for (int e = t; e < 1176; e += 192){
      int tap = e / 24, r = e - tap*24, ci = r >> 3, c = r & 7;
      wl[e] = w11[(c*3 + ci)*49 + tap];
    }
    const float* xb = x + (size_t)bd*3*9216;
    for (int ci=0; ci<3; ci++){
      __syncthreads();
      for (int e = t; e < 37*102; e += 192){
        int ihl = e / 102, pi = e - ihl*102;
        int ih = ihl + 32*g - 3, iw = pi - 3;
        float v = 0.f;
        if (ih>=0 && ih<96 && iw>=0 && iw<96) v = xb[(size_t)ci*9216 + ih*96 + iw];
        st[ihl*108 + (pi&1)*54 + (pi>>1)] = v;
      }
      __syncthreads();
      for (int kh=0; kh<7; kh++){
        int rb0 = (4*pr + kh)*108 + 2*pc;
        int rb1 = rb0 + 216;
        float2 A0 = *(const float2*)&st[rb0];
        float2 A1 = *(const float2*)&st[rb0+2];
        float  A2 = st[rb0+4];
        float2 B0 = *(const float2*)&st[rb0+54];
        float2 B1 = *(const float2*)&st[rb0+56];
        float2 C0 = *(const float2*)&st[rb1];
        float2 C1 = *(const float2*)&st[rb1+2];
        float  C2 = st[rb1+4];
        float2 D0 = *(const float2*)&st[rb1+54];
        float2 D1 = *(const float2*)&st[rb1+56];
        float v00[7], v01[7], v10[7], v11[7];
        v00[0]=A0.x; v01[0]=A0.y; v10[0]=C0.x; v11[0]=C0.y;
        v00[1]=B0.x; v01[1]=B0.y; v10[1]=D0.x; v11[1]=D0.y;
        v00[2]=A0.y; v01[2]=A1.x; v10[2]=C0.y; v11[2]=C1.x;
        v00[3]=B0.y; v01[3]=B1.x; v10[3]=D0.y; v11[3]=D1.x;
        v00[4]=A1.x; v01[4]=A1.y; v10[4]=C1.x; v11[4]=C1.y;
        v00[5]=B1.x; v01[5]=B1.y; v10[5]=D1.x; v11[5]=D1.y;
        v00[6]=A1.y; v01[6]=A2;   v10[6]=C1.y; v11[6]=C2;
        #pragma unroll
        for (int kw=0; kw<7; kw++){
          const float4* wp = (const float4*)&wl[((kh*7+kw)*3 + ci)*8];
          float wv[8];
          *(float4*)&wv[0] = wp[0]; *(float4*)&wv[4] = wp[1];
          #pragma unroll
          for (int c=0;c<8;c++){
            a00[c] += v00[kw]*wv[c]; a01[c] += v01[kw]*wv[c];
            a10[c] += v10[kw]*wv[c]; a11[c] += v11[kw]*wv[c];
          }
        }
      }
    }
    int pos = (g*8 + pr)*24 + pc;
    #pragma unroll
    for (int c=0;c<8;c++){
      float gg=bn11p[c], be=bn11p[8+c], m=bn11p[16+c], vv=bn11p[24+c];
      float s = gg*rsqrtf(vv + 1e-5f);
      float bi = b11[c];
      float mx = 0.f;
      mx = fmaxf(mx, (a00[c]+bi-m)*s+be);
      mx = fmaxf(mx, (a01[c]+bi-m)*s+be);
      mx = fmaxf(mx, (a10[c]+bi-m)*s+be);
      mx = fmaxf(mx, (a11[c]+bi-m)*s+be);
      xs[((size_t)bd*8 + c)*576 + pos] = mx;
    }
  } else {
    // ---------------- s12 ----------------
    int bx = blockIdx.x - 1536;
    int bd = bx / 3, g = bx - bd*3;
    int b = bd >> 8, dd = bd & 255;
    for (int e = t; e < 4704; e += 192){
      int tap = e / 96, r = e - tap*96, ci = r >> 3, c = r & 7;
      wl[e] = w12[(c*12 + ci)*49 + tap];
    }
    int fa[4], fb[4];
    fa[0] = dd>=2 ? dd-1 : 0;     fb[0] = dd>=2 ? dd-2 : 0;
    fa[1] = dd;                   fb[1] = dd>=1 ? dd-1 : 0;
    fa[2] = dd<=254 ? dd+1 : 255; fb[2] = dd;
    fa[3] = dd<=253 ? dd+2 : 255; fb[3] = dd<=254 ? dd+1 : 255;
    for (int g4=0; g4<4; g4++){
      if (fa[g4] == fb[g4]) continue;   // zero diff, uniform per block
      const float* xa = x + ((size_t)(b*256 + fa[g4]))*3*9216;
      const float* xbp= x + ((size_t)(b*256 + fb[g4]))*3*9216;
      for (int rgb=0; rgb<3; rgb++){
        int gch = g4*3 + rgb;
        __syncthreads();
        for (int e = t; e < 37*102; e += 192){
          int ihl = e / 102, pi = e - ihl*102;
          int ih = ihl + 32*g - 3, iw = pi - 3;
          float v = 0.f;
          if (ih>=0 && ih<96 && iw>=0 && iw<96){
            size_t off = (size_t)rgb*9216 + ih*96 + iw;
            v = xa[off] - xbp[off];
          }
          st[ihl*108 + (pi&1)*54 + (pi>>1)] = v;
        }
        __syncthreads();
        for (int kh=0; kh<7; kh++){
          int rb0 = (4*pr + kh)*108 + 2*pc;
          int rb1 = rb0 + 216;
          float2 A0 = *(const float2*)&st[rb0];
          float2 A1 = *(const float2*)&st[rb0+2];
          float  A2 = st[rb0+4];
          float2 B0 = *(const float2*)&st[rb0+54];
          float2 B1 = *(const float2*)&st[rb0+56];
          float2 C0 = *(const float2*)&st[rb1];
          float2 C1 = *(const float2*)&st[rb1+2];
          float  C2 = st[rb1+4];
          float2 D0 = *(const float2*)&st[rb1+54];
          float2 D1 = *(const float2*)&st[rb1+56];
          float v00[7], v01[7], v10[7], v11[7];
          v00[0]=A0.x; v01[0]=A0.y; v10[0]=C0.x; v11[0]=C0.y;
          v00[1]=B0.x; v01[1]=B0.y; v10[1]=D0.x; v11[1]=D0.y;
          v00[2]=A0.y; v01[2]=A1.x; v10[2]=C0.y; v11[2]=C1.x;
          v00[3]=B0.y; v01[3]=B1.x; v10[3]=D0.y; v11[3]=D1.x;
          v00[4]=A1.x; v01[4]=A1.y; v10[4]=C1.x; v11[4]=C1.y;
          v00[5]=B1.x; v01[5]=B1.y; v10[5]=D1.x; v11[5]=D1.y;
          v00[6]=A1.y; v01[6]=A2;   v10[6]=C1.y; v11[6]=C2;
          #pragma unroll
          for (int kw=0; kw<7; kw++){
            const float4* wp = (const float4*)&wl[((kh*7+kw)*12 + gch)*8];
            float wv[8];
            *(float4*)&wv[0] = wp[0]; *(float4*)&wv[4] = wp[1];
            #pragma unroll
            for (int c=0;c<8;c++){
              a00[c] += v00[kw]*wv[c]; a01[c] += v01[kw]*wv[c];
              a10[c] += v10[kw]*wv[c]; a11[c] += v11[kw]*wv[c];
            }
          }
        }
      }
    }
    int pos = (g*8 + pr)*24 + pc;
    #pragma unroll
    for (int c=0;c<8;c++){
      float gg=bn12p[c], be=bn12p[8+c], m=bn12p[16+c], vv=bn12p[24+c];
      float s = gg*rsqrtf(vv + 1e-5f);
      float bi = b12[c];
      float mx = 0.f;
      mx = fmaxf(mx, (a00[c]+bi-m)*s+be);
      mx = fmaxf(mx, (a01[c]+bi-m)*s+be);
      mx = fmaxf(mx, (a10[c]+bi-m)*s+be);
      mx = fmaxf(mx, (a11[c]+bi-m)*s+be);
      xd[((size_t)bd*8 + c)*576 + pos] = mx;
    }
  }
}

// Merged s21+s22, 576 threads = 144 pos x 4 channel-quads. Tile stride 34.
__global__ __launch_bounds__(576) void k_s2m(const float* __restrict__ xs,
    const float* __restrict__ xd,
    const float* __restrict__ w1, const float* __restrict__ b1,
    const float* __restrict__ bn1,
    const float* __restrict__ w2, const float* __restrict__ b2,
    const float* __restrict__ bn2, float* __restrict__ pm){
  __shared__ float st[8*30*34];     // 8160
  __shared__ float wl[49*8*16];     // 6272
  int bd = blockIdx.x;
  int t = threadIdx.x;
  int quad = t / 144;
  int pos = t - quad*144;
  int pr = pos / 12, pc = pos - pr*12;
  const float* pa = xs + (size_t)bd*8*576;
  const float* pb = xd + (size_t)bd*8*576;
  float r1[4];
  for (int e = t; e < 6272; e += 576){
    int tap = e >> 7, r = e & 127, ci = r >> 4, c = r & 15;
    wl[e] = w1[(c*8 + ci)*49 + tap];
  }
  for (int e = t; e < 8160; e += 576){
    int ci = e / 1020, r2 = e - ci*1020;
    int r = r2 / 34, cc = r2 - r*34;
    int ih = r - 3, iw = cc - 3;
    float v = 0.f;
    if (ih>=0 && ih<24 && iw>=0 && iw<24){
      int off = ci*576 + ih*24 + iw;
      v = 0.5f*(pa[off] + pb[off]);
    }
    st[(ci*30 + r)*34 + cc] = v;
  }
  __syncthreads();
  {
    float a00[4], a01[4], a10[4], a11[4];
    #pragma unroll
    for (int c=0;c<4;c++){ a00[c]=0.f; a01[c]=0.f; a10[c]=0.f; a11[c]=0.f; }
    for (int ci=0; ci<8; ci++){
      for (int kh=0; kh<7; kh++){
        int rb = (ci*30 + 2*pr + kh)*34 + 2*pc;
        float2 E0 = *(const float2*)&st[rb];
        float2 E1 = *(const float2*)&st[rb+2];
        float2 E2 = *(const float2*)&st[rb+4];
        float2 E3 = *(const float2*)&st[rb+6];
        float2 F0 = *(const float2*)&st[rb+34];
        float2 F1 = *(const float2*)&st[rb+36];
        float2 F2 = *(const float2*)&st[rb+38];
        float2 F3 = *(const float2*)&st[rb+40];
        float v00[7], v01[7], v10[7], v11[7];
        v00[0]=E0.x; v01[0]=E0.y; v10[0]=F0.x; v11[0]=F0.y;
        v00[1]=E0.y; v01[1]=E1.x; v10[1]=F0.y; v11[1]=F1.x;
        v00[2]=E1.x; v01[2]=E1.y; v10[2]=F1.x; v11[2]=F1.y;
        v00[3]=E1.y; v01[3]=E2.x; v10[3]=F1.y; v11[3]=F2.x;
        v00[4]=E2.x; v01[4]=E2.y; v10[4]=F2.x; v11[4]=F2.y;
        v00[5]=E2.y; v01[5]=E3.x; v10[5]=F2.y; v11[5]=F3.x;
        v00[6]=E3.x; v01[6]=E3.y; v10[6]=F3.x; v11[6]=F3.y;
        #pragma unroll
        for (int kw=0; kw<7; kw++){
          float4 w4 = *(const float4*)&wl[((kh*7+kw)*8 + ci)*16 + quad*4];
          float wv[4];
          *(float4*)&wv[0] = w4;
          #pragma unroll
          for (int c=0;c<4;c++){
            a00[c] += v00[kw]*wv[c]; a01[c] += v01[kw]*wv[c];
            a10[c] += v10[kw]*wv[c]; a11[c] += v11[kw]*wv[c];
          }
        }
      }
    }
    #pragma unroll
    for (int c=0;c<4;c++){
      int c2 = quad*4 + c;
      float gg=bn1[c2], be=bn1[16+c2], m=bn1[32+c2], vv=bn1[48+c2];
      float s = gg*rsqrtf(vv + 1e-5f);
      float bi = b1[c2];
      float mx = 0.f;
      mx = fmaxf(mx, (a00[c]+bi-m)*s+be);
      mx = fmaxf(mx, (a01[c]+bi-m)*s+be);
      mx = fmaxf(mx, (a10[c]+bi-m)*s+be);
      mx = fmaxf(mx, (a11[c]+bi-m)*s+be);
      r1[c] = mx;
    }
  }
  __syncthreads();
  for (int e = t; e < 6272; e += 576){
    int tap = e >> 7, r = e & 127, ci = r >> 4, c = r & 15;
    wl[e] = w2[(c*8 + ci)*49 + tap];
  }
  for (int e = t; e < 8160; e += 576){
    int ci = e / 1020, r2 = e - ci*1020;
    int r = r2 / 34, cc = r2 - r*34;
    int ih = r - 3, iw = cc - 3;
    float v = 0.f;
    if (ih>=0 && ih<24 && iw>=0 && iw<24)
      v = pb[ci*576 + ih*24 + iw];
    st[(ci*30 + r)*34 + cc] = v;
  }
  __syncthreads();
  {
    float a00[4], a01[4], a10[4], a11[4];
    #pragma unroll
    for (int c=0;c<4;c++){ a00[c]=0.f; a01[c]=0.f; a10[c]=0.f; a11[c]=0.f; }
    for (int ci=0; ci<8; ci++){
      for (int kh=0; kh<7; kh++){
        int rb = (ci*30 + 2*pr + kh)*34 + 2*pc;
        float2 E0 = *(const float2*)&st[rb];
        float2 E1 = *(const float2*)&st[rb+2];
        float2 E2 = *(const float2*)&st[rb+4];
        float2 E3 = *(const float2*)&st[rb+6];
        float2 F0 = *(const float2*)&st[rb+34];
        float2 F1 = *(const float2*)&st[rb+36];
        float2 F2 = *(const float2*)&st[rb+38];
        float2 F3 = *(const float2*)&st[rb+40];
        float v00[7], v01[7], v10[7], v11[7];
        v00[0]=E0.x; v01[0]=E0.y; v10[0]=F0.x; v11[0]=F0.y;
        v00[1]=E0.y; v01[1]=E1.x; v10[1]=F0.y; v11[1]=F1.x;
        v00[2]=E1.x; v01[2]=E1.y; v10[2]=F1.x; v11[2]=F1.y;
        v00[3]=E1.y; v01[3]=E2.x; v10[3]=F1.y; v11[3]=F2.x;
        v00[4]=E2.x; v01[4]=E2.y; v10[4]=F2.x; v11[4]=F2.y;
        v00[5]=E2.y; v01[5]=E3.x; v10[5]=F2.y; v11[5]=F3.x;
        v00[6]=E3.x; v01[6]=E3.y; v10[6]=F3.x; v11[6]=F3.y;
        #pragma unroll
        for (int kw=0; kw<7; kw++){
          float4 w4 = *(const float4*)&wl[((kh*7+kw)*8 + ci)*16 + quad*4];
          float wv[4];
          *(float4*)&wv[0] = w4;
          #pragma unroll
          for (int c=0;c<4;c++){
            a00[c] += v00[kw]*wv[c]; a01[c] += v01[kw]*wv[c];
            a10[c] += v10[kw]*wv[c]; a11[c] += v11[kw]*wv[c];
          }
        }
      }
    }
    #pragma unroll
    for (int c=0;c<4;c++){
      int c2 = quad*4 + c;
      float gg=bn2[c2], be=bn2[16+c2], m=bn2[32+c2], vv=bn2[48+c2];
      float s = gg*rsqrtf(vv + 1e-5f);
      float bi = b2[c2];
      float mx = 0.f;
      mx = fmaxf(mx, (a00[c]+bi-m)*s+be);
      mx = fmaxf(mx, (a01[c]+bi-m)*s+be);
      mx = fmaxf(mx, (a10[c]+bi-m)*s+be);
      mx = fmaxf(mx, (a11[c]+bi-m)*s+be);
      pm[((size_t)bd*16 + c2)*144 + pr*12 + pc] = 0.5f*(r1[c] + mx);
    }
  }
}

// s3 conv3x3 p1 + BN + attention-mask pooled signal. Register-row inner loop:
// per ci, load this thread's 5 rows (5x14, float2-aligned) into registers,
// then 3x3x36 FMA from registers. 704 LDS reads/thread vs 5328 before.
__global__ __launch_bounds__(256) void k_s3(const float* __restrict__ pm,
    const float* __restrict__ w,
    const float* __restrict__ bias, const float* __restrict__ bn,
    float* __restrict__ sig){
  __shared__ float ins[16*14*14];
  __shared__ float wT[144*64];
  __shared__ float redS[64*4];
  __shared__ float redF[64*4];
  int bd = blockIdx.x;
  int t = threadIdx.x;
  for (int i = t; i < 16*196; i += 256){
    int ci = i/196, r = i - ci*196, y = r/14, xx = r - y*14;
    float v = 0.f;
    if (y>=1 && y<=12 && xx>=1 && xx<=12){
      size_t idx = ((size_t)bd*16 + ci)*144 + (y-1)*12 + (xx-1);
      v = pm[idx];
    }
    ins[i] = v;
  }
  for (int i = t; i < 9216; i += 256){
    int c = i & 63, k = i >> 6;
    wT[i] = w[c*144 + k];
  }
  __syncthreads();
  int c = t & 63, pg = t >> 6;
  float acc[36];
  #pragma unroll
  for (int pp=0;pp<36;pp++) acc[pp]=0.f;
  for (int ci=0; ci<16; ci++){
    float rw[5][14];
    int rbase = ci*196 + pg*3*14;
    #pragma unroll
    for (int rr=0; rr<5; rr++){
      #pragma unroll
      for (int q=0; q<7; q++){
        float2 v2 = *(const float2*)&ins[rbase + rr*14 + q*2];
        rw[rr][q*2] = v2.x; rw[rr][q*2+1] = v2.y;
      }
    }
    #pragma unroll
    for (int kh=0; kh<3; kh++){
      #pragma unroll
      for (int kw=0; kw<3; kw++){
        float wv = wT[(ci*9 + kh*3 + kw)*64 + c];
        #pragma unroll
        for (int pp=0; pp<36; pp++){
          int y = pp/12, xx = pp - (pp/12)*12;
          acc[pp] += rw[y+kh][xx+kw]*wv;
        }
      }
    }
  }
  float g=bn[c], be=bn[64+c], m=bn[128+c], vv=bn[192+c];
  float s = g*rsqrtf(vv + 1e-5f);
  float bi = bias[c];
  float sS = 0.f, sF = 0.f;
  #pragma unroll
  for (int pp=0;pp<36;pp++){
    float f = (acc[pp] + bi - m)*s + be;
    float sg = sigmf(f);
    sS += sg; sF += f*sg;
  }
  redS[c*4+pg] = sS; redF[c*4+pg] = sF;
  __syncthreads();
  if (t < 64){
    float S = redS[t*4]+redS[t*4+1]+redS[t*4+2]+redS[t*4+3];
    float F = redF[t*4]+redF[t*4+1]+redF[t*4+2]+redF[t*4+3];
    sig[(size_t)bd*64 + t] = 0.5f*F/S;
  }
}

// c1 1x1 conv: sig[b,t,64] -> h[b,256,256] (channel-major). block=(b,o). grid 512.
__global__ __launch_bounds__(256) void k_c1(const float* __restrict__ sig,
    const float* __restrict__ w, const float* __restrict__ bias,
    float* __restrict__ h){
  int b = blockIdx.x >> 8, o = blockIdx.x & 255, tt = threadIdx.x;
  __shared__ float wl[64];
  if (tt < 64) wl[tt] = w[o*64 + tt];
  __syncthreads();
  const float4* sp = (const float4*)(sig + ((size_t)(b*256 + tt))*64);
  const float4* wp = (const float4*)wl;
  float a = bias[o];
  #pragma unroll
  for (int i=0;i<16;i++){
    float4 s4 = sp[i]; float4 w4 = wp[i];
    a += s4.x*w4.x + s4.y*w4.y + s4.z*w4.z + s4.w*w4.w;
  }
  h[((size_t)b*256 + o)*256 + tt] = fmaxf(a, 0.f);
}

// conv1d 256->256 k3 p1 + relu. 512 blocks (8 outch each) for 2 blocks/CU.
// mode: 0=none 1=acc:=out 2=acc+=out.
__global__ __launch_bounds__(256) void k_conv1d(const float* __restrict__ hin,
    const float* __restrict__ w, const float* __restrict__ bias,
    float* __restrict__ hout, float* __restrict__ accb, int mode){
  __shared__ float ins[256*34];
  __shared__ float ws[8*256*4];    // 8 outch, padded stride-4 taps (32KB)
  int bx = blockIdx.x;
  int b = bx >> 8;
  int rem = bx & 255;
  int og = rem >> 3;               // 32 groups of 8 outch
  int tg = rem & 7;
  int tid = threadIdx.x;
  int t0 = tg*32;
  for (int idx = tid; idx < 256*34; idx += 256){
    int ii = idx/34, jj = idx - ii*34;
    int tglob = t0 - 1 + jj;
    float v = 0.f;
    if (tglob >= 0 && tglob < 256) v = hin[((size_t)b*256 + ii)*256 + tglob];
    ins[idx] = v;
  }
  for (int idx = tid; idx < 6144; idx += 256){
    int q = idx/3;
    ws[q*4 + (idx - q*3)] = w[(size_t)og*6144 + idx];
  }
  __syncthreads();
  int ol = tid >> 5, tl = tid & 31;
  int o = og*8 + ol;
  float a1 = bias[o];
  const float4* w1q = (const float4*)(ws + (size_t)ol*1024);
  for (int i=0;i<256;i++){
    float v0 = ins[i*34 + tl];
    float v1 = ins[i*34 + tl + 1];
    float v2 = ins[i*34 + tl + 2];
    float4 wa = w1q[i];
    a1 += wa.x*v0 + wa.y*v1 + wa.z*v2;
  }
  a1 = fmaxf(a1, 0.f);
  size_t i1 = ((size_t)b*256 + o)*256 + t0 + tl;
  hout[i1] = a1;
  if (mode == 1) accb[i1] = a1;
  else if (mode == 2) accb[i1] += a1;
}

// Fused LN + projections + eta. One block per (b,t) row. grid 512.
__global__ __launch_bounds__(256) void k_lnproj(const float* __restrict__ acc,
    const float* __restrict__ g, const float* __restrict__ be,
    const float* __restrict__ wqp, const float* __restrict__ wkp,
    const float* __restrict__ wvp, const float* __restrict__ lrw,
    const float* __restrict__ lrb, float* __restrict__ xq,
    float* __restrict__ xk, float* __restrict__ xv,
    float* __restrict__ etalr){
  int b = blockIdx.x >> 8, tt = blockIdx.x & 255, c = threadIdx.x;
  __shared__ float hrow[256];
  __shared__ float rs[4];
  __shared__ float rq[4];
  __shared__ float epb[4][4];   // [wave][head]
  int wv_ = c >> 6, ln = c & 63;
  float v = acc[((size_t)b*256 + c)*256 + tt];
  float s1 = wsum64(v), s2 = wsum64(v*v);
  if (ln == 0){ rs[wv_]=s1; rq[wv_]=s2; }
  __syncthreads();
  float mu = (rs[0]+rs[1]+rs[2]+rs[3])*(1.f/256.f);
  float msq = (rq[0]+rq[1]+rq[2]+rq[3])*(1.f/256.f);
  float var = msq - mu*mu;
  float hv = (v-mu)*rsqrtf(var + 1e-5f)*g[c] + be[c];
  hrow[c] = hv;
  __syncthreads();
  {
    float p0 = hv*lrw[c];
    float p1 = hv*lrw[256 + c];
    float p2 = hv*lrw[512 + c];
    float p3 = hv*lrw[768 + c];
    p0 = wsum64(p0); p1 = wsum64(p1); p2 = wsum64(p2); p3 = wsum64(p3);
    if (ln == 0){ epb[wv_][0]=p0; epb[wv_][1]=p1; epb[wv_][2]=p2; epb[wv_][3]=p3; }
  }
  float aq = 0.f, ak = 0.f, av = 0.f;
  for (int k=0;k<256;k++){
    float hk = hrow[k];
    aq += hk*wqp[(size_t)k*256 + c];
    ak += hk*wkp[(size_t)k*256 + c];
    av += hk*wvp[(size_t)k*256 + c];
  }
  size_t row = (size_t)blockIdx.x;
  xq[row*256 + c] = aq;
  xk[row*256 + c] = ak;
  xv[row*256 + c] = av;
  __syncthreads();
  if (c < 4){
    float a = lrb[c] + epb[0][c] + epb[1][c] + epb[2][c] + epb[3][c];
    etalr[((size_t)(b*4 + c))*256 + tt] = 0.1f*sigmf(a)*(1.f/64.f);
  }
}

// TTT-MLP scan, 512 threads. Role/K-split (R11 structure, unchanged).
__global__ __launch_bounds__(512) void k_ttt(
    const float* __restrict__ xq, const float* __restrict__ xk,
    const float* __restrict__ xv, const float* __restrict__ etalr,
    const float* __restrict__ tib, const float* __restrict__ lnw,
    const float* __restrict__ lnb, const float* __restrict__ W1g,
    const float* __restrict__ B1g, const float* __restrict__ W2g,
    const float* __restrict__ B2g, float* __restrict__ out){
  __shared__ float W1s[64*256];                 // [d][j]
  __shared__ float W2L[256*65];                 // [r][c] pitch 65
  __shared__ __align__(16) float k_pk[256];     // [d=64][slot4]
  __shared__ __align__(16) float q_pk[256];
  __shared__ __align__(16) float v_pk[256];
  __shared__ __align__(16) float x2_pk[1024];   // [j=256][slot4]
  __shared__ __align__(16) float x2b_pk[1024];
  __shared__ __align__(16) float gb_pk[1024];   // gelu_bwd(Z1) factors
  __shared__ __align__(16) float gz2_pk[256];   // [cl=64][slot4]
  __shared__ __align__(16) float pzs[4*576];    // partials; aliased as gzx
  __shared__ float qwx[512];                    // qw slots 0,1 exchange
  __shared__ float a2w[64];
  __shared__ float coefs[16];                   // row-indexed [i*4+r]
  __shared__ float coef2s[16];
  __shared__ float els[4];
  __shared__ float toks_s[4];

  int b = blockIdx.x >> 2, h = blockIdx.x & 3;
  int tid = threadIdx.x;
  int j = tid & 255;
  int i2 = tid >> 8;
  int iw = j >> 6, cl = j & 63;
  int ps_iw = ((iw & 1) << 1) | (iw >> 1);      // pslot(iw)

  const float* W1b = W1g + (size_t)h*16384;
  const float* W2b = W2g + (size_t)h*16384;
  for (int i = tid; i < 16384; i += 512) W1s[i] = W1b[i];
  for (int i = tid; i < 16384; i += 512){
    int r = i >> 6, c = i & 63;
    W2L[r*65 + c] = W2b[i];
  }
  float b1r = B1g[h*256 + j];
  float b2r = B2g[h*64 + cl];
  float gr = lnw[h*64 + cl], br = lnb[h*64 + cl];
  if (tid < 4) toks_s[tid] = fmaxf(1.f/(float)(tid+1) + tib[tid], 0.f);
  __syncthreads();
  float tok3 = toks_s[3];
  float tik = toks_s[iw];

  const float* xqp = xq + (size_t)b*65536 + h*64;
  const float* xkp = xk + (size_t)b*65536 + h*64;
  const float* xvp = xv + (size_t)b*65536 + h*64;
  const float* ep  = etalr + (size_t)(b*4 + h)*256;

  float qv=0.f, kv=0.f, vv=0.f, elv=0.f;
  if (i2 == 0){ qv = xqp[(size_t)iw*256 + cl]; kv = xkp[(size_t)iw*256 + cl]; }
  else        { vv = xvp[(size_t)iw*256 + cl]; }
  if (tid < 4) elv = ep[tid];

  for (int n=0; n<64; n++){
    // --- phase 0: stage ---
    if (i2 == 0){ k_pk[cl*4 + ps_iw] = kv; q_pk[cl*4 + ps_iw] = qv; }
    else        { v_pk[cl*4 + ps_iw] = vv; }
    if (tid < 4) els[tid] = elv;
    __syncthreads();                              // A
    // --- A1 (half0 waves; wave iw = row iw) ---
    if (i2 == 0){
      float4 k4a = *(const float4*)&k_pk[cl*4];   // slots = rows 0,2,1,3
      float a0 = wsum64(qv*k4a.x);
      float a1 = wsum64(qv*k4a.y);
      float a2 = wsum64(qv*k4a.z);
      float a3 = wsum64(qv*k4a.w);
      if (cl == 0){
        coefs[iw*4+0] = tik*els[0]*(a0+1.f);
        coefs[iw*4+2] = (iw>=2) ? tik*els[2]*(a1+1.f) : 0.f;
        coefs[iw*4+1] = (iw>=1) ? tik*els[1]*(a2+1.f) : 0.f;
        coefs[iw*4+3] = (iw>=3) ? tik*els[3]*(a3+1.f) : 0.f;
      }
    }
    // --- Z1 producer split: h0 -> z1 (4 slots), h1 -> qw (4 slots) ---
    float acc0=b1r, acc1=b1r, acc2=b1r, acc3=b1r;
    {
      const float* src = (i2 == 0) ? k_pk : q_pk;
      #pragma unroll 8
      for (int d=0; d<64; d++){
        float4 s4 = *(const float4*)&src[d*4];
        float w = W1s[d*256 + j];
        acc0 += s4.x*w; acc1 += s4.y*w; acc2 += s4.z*w; acc3 += s4.w*w;
      }
    }
    float x2o0=0.f, x2o1=0.f, qw0r=0.f, qw1r=0.f;
    if (i2 == 0){
      float g0 = geluf(acc0), g1 = geluf(acc1), g2 = geluf(acc2), g3 = geluf(acc3);
      { float4 t4; t4.x=g0; t4.y=g1; t4.z=g2; t4.w=g3;
        *(float4*)&x2_pk[j*4] = t4; }
      { float4 t4; t4.x=gelu_bwdf(acc0); t4.y=gelu_bwdf(acc1);
        t4.z=gelu_bwdf(acc2); t4.w=gelu_bwdf(acc3);
        *(float4*)&gb_pk[j*4] = t4; }
      x2o0 = g0; x2o1 = g1;                       // own rows 0,2 (slots 0,1)
    } else {
      qwx[j*2]   = acc0;                          // qw slot0 (row0) for h0
      qwx[j*2+1] = acc1;                          // qw slot1 (row2) for h0
      qw0r = acc2; qw1r = acc3;                   // own rows 1,3 (slots 2,3)
    }
    __syncthreads();                              // B
    if (i2 == 0){ qw0r = qwx[j*2]; qw1r = qwx[j*2+1]; }
    else { float2 xo = *(const float2*)&x2_pk[j*4+2]; x2o0 = xo.x; x2o1 = xo.y; }
    // --- prefetch next step ---
    float qn=0.f, kn=0.f, vn=0.f, eln=0.f;
    if (n < 63){
      int l2 = (n+1)*4 + iw;
      if (i2 == 0){ qn = xqp[(size_t)l2*256 + cl]; kn = xkp[(size_t)l2*256 + cl]; }
      else        { vn = xvp[(size_t)l2*256 + cl]; }
      if (tid < 4) eln = ep[(n+1)*4 + tid];
    }
    // --- Z2 split-K: seg = iw*2+i2, 32 d's, all 4 rows via slots ---
    {
      int d0 = (iw*2 + i2)*32;
      int seg = iw*2 + i2;
      float p0=0.f,p1=0.f,p2=0.f,p3=0.f;
      #pragma unroll 8
      for (int dd=0; dd<32; dd++){
        float4 x4 = *(const float4*)&x2_pk[(d0+dd)*4];
        float w = W2L[(d0+dd)*65 + cl];
        p0 += x4.x*w; p1 += x4.y*w; p2 += x4.z*w; p3 += x4.w*w;
      }
      pzs[0*576 + cl*9 + seg] = p0;   // slot0 = row0
      pzs[2*576 + cl*9 + seg] = p1;   // slot1 = row2
      pzs[1*576 + cl*9 + seg] = p2;   // slot2 = row1
      pzs[3*576 + cl*9 + seg] = p3;   // slot3 = row3
    }
    __syncthreads();                              // C
    // --- fused LN-L2 backward (half0 wave iw = row iw) ---
    if (i2 == 0){
      float z2 = b2r;
      #pragma unroll
      for (int sg=0; sg<8; sg++) z2 += pzs[iw*576 + cl*9 + sg];
      float mu = wsum64(z2)*(1.f/64.f);
      float df = z2 - mu;
      float var = wsum64(df*df)*(1.f/64.f);
      float stdv = sqrtf(var + 1e-6f);
      float xhat = df/stdv;
      float tgt = v_pk[cl*4 + ps_iw] - kv;
      float gxh = (gr*xhat + br - tgt)*gr;
      float sg1 = wsum64(gxh);
      float sg2 = wsum64(gxh*xhat);
      float gz2 = (64.f*gxh - sg1 - xhat*sg2)*(1.f/(64.f*stdv));
      gz2_pk[cl*4 + ps_iw] = gz2;
    }
    __syncthreads();                              // D0
    // --- gZ1 split-K: half i2 covers c in [i2*32, i2*32+32) ---
    float gd0=0.f, gd1=0.f, gd2=0.f, gd3=0.f;
    {
      int cb = i2*32;
      #pragma unroll 8
      for (int cc=0; cc<32; cc++){
        float4 g4 = *(const float4*)&gz2_pk[(cb+cc)*4];
        float w = W2L[j*65 + cb + cc];
        gd0 += g4.x*w; gd1 += g4.y*w; gd2 += g4.z*w; gd3 += g4.w*w;
      }
      float4 t4; t4.x=gd0; t4.y=gd1; t4.z=gd2; t4.w=gd3;
      *(float4*)&pzs[i2*1024 + j*4] = t4;         // gzx alias on pzs
    }
    __syncthreads();                              // D1
    {
      float4 po = *(const float4*)&pzs[(1-i2)*1024 + j*4];
      gd0 += po.x; gd1 += po.y; gd2 += po.z; gd3 += po.w;
    }
    float4 gb4 = *(const float4*)&gb_pk[j*4];
    float4 gz14;
    gz14.x = gd0*gb4.x; gz14.y = gd1*gb4.y;
    gz14.z = gd2*gb4.z; gz14.w = gd3*gb4.w;       // slots 0,2,1,3
    // --- Z1b/X2b rows (i2, i2+2) ---
    int R0 = i2, R1 = i2 + 2;
    float zb0 = qw0r - (coefs[R0*4+0]*gz14.x + coefs[R0*4+2]*gz14.y
                      + coefs[R0*4+1]*gz14.z + coefs[R0*4+3]*gz14.w);
    float zb1 = qw1r - (coefs[R1*4+0]*gz14.x + coefs[R1*4+2]*gz14.y
                      + coefs[R1*4+1]*gz14.z + coefs[R1*4+3]*gz14.w);
    float xb0 = geluf(zb0), xb1 = geluf(zb1);
    { float2 t; t.x=xb0; t.y=xb1; *(float2*)&x2b_pk[j*4 + i2*2] = t; }
    // --- W1 + b1 update ---
    float le_s0 = tok3*els[0], le_s1 = tok3*els[2], le_s2 = tok3*els[1], le_s3 = tok3*els[3];
    {
      float lg0 = le_s0*gz14.x, lg1v = le_s1*gz14.y, lg2 = le_s2*gz14.z, lg3 = le_s3*gz14.w;
      int d0 = i2*32;
      #pragma unroll 8
      for (int dd=0; dd<32; dd++){
        float4 k4 = *(const float4*)&k_pk[(d0+dd)*4];
        W1s[(d0+dd)*256 + j] -= lg0*k4.x + lg1v*k4.y + lg2*k4.z + lg3*k4.w;
      }
      b1r -= lg0 + lg1v + lg2 + lg3;
    }
    // --- A2 masked products, split 4/6 across halves ---
    if (i2 == 0){
      float xo1 = x2_pk[j*4 + 2];                 // row1
      float s00 = wsum64(xb0*x2o0);               // (0,0)
      float s20 = wsum64(xb1*x2o0);               // (2,0)
      float s22 = wsum64(xb1*x2o1);               // (2,2)
      float s21 = wsum64(xb1*xo1);                // (2,1)
      if (cl == 0){
        a2w[iw*16+0]  = s00;
        a2w[iw*16+8]  = s20;
        a2w[iw*16+10] = s22;
        a2w[iw*16+9]  = s21;
      }
    } else {
      float2 xo02 = *(const float2*)&x2_pk[j*4];  // rows 0,2
      float s11 = wsum64(xb0*x2o0);               // (1,1)
      float s10 = wsum64(xb0*xo02.x);             // (1,0)
      float s31 = wsum64(xb1*x2o0);               // (3,1)
      float s33 = wsum64(xb1*x2o1);               // (3,3)
      float s30 = wsum64(xb1*xo02.x);             // (3,0)
      float s32 = wsum64(xb1*xo02.y);             // (3,2)
      if (cl == 0){
        a2w[iw*16+5]  = s11;
        a2w[iw*16+4]  = s10;
        a2w[iw*16+13] = s31;
        a2w[iw*16+15] = s33;
        a2w[iw*16+12] = s30;
        a2w[iw*16+14] = s32;
      }
    }
    __syncthreads();                              // E
    if (tid < 16){
      int ii = tid >> 2, rr = tid & 3;
      float s = a2w[tid] + a2w[16+tid] + a2w[32+tid] + a2w[48+tid];
      coef2s[tid] = (rr <= ii) ? toks_s[ii]*els[rr]*(s + 1.f) : 0.f;
    }
    // --- Z2b split-K ---
    {
      int d0 = (iw*2 + i2)*32;
      int seg = iw*2 + i2;
      float p0=0.f,p1=0.f,p2=0.f,p3=0.f;
      #pragma unroll 8
      for (int dd=0; dd<32; dd++){
        float4 x4 = *(const float4*)&x2b_pk[(d0+dd)*4];
        float w = W2L[(d0+dd)*65 + cl];
        p0 += x4.x*w; p1 += x4.y*w; p2 += x4.z*w; p3 += x4.w*w;
      }
      pzs[0*576 + cl*9 + seg] = p0;
      pzs[2*576 + cl*9 + seg] = p1;
      pzs[1*576 + cl*9 + seg] = p2;
      pzs[3*576 + cl*9 + seg] = p3;
    }
    __syncthreads();                              // F
    // --- ln_fwd + output (half0) ---
    if (i2 == 0){
      float z2b = b2r;
      #pragma unroll
      for (int sg=0; sg<8; sg++) z2b += pzs[iw*576 + cl*9 + sg];
      float4 g4r = *(const float4*)&gz2_pk[cl*4];
      z2b -= coef2s[iw*4+0]*g4r.x + coef2s[iw*4+2]*g4r.y
           + coef2s[iw*4+1]*g4r.z + coef2s[iw*4+3]*g4r.w;
      float mu2 = wsum64(z2b)*(1.f/64.f);
      float df2 = z2b - mu2;
      float var2 = wsum64(df2*df2)*(1.f/64.f);
      float lnv = gr*df2*rsqrtf(var2 + 1e-6f) + br;
      out[((size_t)b*256 + n*4 + iw)*256 + h*64 + cl] = qv + lnv;
    }
    // --- W2 + b2 update ---
    float4 xb4 = *(const float4*)&x2b_pk[j*4];    // slots
    float lx0 = le_s0*xb4.x, lx1 = le_s1*xb4.y, lx2 = le_s2*xb4.z, lx3 = le_s3*xb4.w;
    {
      int c0 = i2*32;
      #pragma unroll 8
      for (int cc=0; cc<32; cc++){
        float4 g4 = *(const float4*)&gz2_pk[(c0+cc)*4];
        W2L[j*65 + c0+cc] -= lx0*g4.x + lx1*g4.y + lx2*g4.z + lx3*g4.w;
      }
    }
    {
      float4 g4r = *(const float4*)&gz2_pk[cl*4];
      b2r -= le_s0*g4r.x + le_s1*g4r.y + le_s2*g4r.z + le_s3*g4r.w;
    }
    __syncthreads();                              // G
    qv = qn; kv = kn; vv = vn; elv = eln;
  }
}

// Fused head: LN(post) -> @wo -> LN(ln) -> fc1 -> fc2 -> fc3. grid 512 rows.
__global__ __launch_bounds__(256) void k_head(const float* __restrict__ hid2,
    const float* __restrict__ pg, const float* __restrict__ pb,
    const float* __restrict__ wo, const float* __restrict__ lg,
    const float* __restrict__ lb, const float* __restrict__ fcw,
    const float* __restrict__ fcb, const float* __restrict__ fc2w,
    const float* __restrict__ fc2b, const float* __restrict__ fc3w,
    const float* __restrict__ fc3b, float* __restrict__ outp){
  int row = blockIdx.x, c = threadIdx.x;
  __shared__ float t1[256];
  __shared__ float t3[256];
  __shared__ float t4[128];
  __shared__ float t5[64];
  __shared__ float rs[4];
  __shared__ float rq[4];
  int wv = c >> 6, ln = c & 63;
  float v = hid2[(size_t)row*256 + c];
  float s1 = wsum64(v), s2 = wsum64(v*v);
  if (ln == 0){ rs[wv]=s1; rq[wv]=s2; }
  __syncthreads();
  float mu = (rs[0]+rs[1]+rs[2]+rs[3])*(1.f/256.f);
  float msq = (rq[0]+rq[1]+rq[2]+rq[3])*(1.f/256.f);
  float var = msq - mu*mu;
  t1[c] = (v-mu)*rsqrtf(var + 1e-5f)*pg[c] + pb[c];
  __syncthreads();
  float a = 0.f;
  for (int k=0;k<256;k++) a += t1[k]*wo[(size_t)k*256 + c];
  float u1 = wsum64(a), u2 = wsum64(a*a);
  if (ln == 0){ rs[wv]=u1; rq[wv]=u2; }
  __syncthreads();
  mu = (rs[0]+rs[1]+rs[2]+rs[3])*(1.f/256.f);
  msq = (rq[0]+rq[1]+rq[2]+rq[3])*(1.f/256.f);
  var = msq - mu*mu;
  t3[c] = (a-mu)*rsqrtf(var + 1e-5f)*lg[c] + lb[c];
  __syncthreads();
  if (c < 128){
    float s = fcb[c];
    for (int k=0;k<256;k++) s += t3[k]*fcw[(size_t)k*128 + c];
    t4[c] = s;
  }
  __syncthreads();
  if (c < 64){
    float s = fc2b[c];
    for (int k=0;k<128;k++) s += t4[k]*fc2w[(size_t)k*64 + c];
    t5[c] = s;
  }
  __syncthreads();
  if (c < 64){
    float p = t5[c]*fc3w[c];
    p = wsum64(p);
    if (c == 0) outp[row] = p + fc3b[0];
  }
}

extern "C" void kernel_launch(void* const* d_in, const int* in_sizes, int n_in,
                              void* d_out, int out_size, void* d_ws, size_t ws_size,
                              hipStream_t stream){
  (void)in_sizes; (void)n_in; (void)out_size; (void)ws_size;
  const float* x       = (const float*)d_in[0];
  const float* s11_w   = (const float*)d_in[1];
  const float* s11_b   = (const float*)d_in[2];
  const float* bn11    = (const float*)d_in[3];
  const float* s12_w   = (const float*)d_in[4];
  const float* s12_b   = (const float*)d_in[5];
  const float* bn12    = (const float*)d_in[6];
  const float* s21_w   = (const float*)d_in[7];
  const float* s21_b   = (const float*)d_in[8];
  const float* bn21    = (const float*)d_in[9];
  const float* s22_w   = (const float*)d_in[10];
  const float* s22_b   = (const float*)d_in[11];
  const float* bn22    = (const float*)d_in[12];
  const float* s3_w    = (const float*)d_in[13];
  const float* s3_b    = (const float*)d_in[14];
  const float* bn3     = (const float*)d_in[15];
  const float* c1_w    = (const float*)d_in[16];
  const float* c1_b    = (const float*)d_in[17];
  const float* cb_w    = (const float*)d_in[18];
  const float* cb_b    = (const float*)d_in[19];
  const float* ln_g    = (const float*)d_in[20];
  const float* ln_b    = (const float*)d_in[21];
  const float* wq      = (const float*)d_in[22];
  const float* wk      = (const float*)d_in[23];
  const float* wv      = (const float*)d_in[24];
  const float* wo      = (const float*)d_in[25];
  const float* lr_w    = (const float*)d_in[26];
  const float* lr_b    = (const float*)d_in[27];
  const float* tib     = (const float*)d_in[28];
  const float* tlnw    = (const float*)d_in[29];
  const float* tlnb    = (const float*)d_in[30];
  const float* W1      = (const float*)d_in[31];
  const float* B1      = (const float*)d_in[32];
  const float* W2      = (const float*)d_in[33];
  const float* B2      = (const float*)d_in[34];
  const float* post_g  = (const float*)d_in[35];
  const float* post_b  = (const float*)d_in[36];
  const float* fc_w    = (const float*)d_in[37];
  const float* fc_b    = (const float*)d_in[38];
  const float* fc2_w   = (const float*)d_in[39];
  const float* fc2_b   = (const float*)d_in[40];
  const float* fc3_w   = (const float*)d_in[41];
  const float* fc3_b   = (const float*)d_in[42];

  float* ws = (float*)d_ws;
  float* xs   = ws;                       // 2359296
  float* xd   = ws + 2359296;             // 2359296
  float* p1   = ws + 4718592;             // 1179648 (pm)
  float* sig  = ws + 7077888;             // 32768
  float* buf0 = ws + 7110656;             // 131072
  float* buf1 = ws + 7241728;             // 131072
  float* accb = ws + 7372800;             // 131072
  float* xqb  = ws + 7634944;             // 131072
  float* xkb  = ws + 7766016;             // 131072
  float* xvb  = ws + 7897088;             // 131072
  float* eta  = ws + 8028160;             // 2048
  float* hid2 = ws + 8030208;             // 131072

  k_stem<<<3072, 192, 0, stream>>>(x, s11_w, s11_b, bn11, xs,
                                   s12_w, s12_b, bn12, xd);
  k_s2m<<<512, 576, 0, stream>>>(xs, xd, s21_w, s21_b, bn21,
                                 s22_w, s22_b, bn22, p1);
  k_s3<<<512, 256, 0, stream>>>(p1, s3_w, s3_b, bn3, sig);
  k_c1<<<512, 256, 0, stream>>>(sig, c1_w, c1_b, buf0);
  {
    float* cin = buf0; float* cout = buf1;
    for (int l=0; l<8; l++){
      int mode = (l == 1) ? 1 : ((l & 1) ? 2 : 0);
      k_conv1d<<<512, 256, 0, stream>>>(cin, cb_w + (size_t)l*196608,
                                        cb_b + l*256, cout, accb, mode);
      float* tmp = cin; cin = cout; cout = tmp;
    }
  }
  k_lnproj<<<512, 256, 0, stream>>>(accb, ln_g, ln_b, wq, wk, wv,
                                    lr_w, lr_b, xqb, xkb, xvb, eta);
  k_ttt<<<8, 512, 0, stream>>>(xqb, xkb, xvb, eta, tib, tlnw, tlnb,
                               W1, B1, W2, B2, hid2);
  k_head<<<512, 256, 0, stream>>>(hid2, post_g, post_b, wo, ln_g, ln_b,
                                  fc_w, fc_b, fc2_w, fc2_b, fc3_w, fc3_b,
                                  (float*)d_out);
}